// Round 3
// baseline (1269.063 us; speedup 1.0000x reference)
//
#include <hip/hip_runtime.h>
#include <cmath>

#define B 8
#define L 1024
#define D 512
#define H 8
#define DH 64
#define DF 2048
#define BLD (B*L*D)
#define M_TOT (B*L)

typedef __attribute__((ext_vector_type(8))) short bf16x8;
typedef __attribute__((ext_vector_type(4))) float f32x4;

__device__ __forceinline__ unsigned short f2bf(float f) {
    unsigned int u = __builtin_bit_cast(unsigned int, f);
    u += 0x7FFFu + ((u >> 16) & 1u);
    return (unsigned short)(u >> 16);
}

__device__ __forceinline__ float gelu_f(float x) {
    float x3 = x * x * x;
    return 0.5f * x * (1.0f + tanhf(0.7978845608028654f * (x + 0.044715f * x3)));
}

__global__ void pos_kernel(const int* __restrict__ seq, const int* __restrict__ pSOC,
                           const int* __restrict__ pEOS, int* __restrict__ pos,
                           int* __restrict__ counts) {
    int b = threadIdx.x;
    if (b >= B) return;
    int SOC = pSOC[0], EOS = pEOS[0];
    int cnt = 0, eos = 0;
    const int* s = seq + b * L;
    int* p = pos + b * L;
    for (int l = 0; l < L; ++l) {
        eos += (s[l] == EOS);
        if (s[l] == SOC && eos == 0) p[cnt++] = l;
    }
    counts[b] = cnt;
}

__global__ void gather_kernel(const float* __restrict__ hid, const int* __restrict__ pos,
                              const int* __restrict__ counts, float* __restrict__ x) {
    int j = blockIdx.x % L, b = blockIdx.x / L;
    int t = threadIdx.x; // 128 threads * float4 = 512
    float4 val = make_float4(0.f, 0.f, 0.f, 0.f);
    if (j < counts[b]) {
        const float4* src = (const float4*)(hid + (size_t)(b * L + pos[b * L + j]) * D);
        val = src[t];
    }
    ((float4*)(x + (size_t)(b * L + j) * D))[t] = val;
}

__global__ void scatter_kernel(const float* __restrict__ x, const int* __restrict__ pos,
                               const int* __restrict__ counts, float* __restrict__ out0) {
    int j = blockIdx.x % L, b = blockIdx.x / L;
    if (j >= counts[b]) return;
    int t = threadIdx.x;
    const float4* src = (const float4*)(x + (size_t)(b * L + j) * D);
    float4* dst = (float4*)(out0 + (size_t)(b * L + pos[b * L + j]) * D);
    dst[t] = src[t];
}

// LayerNorm, f32 in -> bf16 out (consumed only as GEMM A-operand)
__global__ void ln_kernel(const float* __restrict__ X, unsigned short* __restrict__ Y) {
    int row = blockIdx.x;
    int t = threadIdx.x; // 256
    const float* xr = X + (size_t)row * D;
    float a = xr[t], b2 = xr[t + 256];
    float s = a + b2, sq = a * a + b2 * b2;
    for (int m = 1; m < 64; m <<= 1) {
        s += __shfl_xor(s, m);
        sq += __shfl_xor(sq, m);
    }
    __shared__ float ws[4], wq[4];
    int wid = t >> 6;
    if ((t & 63) == 0) { ws[wid] = s; wq[wid] = sq; }
    __syncthreads();
    s = ws[0] + ws[1] + ws[2] + ws[3];
    sq = wq[0] + wq[1] + wq[2] + wq[3];
    float mu = s * (1.0f / D);
    float var = sq * (1.0f / D) - mu * mu;
    float rs = rsqrtf(var + 1e-5f);
    Y[(size_t)row * D + t] = f2bf((a - mu) * rs);
    Y[(size_t)row * D + t + 256] = f2bf((b2 - mu) * rs);
}

// One-time: Wt[n][k] = bf16(W[k][n]).  W is [K][N] f32 row-major.
__global__ void wtrans_kernel(const float* __restrict__ W, unsigned short* __restrict__ Wt,
                              int K, int N) {
    __shared__ float t[32][33];
    int k0 = blockIdx.y * 32, n0 = blockIdx.x * 32;
    int tx = threadIdx.x, ty = threadIdx.y; // (32,8)
    for (int i = ty; i < 32; i += 8)
        t[i][tx] = W[(size_t)(k0 + i) * N + n0 + tx];
    __syncthreads();
    for (int i = ty; i < 32; i += 8)
        Wt[(size_t)(n0 + i) * K + k0 + tx] = f2bf(t[tx][i]);
}

// elementwise f32 -> bf16 (for img)
__global__ void cvt_kernel(const float* __restrict__ X, unsigned short* __restrict__ Y, int n4) {
    int i = blockIdx.x * blockDim.x + threadIdx.x;
    if (i >= n4) return;
    float4 f = ((const float4*)X)[i];
    ushort4 u;
    u.x = f2bf(f.x); u.y = f2bf(f.y); u.z = f2bf(f.z); u.w = f2bf(f.w);
    ((ushort4*)Y)[i] = u;
}

// C[M,N] = A[M,K] @ W[K,N], A bf16 row-major, Wt = W^T bf16 [N][K] row-major.
// MODE 0: f32 store; 1: f32 accumulate; 2: gelu -> bf16 store.
template<int MODE>
__global__ __launch_bounds__(256) void gemm_mfma(const unsigned short* __restrict__ A,
                                                 const unsigned short* __restrict__ Wt,
                                                 void* __restrict__ Cv,
                                                 int M, int K, int N) {
    __shared__ __align__(16) unsigned short As[128][40];
    __shared__ __align__(16) unsigned short Bs[128][40];
    int tid = threadIdx.x, lane = tid & 63;
    int wid = tid >> 6;                     // 4 waves, 2x2 of 64x64
    int wr = (wid >> 1) * 64, wc = (wid & 1) * 64;
    int m0 = blockIdx.y * 128, n0 = blockIdx.x * 128;
    int row16 = lane & 15, koff = (lane >> 4) * 8;
    f32x4 acc[4][4] = {};
    for (int k0 = 0; k0 < K; k0 += 32) {
        #pragma unroll
        for (int qq = 0; qq < 2; ++qq) {
            int e = tid + qq * 256;         // 0..511 chunks of 8 bf16
            int r = e >> 2, c8 = (e & 3) * 8;
            *(bf16x8*)&As[r][c8] = *(const bf16x8*)&A[(size_t)(m0 + r) * K + k0 + c8];
            *(bf16x8*)&Bs[r][c8] = *(const bf16x8*)&Wt[(size_t)(n0 + r) * K + k0 + c8];
        }
        __syncthreads();
        bf16x8 av[4], bv[4];
        #pragma unroll
        for (int m = 0; m < 4; ++m) av[m] = *(const bf16x8*)&As[wr + m * 16 + row16][koff];
        #pragma unroll
        for (int n = 0; n < 4; ++n) bv[n] = *(const bf16x8*)&Bs[wc + n * 16 + row16][koff];
        #pragma unroll
        for (int m = 0; m < 4; ++m)
            #pragma unroll
            for (int n = 0; n < 4; ++n)
                acc[m][n] = __builtin_amdgcn_mfma_f32_16x16x32_bf16(av[m], bv[n], acc[m][n], 0, 0, 0);
        __syncthreads();
    }
    int crow = (lane >> 4) * 4, ccol = lane & 15; // C/D: col=lane&15, row=(lane>>4)*4+reg
    #pragma unroll
    for (int m = 0; m < 4; ++m)
        #pragma unroll
        for (int n = 0; n < 4; ++n)
            #pragma unroll
            for (int r = 0; r < 4; ++r) {
                int grow = m0 + wr + m * 16 + crow + r;
                int gcol = n0 + wc + n * 16 + ccol;
                size_t off = (size_t)grow * N + gcol;
                float vv = acc[m][n][r];
                if (MODE == 0) ((float*)Cv)[off] = vv;
                else if (MODE == 1) ((float*)Cv)[off] += vv;
                else ((unsigned short*)Cv)[off] = f2bf(gelu_f(vv));
            }
}

// Flash-style attention, f32 compute. Q,K,V f32 [B,L,D]; O bf16 [B,L,D].
template<bool MASK>
__global__ __launch_bounds__(256) void attn_kernel(const float* __restrict__ Q,
                                                   const float* __restrict__ Kb,
                                                   const float* __restrict__ Vb,
                                                   unsigned short* __restrict__ O,
                                                   const int* __restrict__ counts) {
    __shared__ float Qs[64][65];
    __shared__ float Ks[64][65];
    __shared__ float Vs[64][65];
    __shared__ float Ss[64][65];
    int tid = threadIdx.x;
    int tx = tid & 15, ty = tid >> 4;
    int qt = blockIdx.x & 15;       // L/64 = 16 q tiles
    int h = (blockIdx.x >> 4) & 7;
    int b = blockIdx.x >> 7;
    int q0 = qt * 64;
    int cnt = MASK ? counts[b] : L;
    for (int e = tid; e < 4096; e += 256) {
        int r = e >> 6, d = e & 63;
        Qs[r][d] = Q[(size_t)(b * L + q0 + r) * D + h * DH + d];
    }
    float m_run[4], l_run[4], o[4][4] = {};
    #pragma unroll
    for (int i = 0; i < 4; ++i) { m_run[i] = -1e30f; l_run[i] = 0.f; }
    for (int kt = 0; kt < 16; ++kt) {
        __syncthreads();
        for (int e = tid; e < 4096; e += 256) {
            int r = e >> 6, d = e & 63;
            Ks[r][d] = Kb[(size_t)(b * L + kt * 64 + r) * D + h * DH + d];
            Vs[r][d] = Vb[(size_t)(b * L + kt * 64 + r) * D + h * DH + d];
        }
        __syncthreads();
        float s[4][4] = {};
        for (int kd = 0; kd < 64; ++kd) {
            float a[4], bb[4];
            #pragma unroll
            for (int i = 0; i < 4; ++i) a[i] = Qs[ty * 4 + i][kd];
            #pragma unroll
            for (int j = 0; j < 4; ++j) bb[j] = Ks[tx * 4 + j][kd];
            #pragma unroll
            for (int i = 0; i < 4; ++i)
                #pragma unroll
                for (int j = 0; j < 4; ++j)
                    s[i][j] += a[i] * bb[j];
        }
        #pragma unroll
        for (int i = 0; i < 4; ++i)
            #pragma unroll
            for (int j = 0; j < 4; ++j) {
                float v = s[i][j] * 0.125f; // 1/sqrt(64)
                if (MASK) {
                    int kidx = kt * 64 + tx * 4 + j;
                    v = (kidx < cnt) ? v : -1e9f;
                }
                s[i][j] = v;
            }
        #pragma unroll
        for (int i = 0; i < 4; ++i) {
            float rm = fmaxf(fmaxf(s[i][0], s[i][1]), fmaxf(s[i][2], s[i][3]));
            for (int mm = 1; mm < 16; mm <<= 1) rm = fmaxf(rm, __shfl_xor(rm, mm));
            float m_new = fmaxf(m_run[i], rm);
            float rs = 0.f;
            #pragma unroll
            for (int j = 0; j < 4; ++j) { s[i][j] = __expf(s[i][j] - m_new); rs += s[i][j]; }
            for (int mm = 1; mm < 16; mm <<= 1) rs += __shfl_xor(rs, mm);
            float factor = __expf(m_run[i] - m_new);
            l_run[i] = l_run[i] * factor + rs;
            m_run[i] = m_new;
            #pragma unroll
            for (int j = 0; j < 4; ++j) o[i][j] *= factor;
        }
        #pragma unroll
        for (int i = 0; i < 4; ++i)
            #pragma unroll
            for (int j = 0; j < 4; ++j)
                Ss[ty * 4 + i][tx * 4 + j] = s[i][j];
        __syncthreads();
        for (int kd = 0; kd < 64; ++kd) {
            float vv[4];
            #pragma unroll
            for (int j = 0; j < 4; ++j) vv[j] = Vs[kd][tx * 4 + j];
            #pragma unroll
            for (int i = 0; i < 4; ++i) {
                float p = Ss[ty * 4 + i][kd];
                #pragma unroll
                for (int j = 0; j < 4; ++j) o[i][j] += p * vv[j];
            }
        }
    }
    #pragma unroll
    for (int i = 0; i < 4; ++i) {
        float inv = 1.0f / l_run[i];
        size_t ro = (size_t)(b * L + q0 + ty * 4 + i) * D + h * DH;
        #pragma unroll
        for (int j = 0; j < 4; ++j) O[ro + tx * 4 + j] = f2bf(o[i][j] * inv);
    }
}

extern "C" void kernel_launch(void* const* d_in, const int* in_sizes, int n_in,
                              void* d_out, int out_size, void* d_ws, size_t ws_size,
                              hipStream_t stream) {
    const float* hid = (const float*)d_in[0];
    const float* img = (const float*)d_in[1];
    const float* Wq  = (const float*)d_in[2];
    const float* Wk  = (const float*)d_in[3];
    const float* Wv  = (const float*)d_in[4];
    const float* Wo  = (const float*)d_in[5];
    const float* Wq2 = (const float*)d_in[6];
    const float* Wk2 = (const float*)d_in[7];
    const float* Wv2 = (const float*)d_in[8];
    const float* Wo2 = (const float*)d_in[9];
    const float* W1  = (const float*)d_in[10];
    const float* W2  = (const float*)d_in[11];
    const int* seq   = (const int*)d_in[12];
    const int* pSOC  = (const int*)d_in[13];
    const int* pEOS  = (const int*)d_in[14];
    float* out0 = (float*)d_out;            // hid_new
    float* out1 = out0 + (size_t)BLD;       // x

    char* w = (char*)d_ws;
    int* pos    = (int*)w;
    int* counts = pos + B * L;
    size_t off = 64 * 1024;
    float* x = (float*)(w + off);              off += (size_t)BLD * 4;   // f32
    unsigned short* xn = (unsigned short*)(w + off); off += (size_t)BLD * 2; // bf16
    float* q = (float*)(w + off);              size_t q_off = off; off += (size_t)BLD * 4;
    float* k = (float*)(w + off);              off += (size_t)BLD * 4;
    float* v = (float*)(w + off);              off += (size_t)BLD * 4;
    unsigned short* o = (unsigned short*)(w + off);    off += (size_t)BLD * 2;
    unsigned short* imgb = (unsigned short*)(w + off); off += (size_t)BLD * 2;
    unsigned short* Wqt  = (unsigned short*)(w + off); off += (size_t)D * D * 2;
    unsigned short* Wkt  = (unsigned short*)(w + off); off += (size_t)D * D * 2;
    unsigned short* Wvt  = (unsigned short*)(w + off); off += (size_t)D * D * 2;
    unsigned short* Wot  = (unsigned short*)(w + off); off += (size_t)D * D * 2;
    unsigned short* Wq2t = (unsigned short*)(w + off); off += (size_t)D * D * 2;
    unsigned short* Wk2t = (unsigned short*)(w + off); off += (size_t)D * D * 2;
    unsigned short* Wv2t = (unsigned short*)(w + off); off += (size_t)D * D * 2;
    unsigned short* Wo2t = (unsigned short*)(w + off); off += (size_t)D * D * 2;
    unsigned short* W1t  = (unsigned short*)(w + off); off += (size_t)D * DF * 2;
    unsigned short* W2t  = (unsigned short*)(w + off); off += (size_t)D * DF * 2;
    unsigned short* mid = (unsigned short*)(w + q_off); // 32MB, aliases q..v (48MB)

    pos_kernel<<<1, 64, 0, stream>>>(seq, pSOC, pEOS, pos, counts);
    // one-time weight transposes to bf16 [N][K]
    dim3 wtb(32, 8);
    dim3 gdd(D / 32, D / 32);
    wtrans_kernel<<<gdd, wtb, 0, stream>>>(Wq,  Wqt,  D, D);
    wtrans_kernel<<<gdd, wtb, 0, stream>>>(Wk,  Wkt,  D, D);
    wtrans_kernel<<<gdd, wtb, 0, stream>>>(Wv,  Wvt,  D, D);
    wtrans_kernel<<<gdd, wtb, 0, stream>>>(Wo,  Wot,  D, D);
    wtrans_kernel<<<gdd, wtb, 0, stream>>>(Wq2, Wq2t, D, D);
    wtrans_kernel<<<gdd, wtb, 0, stream>>>(Wk2, Wk2t, D, D);
    wtrans_kernel<<<gdd, wtb, 0, stream>>>(Wv2, Wv2t, D, D);
    wtrans_kernel<<<gdd, wtb, 0, stream>>>(Wo2, Wo2t, D, D);
    wtrans_kernel<<<dim3(DF / 32, D / 32), wtb, 0, stream>>>(W1, W1t, D, DF);
    wtrans_kernel<<<dim3(D / 32, DF / 32), wtb, 0, stream>>>(W2, W2t, DF, D);
    cvt_kernel<<<(BLD / 4 + 255) / 256, 256, 0, stream>>>(img, imgb, BLD / 4);

    gather_kernel<<<B * L, 128, 0, stream>>>(hid, pos, counts, x);

    dim3 gDD(D / 128, M_TOT / 128);      // (4, 64)
    // block 1: masked self-attention
    ln_kernel<<<M_TOT, 256, 0, stream>>>(x, xn);
    gemm_mfma<0><<<gDD, 256, 0, stream>>>(xn, Wqt, q, M_TOT, D, D);
    gemm_mfma<0><<<gDD, 256, 0, stream>>>(xn, Wkt, k, M_TOT, D, D);
    gemm_mfma<0><<<gDD, 256, 0, stream>>>(xn, Wvt, v, M_TOT, D, D);
    attn_kernel<true><<<B * H * (L / 64), 256, 0, stream>>>(q, k, v, o, counts);
    gemm_mfma<1><<<gDD, 256, 0, stream>>>(o, Wot, x, M_TOT, D, D);
    // block 2: cross-attention to img
    ln_kernel<<<M_TOT, 256, 0, stream>>>(x, xn);
    gemm_mfma<0><<<gDD, 256, 0, stream>>>(xn, Wq2t, q, M_TOT, D, D);
    gemm_mfma<0><<<gDD, 256, 0, stream>>>(imgb, Wk2t, k, M_TOT, D, D);
    gemm_mfma<0><<<gDD, 256, 0, stream>>>(imgb, Wv2t, v, M_TOT, D, D);
    attn_kernel<false><<<B * H * (L / 64), 256, 0, stream>>>(q, k, v, o, counts);
    gemm_mfma<1><<<gDD, 256, 0, stream>>>(o, Wo2t, x, M_TOT, D, D);
    // FFN
    ln_kernel<<<M_TOT, 256, 0, stream>>>(x, xn);
    gemm_mfma<2><<<dim3(DF / 128, M_TOT / 128), 256, 0, stream>>>(xn, W1t, mid, M_TOT, D, DF);
    gemm_mfma<1><<<gDD, 256, 0, stream>>>(mid, W2t, x, M_TOT, DF, D);
    // outputs
    hipMemcpyAsync(out0, hid, (size_t)BLD * sizeof(float), hipMemcpyDeviceToDevice, stream);
    hipMemcpyAsync(out1, x, (size_t)BLD * sizeof(float), hipMemcpyDeviceToDevice, stream);
    scatter_kernel<<<B * L, 128, 0, stream>>>(x, pos, counts, out0);
}

// Round 4
// 568.933 us; speedup vs baseline: 2.2306x; 2.2306x over previous
//
#include <hip/hip_runtime.h>
#include <cmath>

#define B 8
#define L 1024
#define D 512
#define H 8
#define DH 64
#define DF 2048
#define BLD (B*L*D)
#define M_TOT (B*L)

typedef __attribute__((ext_vector_type(8))) short bf16x8;
typedef __attribute__((ext_vector_type(4))) float f32x4;

__device__ __forceinline__ unsigned short f2bf(float f) {
    unsigned int u = __builtin_bit_cast(unsigned int, f);
    u += 0x7FFFu + ((u >> 16) & 1u);
    return (unsigned short)(u >> 16);
}

__device__ __forceinline__ float gelu_f(float x) {
    float x3 = x * x * x;
    return 0.5f * x * (1.0f + tanhf(0.7978845608028654f * (x + 0.044715f * x3)));
}

__global__ void pos_kernel(const int* __restrict__ seq, const int* __restrict__ pSOC,
                           const int* __restrict__ pEOS, int* __restrict__ pos,
                           int* __restrict__ counts) {
    int b = threadIdx.x;
    if (b >= B) return;
    int SOC = pSOC[0], EOS = pEOS[0];
    int cnt = 0, eos = 0;
    const int* s = seq + b * L;
    int* p = pos + b * L;
    for (int l = 0; l < L; ++l) {
        eos += (s[l] == EOS);
        if (s[l] == SOC && eos == 0) p[cnt++] = l;
    }
    counts[b] = cnt;
}

__global__ void gather_kernel(const float* __restrict__ hid, const int* __restrict__ pos,
                              const int* __restrict__ counts, float* __restrict__ x) {
    int j = blockIdx.x % L, b = blockIdx.x / L;
    int t = threadIdx.x; // 128 threads * float4 = 512
    float4 val = make_float4(0.f, 0.f, 0.f, 0.f);
    if (j < counts[b]) {
        const float4* src = (const float4*)(hid + (size_t)(b * L + pos[b * L + j]) * D);
        val = src[t];
    }
    ((float4*)(x + (size_t)(b * L + j) * D))[t] = val;
}

__global__ void scatter_kernel(const float* __restrict__ x, const int* __restrict__ pos,
                               const int* __restrict__ counts, float* __restrict__ out0) {
    int j = blockIdx.x % L, b = blockIdx.x / L;
    if (j >= counts[b]) return;
    int t = threadIdx.x;
    const float4* src = (const float4*)(x + (size_t)(b * L + j) * D);
    float4* dst = (float4*)(out0 + (size_t)(b * L + pos[b * L + j]) * D);
    dst[t] = src[t];
}

// LayerNorm, f32 in -> bf16 out (consumed only as GEMM A-operand)
__global__ void ln_kernel(const float* __restrict__ X, unsigned short* __restrict__ Y) {
    int row = blockIdx.x;
    int t = threadIdx.x; // 256
    const float* xr = X + (size_t)row * D;
    float a = xr[t], b2 = xr[t + 256];
    float s = a + b2, sq = a * a + b2 * b2;
    for (int m = 1; m < 64; m <<= 1) {
        s += __shfl_xor(s, m);
        sq += __shfl_xor(sq, m);
    }
    __shared__ float ws[4], wq[4];
    int wid = t >> 6;
    if ((t & 63) == 0) { ws[wid] = s; wq[wid] = sq; }
    __syncthreads();
    s = ws[0] + ws[1] + ws[2] + ws[3];
    sq = wq[0] + wq[1] + wq[2] + wq[3];
    float mu = s * (1.0f / D);
    float var = sq * (1.0f / D) - mu * mu;
    float rs = rsqrtf(var + 1e-5f);
    Y[(size_t)row * D + t] = f2bf((a - mu) * rs);
    Y[(size_t)row * D + t + 256] = f2bf((b2 - mu) * rs);
}

// One-time: Wt[n][k] = bf16(W[k][n]).  W is [K][N] f32 row-major.
__global__ void wtrans_kernel(const float* __restrict__ W, unsigned short* __restrict__ Wt,
                              int K, int N) {
    __shared__ float t[32][33];
    int k0 = blockIdx.y * 32, n0 = blockIdx.x * 32;
    int tx = threadIdx.x, ty = threadIdx.y; // (32,8)
    for (int i = ty; i < 32; i += 8)
        t[i][tx] = W[(size_t)(k0 + i) * N + n0 + tx];
    __syncthreads();
    for (int i = ty; i < 32; i += 8)
        Wt[(size_t)(n0 + i) * K + k0 + tx] = f2bf(t[tx][i]);
}

// elementwise f32 -> bf16 (for img)
__global__ void cvt_kernel(const float* __restrict__ X, unsigned short* __restrict__ Y, int n4) {
    int i = blockIdx.x * blockDim.x + threadIdx.x;
    if (i >= n4) return;
    float4 f = ((const float4*)X)[i];
    ushort4 u;
    u.x = f2bf(f.x); u.y = f2bf(f.y); u.z = f2bf(f.z); u.w = f2bf(f.w);
    ((ushort4*)Y)[i] = u;
}

// V [B,L,D] bf16 -> Vt [B,H,DH,L] bf16 (per-head transpose)
__global__ __launch_bounds__(256) void vtrans_kernel(const unsigned short* __restrict__ V,
                                                     unsigned short* __restrict__ Vt) {
    __shared__ unsigned short t[64][72];
    int l0 = (blockIdx.x & 15) * 64;
    int h = (blockIdx.x >> 4) & 7;
    int b = blockIdx.x >> 7;
    int tid = threadIdx.x; // 256
    for (int e = tid; e < 512; e += 256) {
        int i = e >> 3, d0 = (e & 7) * 8;
        *(bf16x8*)&t[i][d0] = *(const bf16x8*)&V[(size_t)(b * L + l0 + i) * D + h * DH + d0];
    }
    __syncthreads();
    // read columns: lanes span d=0..63 -> banks spread (stride 36 dwords -> free)
    for (int e = tid; e < 512; e += 256) {
        int d = e & 63, i0 = (e >> 6) * 8;
        bf16x8 val;
        #pragma unroll
        for (int j = 0; j < 8; ++j) val[j] = t[i0 + j][d];
        *(bf16x8*)&Vt[((size_t)((b * H + h) * DH + d)) * L + l0 + i0] = val;
    }
}

// C[M,N] = A[M,K] @ W[K,N], A bf16 row-major, Wt = W^T bf16 [N][K] row-major.
// MODE 0: f32 store; 1: f32 accumulate; 2: gelu -> bf16 store; 3: bf16 store.
template<int MODE>
__global__ __launch_bounds__(256) void gemm_mfma(const unsigned short* __restrict__ A,
                                                 const unsigned short* __restrict__ Wt,
                                                 void* __restrict__ Cv,
                                                 int M, int K, int N) {
    __shared__ __align__(16) unsigned short As[128][40];
    __shared__ __align__(16) unsigned short Bs[128][40];
    int tid = threadIdx.x, lane = tid & 63;
    int wid = tid >> 6;                     // 4 waves, 2x2 of 64x64
    int wr = (wid >> 1) * 64, wc = (wid & 1) * 64;
    int m0 = blockIdx.y * 128, n0 = blockIdx.x * 128;
    int row16 = lane & 15, koff = (lane >> 4) * 8;
    f32x4 acc[4][4] = {};
    for (int k0 = 0; k0 < K; k0 += 32) {
        #pragma unroll
        for (int qq = 0; qq < 2; ++qq) {
            int e = tid + qq * 256;         // 0..511 chunks of 8 bf16
            int r = e >> 2, c8 = (e & 3) * 8;
            *(bf16x8*)&As[r][c8] = *(const bf16x8*)&A[(size_t)(m0 + r) * K + k0 + c8];
            *(bf16x8*)&Bs[r][c8] = *(const bf16x8*)&Wt[(size_t)(n0 + r) * K + k0 + c8];
        }
        __syncthreads();
        bf16x8 av[4], bv[4];
        #pragma unroll
        for (int m = 0; m < 4; ++m) av[m] = *(const bf16x8*)&As[wr + m * 16 + row16][koff];
        #pragma unroll
        for (int n = 0; n < 4; ++n) bv[n] = *(const bf16x8*)&Bs[wc + n * 16 + row16][koff];
        #pragma unroll
        for (int m = 0; m < 4; ++m)
            #pragma unroll
            for (int n = 0; n < 4; ++n)
                acc[m][n] = __builtin_amdgcn_mfma_f32_16x16x32_bf16(av[m], bv[n], acc[m][n], 0, 0, 0);
        __syncthreads();
    }
    int crow = (lane >> 4) * 4, ccol = lane & 15; // C/D: col=lane&15, row=(lane>>4)*4+reg
    #pragma unroll
    for (int m = 0; m < 4; ++m)
        #pragma unroll
        for (int n = 0; n < 4; ++n)
            #pragma unroll
            for (int r = 0; r < 4; ++r) {
                int grow = m0 + wr + m * 16 + crow + r;
                int gcol = n0 + wc + n * 16 + ccol;
                size_t off = (size_t)grow * N + gcol;
                float vv = acc[m][n][r];
                if (MODE == 0) ((float*)Cv)[off] = vv;
                else if (MODE == 1) ((float*)Cv)[off] += vv;
                else if (MODE == 2) ((unsigned short*)Cv)[off] = f2bf(gelu_f(vv));
                else ((unsigned short*)Cv)[off] = f2bf(vv);
            }
}

// MFMA flash attention. Q,K bf16 [B,L,D]; Vt bf16 [B,H,DH,L]; O bf16 [B,L,D].
// grid = B*H*(L/64); 4 waves/block, each wave 16 q-rows.
template<bool MASK>
__global__ __launch_bounds__(256) void attn_mfma(const unsigned short* __restrict__ Q,
                                                 const unsigned short* __restrict__ Kb,
                                                 const unsigned short* __restrict__ Vt,
                                                 unsigned short* __restrict__ O,
                                                 const int* __restrict__ counts) {
    __shared__ __align__(16) unsigned short Ks[64][72];   // [kv][d]
    __shared__ __align__(16) unsigned short Vs[64][72];   // [d][kv]  (from Vt)
    __shared__ __align__(16) unsigned short Ps[4][16][72];// per-wave [q][kv]
    int tid = threadIdx.x, lane = tid & 63, wid = tid >> 6;
    int qt = blockIdx.x & 15, h = (blockIdx.x >> 4) & 7, b = blockIdx.x >> 7;
    int q0 = qt * 64 + wid * 16;
    int cnt = MASK ? counts[b] : L;
    int nt = MASK ? min(16, max(1, (cnt + 63) >> 6)) : 16;
    int r16 = lane & 15, g = lane >> 4;
    // Q fragments (A-frag: row=lane&15, k=(lane>>4)*8+j), 2 k-steps of 32
    const unsigned short* qbase = Q + ((size_t)(b * L + q0 + r16) * D + h * DH + g * 8);
    bf16x8 qv0 = *(const bf16x8*)(qbase);
    bf16x8 qv1 = *(const bf16x8*)(qbase + 32);
    f32x4 o_acc[4] = {};
    float m_run[4], l_run[4];
    #pragma unroll
    for (int r = 0; r < 4; ++r) { m_run[r] = -1e30f; l_run[r] = 0.f; }
    const unsigned short* kb = Kb + (size_t)b * L * D + h * DH;
    const unsigned short* vtb = Vt + (size_t)(b * H + h) * DH * L;
    for (int kt = 0; kt < nt; ++kt) {
        __syncthreads();
        for (int e = tid; e < 512; e += 256) {
            int kv = e >> 3, c0 = (e & 7) * 8;
            *(bf16x8*)&Ks[kv][c0] = *(const bf16x8*)&kb[(size_t)(kt * 64 + kv) * D + c0];
            // Vs rows = d, cols = kv: Vt natural rows
            *(bf16x8*)&Vs[kv][c0] = *(const bf16x8*)&vtb[(size_t)kv * L + kt * 64 + c0];
        }
        __syncthreads();
        // S = Q @ K^T : B-frag from Ks[kv-row][d contiguous]
        f32x4 s[4];
        #pragma unroll
        for (int n = 0; n < 4; ++n) {
            bf16x8 k0 = *(const bf16x8*)&Ks[n * 16 + r16][g * 8];
            bf16x8 k1 = *(const bf16x8*)&Ks[n * 16 + r16][g * 8 + 32];
            f32x4 z = {};
            z = __builtin_amdgcn_mfma_f32_16x16x32_bf16(qv0, k0, z, 0, 0, 0);
            s[n] = __builtin_amdgcn_mfma_f32_16x16x32_bf16(qv1, k1, z, 0, 0, 0);
        }
        // scale + mask; S layout: row(q)=g*4+r, col(kv)=n*16+r16
        #pragma unroll
        for (int n = 0; n < 4; ++n)
            #pragma unroll
            for (int r = 0; r < 4; ++r) {
                float v = s[n][r] * 0.125f;
                if (MASK) {
                    int kidx = kt * 64 + n * 16 + r16;
                    v = (kidx < cnt) ? v : -1e30f;
                }
                s[n][r] = v;
            }
        // online softmax per q-row r
        #pragma unroll
        for (int r = 0; r < 4; ++r) {
            float rm = fmaxf(fmaxf(s[0][r], s[1][r]), fmaxf(s[2][r], s[3][r]));
            #pragma unroll
            for (int mm = 1; mm < 16; mm <<= 1) rm = fmaxf(rm, __shfl_xor(rm, mm));
            float m_new = fmaxf(m_run[r], rm);
            float rs = 0.f;
            #pragma unroll
            for (int n = 0; n < 4; ++n) { float e = __expf(s[n][r] - m_new); s[n][r] = e; rs += e; }
            #pragma unroll
            for (int mm = 1; mm < 16; mm <<= 1) rs += __shfl_xor(rs, mm);
            float factor = __expf(m_run[r] - m_new);
            l_run[r] = l_run[r] * factor + rs;
            m_run[r] = m_new;
            #pragma unroll
            for (int n = 0; n < 4; ++n) o_acc[n][r] *= factor;
        }
        // P -> per-wave LDS, reload as A-frag
        #pragma unroll
        for (int n = 0; n < 4; ++n)
            #pragma unroll
            for (int r = 0; r < 4; ++r)
                Ps[wid][g * 4 + r][n * 16 + r16] = f2bf(s[n][r]);
        bf16x8 pa0 = *(const bf16x8*)&Ps[wid][r16][g * 8];
        bf16x8 pa1 = *(const bf16x8*)&Ps[wid][r16][g * 8 + 32];
        // O += P @ V : B-frag from Vs[d-row][kv contiguous]
        #pragma unroll
        for (int n = 0; n < 4; ++n) {
            bf16x8 v0 = *(const bf16x8*)&Vs[n * 16 + r16][g * 8];
            bf16x8 v1 = *(const bf16x8*)&Vs[n * 16 + r16][g * 8 + 32];
            o_acc[n] = __builtin_amdgcn_mfma_f32_16x16x32_bf16(pa0, v0, o_acc[n], 0, 0, 0);
            o_acc[n] = __builtin_amdgcn_mfma_f32_16x16x32_bf16(pa1, v1, o_acc[n], 0, 0, 0);
        }
    }
    #pragma unroll
    for (int r = 0; r < 4; ++r) {
        float inv = 1.0f / l_run[r];
        size_t ro = (size_t)(b * L + q0 + g * 4 + r) * D + h * DH;
        #pragma unroll
        for (int n = 0; n < 4; ++n)
            O[ro + n * 16 + r16] = f2bf(o_acc[n][r] * inv);
    }
}

extern "C" void kernel_launch(void* const* d_in, const int* in_sizes, int n_in,
                              void* d_out, int out_size, void* d_ws, size_t ws_size,
                              hipStream_t stream) {
    const float* hid = (const float*)d_in[0];
    const float* img = (const float*)d_in[1];
    const float* Wq  = (const float*)d_in[2];
    const float* Wk  = (const float*)d_in[3];
    const float* Wv  = (const float*)d_in[4];
    const float* Wo  = (const float*)d_in[5];
    const float* Wq2 = (const float*)d_in[6];
    const float* Wk2 = (const float*)d_in[7];
    const float* Wv2 = (const float*)d_in[8];
    const float* Wo2 = (const float*)d_in[9];
    const float* W1  = (const float*)d_in[10];
    const float* W2  = (const float*)d_in[11];
    const int* seq   = (const int*)d_in[12];
    const int* pSOC  = (const int*)d_in[13];
    const int* pEOS  = (const int*)d_in[14];
    float* out0 = (float*)d_out;            // hid_new
    float* out1 = out0 + (size_t)BLD;       // x

    char* w = (char*)d_ws;
    int* pos    = (int*)w;
    int* counts = pos + B * L;
    size_t off = 64 * 1024;
    float* x = (float*)(w + off);                    off += (size_t)BLD * 4;
    unsigned short* xn = (unsigned short*)(w + off); off += (size_t)BLD * 2;
    unsigned short* q  = (unsigned short*)(w + off); size_t q_off = off; off += (size_t)BLD * 2;
    unsigned short* k  = (unsigned short*)(w + off); off += (size_t)BLD * 2;
    unsigned short* v  = (unsigned short*)(w + off); off += (size_t)BLD * 2;
    unsigned short* o  = (unsigned short*)(w + off); off += (size_t)BLD * 2;
    unsigned short* vt   = (unsigned short*)(w + off); off += (size_t)BLD * 2;
    unsigned short* imgb = (unsigned short*)(w + off); off += (size_t)BLD * 2;
    unsigned short* Wqt  = (unsigned short*)(w + off); off += (size_t)D * D * 2;
    unsigned short* Wkt  = (unsigned short*)(w + off); off += (size_t)D * D * 2;
    unsigned short* Wvt  = (unsigned short*)(w + off); off += (size_t)D * D * 2;
    unsigned short* Wot  = (unsigned short*)(w + off); off += (size_t)D * D * 2;
    unsigned short* Wq2t = (unsigned short*)(w + off); off += (size_t)D * D * 2;
    unsigned short* Wk2t = (unsigned short*)(w + off); off += (size_t)D * D * 2;
    unsigned short* Wv2t = (unsigned short*)(w + off); off += (size_t)D * D * 2;
    unsigned short* Wo2t = (unsigned short*)(w + off); off += (size_t)D * D * 2;
    unsigned short* W1t  = (unsigned short*)(w + off); off += (size_t)D * DF * 2;
    unsigned short* W2t  = (unsigned short*)(w + off); off += (size_t)D * DF * 2;
    unsigned short* mid = (unsigned short*)(w + q_off); // 32MB = q+k+v+o (all dead by FFN)

    pos_kernel<<<1, 64, 0, stream>>>(seq, pSOC, pEOS, pos, counts);
    dim3 wtb(32, 8);
    dim3 gdd(D / 32, D / 32);
    wtrans_kernel<<<gdd, wtb, 0, stream>>>(Wq,  Wqt,  D, D);
    wtrans_kernel<<<gdd, wtb, 0, stream>>>(Wk,  Wkt,  D, D);
    wtrans_kernel<<<gdd, wtb, 0, stream>>>(Wv,  Wvt,  D, D);
    wtrans_kernel<<<gdd, wtb, 0, stream>>>(Wo,  Wot,  D, D);
    wtrans_kernel<<<gdd, wtb, 0, stream>>>(Wq2, Wq2t, D, D);
    wtrans_kernel<<<gdd, wtb, 0, stream>>>(Wk2, Wk2t, D, D);
    wtrans_kernel<<<gdd, wtb, 0, stream>>>(Wv2, Wv2t, D, D);
    wtrans_kernel<<<gdd, wtb, 0, stream>>>(Wo2, Wo2t, D, D);
    wtrans_kernel<<<dim3(DF / 32, D / 32), wtb, 0, stream>>>(W1, W1t, D, DF);
    wtrans_kernel<<<dim3(D / 32, DF / 32), wtb, 0, stream>>>(W2, W2t, DF, D);
    cvt_kernel<<<(BLD / 4 + 255) / 256, 256, 0, stream>>>(img, imgb, BLD / 4);

    gather_kernel<<<B * L, 128, 0, stream>>>(hid, pos, counts, x);

    dim3 gDD(D / 128, M_TOT / 128);
    int attn_grid = B * H * (L / 64);
    // block 1: masked self-attention
    ln_kernel<<<M_TOT, 256, 0, stream>>>(x, xn);
    gemm_mfma<3><<<gDD, 256, 0, stream>>>(xn, Wqt, q, M_TOT, D, D);
    gemm_mfma<3><<<gDD, 256, 0, stream>>>(xn, Wkt, k, M_TOT, D, D);
    gemm_mfma<3><<<gDD, 256, 0, stream>>>(xn, Wvt, v, M_TOT, D, D);
    vtrans_kernel<<<attn_grid, 256, 0, stream>>>(v, vt);
    attn_mfma<true><<<attn_grid, 256, 0, stream>>>(q, k, vt, o, counts);
    gemm_mfma<1><<<gDD, 256, 0, stream>>>(o, Wot, x, M_TOT, D, D);
    // block 2: cross-attention to img
    ln_kernel<<<M_TOT, 256, 0, stream>>>(x, xn);
    gemm_mfma<3><<<gDD, 256, 0, stream>>>(xn, Wq2t, q, M_TOT, D, D);
    gemm_mfma<3><<<gDD, 256, 0, stream>>>(imgb, Wk2t, k, M_TOT, D, D);
    gemm_mfma<3><<<gDD, 256, 0, stream>>>(imgb, Wv2t, v, M_TOT, D, D);
    vtrans_kernel<<<attn_grid, 256, 0, stream>>>(v, vt);
    attn_mfma<false><<<attn_grid, 256, 0, stream>>>(q, k, vt, o, counts);
    gemm_mfma<1><<<gDD, 256, 0, stream>>>(o, Wo2t, x, M_TOT, D, D);
    // FFN
    ln_kernel<<<M_TOT, 256, 0, stream>>>(x, xn);
    gemm_mfma<2><<<dim3(DF / 128, M_TOT / 128), 256, 0, stream>>>(xn, W1t, mid, M_TOT, D, DF);
    gemm_mfma<1><<<gDD, 256, 0, stream>>>(mid, W2t, x, M_TOT, DF, D);
    // outputs
    hipMemcpyAsync(out0, hid, (size_t)BLD * sizeof(float), hipMemcpyDeviceToDevice, stream);
    hipMemcpyAsync(out1, x, (size_t)BLD * sizeof(float), hipMemcpyDeviceToDevice, stream);
    scatter_kernel<<<B * L, 128, 0, stream>>>(x, pos, counts, out0);
}

// Round 5
// 394.548 us; speedup vs baseline: 3.2165x; 1.4420x over previous
//
#include <hip/hip_runtime.h>
#include <cmath>

#define B 8
#define L 1024
#define D 512
#define H 8
#define DH 64
#define DF 2048
#define BLD (B*L*D)
#define M_TOT (B*L)

typedef __attribute__((ext_vector_type(8))) short bf16x8;
typedef __attribute__((ext_vector_type(4))) float f32x4;
typedef const __attribute__((address_space(1))) void* gas_ptr;
typedef __attribute__((address_space(3))) void* las_ptr;

__device__ __forceinline__ unsigned short f2bf(float f) {
    unsigned int u = __builtin_bit_cast(unsigned int, f);
    u += 0x7FFFu + ((u >> 16) & 1u);
    return (unsigned short)(u >> 16);
}

__device__ __forceinline__ float gelu_f(float x) {
    float x3 = x * x * x;
    return 0.5f * x * (1.0f + tanhf(0.7978845608028654f * (x + 0.044715f * x3)));
}

// parallel compaction scan: 1 block/batch, 1024 threads
__global__ __launch_bounds__(1024) void pos_kernel(const int* __restrict__ seq,
                                                   const int* __restrict__ pSOC,
                                                   const int* __restrict__ pEOS,
                                                   int* __restrict__ pos,
                                                   int* __restrict__ counts) {
    int b = blockIdx.x, t = threadIdx.x;
    int lane = t & 63, w = t >> 6;
    int sv = seq[b * L + t];
    int SOC = pSOC[0], EOS = pEOS[0];
    int eosf = (sv == EOS) ? 1 : 0;
    unsigned long long em = __ballot(eosf);
    int eexcl = __popcll(em & ((1ull << lane) - 1ull));
    __shared__ int ewt[16], swt[16];
    if (lane == 63) ewt[w] = eexcl + eosf;
    __syncthreads();
    int ebase = 0;
    for (int i = 0; i < w; ++i) ebase += ewt[i];
    int ecum_incl = ebase + eexcl + eosf;           // cumsum(eos) inclusive
    int socf = (sv == SOC && ecum_incl == 0) ? 1 : 0;
    unsigned long long sm = __ballot(socf);
    int sexcl = __popcll(sm & ((1ull << lane) - 1ull));
    if (lane == 63) swt[w] = sexcl + socf;
    __syncthreads();
    int sbase = 0, stot = 0;
    for (int i = 0; i < 16; ++i) { int v = swt[i]; if (i < w) sbase += v; stot += v; }
    if (socf) pos[b * L + sbase + sexcl] = t;
    if (t == 0) counts[b] = stot;
}

__global__ void gather_kernel(const float* __restrict__ hid, const int* __restrict__ pos,
                              const int* __restrict__ counts, float* __restrict__ x) {
    int j = blockIdx.x % L, b = blockIdx.x / L;
    int t = threadIdx.x;
    float4 val = make_float4(0.f, 0.f, 0.f, 0.f);
    if (j < counts[b]) {
        const float4* src = (const float4*)(hid + (size_t)(b * L + pos[b * L + j]) * D);
        val = src[t];
    }
    ((float4*)(x + (size_t)(b * L + j) * D))[t] = val;
}

__global__ void scatter_kernel(const float* __restrict__ x, const int* __restrict__ pos,
                               const int* __restrict__ counts, float* __restrict__ out0) {
    int j = blockIdx.x % L, b = blockIdx.x / L;
    if (j >= counts[b]) return;
    int t = threadIdx.x;
    const float4* src = (const float4*)(x + (size_t)(b * L + j) * D);
    float4* dst = (float4*)(out0 + (size_t)(b * L + pos[b * L + j]) * D);
    dst[t] = src[t];
}

// LayerNorm, f32 in -> bf16 out
__global__ void ln_kernel(const float* __restrict__ X, unsigned short* __restrict__ Y) {
    int row = blockIdx.x;
    int t = threadIdx.x; // 256
    const float* xr = X + (size_t)row * D;
    float a = xr[t], b2 = xr[t + 256];
    float s = a + b2, sq = a * a + b2 * b2;
    for (int m = 1; m < 64; m <<= 1) {
        s += __shfl_xor(s, m);
        sq += __shfl_xor(sq, m);
    }
    __shared__ float ws[4], wq[4];
    int wid = t >> 6;
    if ((t & 63) == 0) { ws[wid] = s; wq[wid] = sq; }
    __syncthreads();
    s = ws[0] + ws[1] + ws[2] + ws[3];
    sq = wq[0] + wq[1] + wq[2] + wq[3];
    float mu = s * (1.0f / D);
    float var = sq * (1.0f / D) - mu * mu;
    float rs = rsqrtf(var + 1e-5f);
    Y[(size_t)row * D + t] = f2bf((a - mu) * rs);
    Y[(size_t)row * D + t + 256] = f2bf((b2 - mu) * rs);
}

// One-time: Wt[n][k] = bf16(W[k][n]).  W is [K][N] f32 row-major.
__global__ void wtrans_kernel(const float* __restrict__ W, unsigned short* __restrict__ Wt,
                              int K, int N) {
    __shared__ float t[32][33];
    int k0 = blockIdx.y * 32, n0 = blockIdx.x * 32;
    int tx = threadIdx.x, ty = threadIdx.y; // (32,8)
    for (int i = ty; i < 32; i += 8)
        t[i][tx] = W[(size_t)(k0 + i) * N + n0 + tx];
    __syncthreads();
    for (int i = ty; i < 32; i += 8)
        Wt[(size_t)(n0 + i) * K + k0 + tx] = f2bf(t[tx][i]);
}

__global__ void cvt_kernel(const float* __restrict__ X, unsigned short* __restrict__ Y, int n4) {
    int i = blockIdx.x * blockDim.x + threadIdx.x;
    if (i >= n4) return;
    float4 f = ((const float4*)X)[i];
    ushort4 u;
    u.x = f2bf(f.x); u.y = f2bf(f.y); u.z = f2bf(f.z); u.w = f2bf(f.w);
    ((ushort4*)Y)[i] = u;
}

// V rows (stride vstride, head h at col h*DH) -> Vt [B,H,DH,L]
__global__ __launch_bounds__(256) void vtrans_kernel(const unsigned short* __restrict__ V,
                                                     int vstride,
                                                     unsigned short* __restrict__ Vt) {
    __shared__ unsigned short t[64][72];
    int l0 = (blockIdx.x & 15) * 64;
    int h = (blockIdx.x >> 4) & 7;
    int b = blockIdx.x >> 7;
    int tid = threadIdx.x; // 256
    const unsigned short* vb = V + (size_t)b * L * vstride + h * DH;
    for (int e = tid; e < 512; e += 256) {
        int i = e >> 3, d0 = (e & 7) * 8;
        *(bf16x8*)&t[i][d0] = *(const bf16x8*)&vb[(size_t)(l0 + i) * vstride + d0];
    }
    __syncthreads();
    for (int e = tid; e < 512; e += 256) {
        int d = e & 63, i0 = (e >> 6) * 8;
        bf16x8 val;
        #pragma unroll
        for (int j = 0; j < 8; ++j) val[j] = t[i0 + j][d];
        *(bf16x8*)&Vt[((size_t)((b * H + h) * DH + d)) * L + l0 + i0] = val;
    }
}

// C[M,N] = A[M,K] @ W[K,N]; A bf16 row-major, Wt = W^T bf16 [N][K].
// m97-style: linear LDS + global_load_lds width-16 staging.
// MODE 0: f32 store; 1: f32 accumulate; 2: gelu->bf16; 3: bf16 store.
template<int MODE>
__global__ __launch_bounds__(256) void gemm_mfma(const unsigned short* __restrict__ A,
                                                 const unsigned short* __restrict__ Wt,
                                                 void* __restrict__ Cv,
                                                 int M, int K, int N) {
    __shared__ __align__(16) unsigned short As[128 * 32];
    __shared__ __align__(16) unsigned short Bs[128 * 32];
    int tid = threadIdx.x, lane = tid & 63;
    int wid = tid >> 6;
    int wr = (wid >> 1) * 64, wc = (wid & 1) * 64;
    int m0 = blockIdx.y * 128, n0 = blockIdx.x * 128;
    int row16 = lane & 15, g = lane >> 4;
    f32x4 acc[4][4] = {};
    for (int k0 = 0; k0 < K; k0 += 32) {
        #pragma unroll
        for (int q = 0; q < 2; ++q) {
            int e = q * 256 + tid;             // 16B chunk id, 0..511
            int r = e >> 2, c8 = (e & 3) * 8;
            int ldso = (q * 256 + wid * 64) * 8;  // wave-uniform short offset
            __builtin_amdgcn_global_load_lds((gas_ptr)(A + (size_t)(m0 + r) * K + k0 + c8),
                                             (las_ptr)(As + ldso), 16, 0, 0);
            __builtin_amdgcn_global_load_lds((gas_ptr)(Wt + (size_t)(n0 + r) * K + k0 + c8),
                                             (las_ptr)(Bs + ldso), 16, 0, 0);
        }
        __syncthreads();
        bf16x8 av[4], bv[4];
        #pragma unroll
        for (int m = 0; m < 4; ++m) av[m] = *(const bf16x8*)&As[(wr + m * 16 + row16) * 32 + g * 8];
        #pragma unroll
        for (int n = 0; n < 4; ++n) bv[n] = *(const bf16x8*)&Bs[(wc + n * 16 + row16) * 32 + g * 8];
        #pragma unroll
        for (int m = 0; m < 4; ++m)
            #pragma unroll
            for (int n = 0; n < 4; ++n)
                acc[m][n] = __builtin_amdgcn_mfma_f32_16x16x32_bf16(av[m], bv[n], acc[m][n], 0, 0, 0);
        __syncthreads();
    }
    int crow = (lane >> 4) * 4, ccol = lane & 15;
    #pragma unroll
    for (int m = 0; m < 4; ++m)
        #pragma unroll
        for (int n = 0; n < 4; ++n)
            #pragma unroll
            for (int r = 0; r < 4; ++r) {
                int grow = m0 + wr + m * 16 + crow + r;
                int gcol = n0 + wc + n * 16 + ccol;
                size_t off = (size_t)grow * N + gcol;
                float vv = acc[m][n][r];
                if (MODE == 0) ((float*)Cv)[off] = vv;
                else if (MODE == 1) ((float*)Cv)[off] += vv;
                else if (MODE == 2) ((unsigned short*)Cv)[off] = f2bf(gelu_f(vv));
                else ((unsigned short*)Cv)[off] = f2bf(vv);
            }
}

// MFMA flash attention. Q,K row-strided (head col at h*DH); Vt [B,H,DH,L]; O bf16 [B,L,D].
template<bool MASK>
__global__ __launch_bounds__(256) void attn_mfma(const unsigned short* __restrict__ Q, int qstride,
                                                 const unsigned short* __restrict__ Kb, int kstride,
                                                 const unsigned short* __restrict__ Vt,
                                                 unsigned short* __restrict__ O,
                                                 const int* __restrict__ counts) {
    __shared__ __align__(16) unsigned short Ks[64][72];
    __shared__ __align__(16) unsigned short Vs[64][72];
    __shared__ __align__(16) unsigned short Ps[4][16][72];
    int tid = threadIdx.x, lane = tid & 63, wid = tid >> 6;
    int qt = blockIdx.x & 15, h = (blockIdx.x >> 4) & 7, b = blockIdx.x >> 7;
    int q0 = qt * 64 + wid * 16;
    int cnt = MASK ? counts[b] : L;
    int nt = MASK ? min(16, max(1, (cnt + 63) >> 6)) : 16;
    int r16 = lane & 15, g = lane >> 4;
    const unsigned short* qbase = Q + ((size_t)(b * L + q0 + r16) * qstride + h * DH + g * 8);
    bf16x8 qv0 = *(const bf16x8*)(qbase);
    bf16x8 qv1 = *(const bf16x8*)(qbase + 32);
    f32x4 o_acc[4] = {};
    float m_run[4], l_run[4];
    #pragma unroll
    for (int r = 0; r < 4; ++r) { m_run[r] = -1e30f; l_run[r] = 0.f; }
    const unsigned short* kb = Kb + (size_t)b * L * kstride + h * DH;
    const unsigned short* vtb = Vt + (size_t)(b * H + h) * DH * L;
    for (int kt = 0; kt < nt; ++kt) {
        __syncthreads();
        for (int e = tid; e < 512; e += 256) {
            int kv = e >> 3, c0 = (e & 7) * 8;
            *(bf16x8*)&Ks[kv][c0] = *(const bf16x8*)&kb[(size_t)(kt * 64 + kv) * kstride + c0];
            *(bf16x8*)&Vs[kv][c0] = *(const bf16x8*)&vtb[(size_t)kv * L + kt * 64 + c0];
        }
        __syncthreads();
        f32x4 s[4];
        #pragma unroll
        for (int n = 0; n < 4; ++n) {
            bf16x8 k0 = *(const bf16x8*)&Ks[n * 16 + r16][g * 8];
            bf16x8 k1 = *(const bf16x8*)&Ks[n * 16 + r16][g * 8 + 32];
            f32x4 z = {};
            z = __builtin_amdgcn_mfma_f32_16x16x32_bf16(qv0, k0, z, 0, 0, 0);
            s[n] = __builtin_amdgcn_mfma_f32_16x16x32_bf16(qv1, k1, z, 0, 0, 0);
        }
        #pragma unroll
        for (int n = 0; n < 4; ++n)
            #pragma unroll
            for (int r = 0; r < 4; ++r) {
                float v = s[n][r] * 0.125f;
                if (MASK) {
                    int kidx = kt * 64 + n * 16 + r16;
                    v = (kidx < cnt) ? v : -1e30f;
                }
                s[n][r] = v;
            }
        #pragma unroll
        for (int r = 0; r < 4; ++r) {
            float rm = fmaxf(fmaxf(s[0][r], s[1][r]), fmaxf(s[2][r], s[3][r]));
            #pragma unroll
            for (int mm = 1; mm < 16; mm <<= 1) rm = fmaxf(rm, __shfl_xor(rm, mm));
            float m_new = fmaxf(m_run[r], rm);
            float rs = 0.f;
            #pragma unroll
            for (int n = 0; n < 4; ++n) { float e = __expf(s[n][r] - m_new); s[n][r] = e; rs += e; }
            #pragma unroll
            for (int mm = 1; mm < 16; mm <<= 1) rs += __shfl_xor(rs, mm);
            float factor = __expf(m_run[r] - m_new);
            l_run[r] = l_run[r] * factor + rs;
            m_run[r] = m_new;
            #pragma unroll
            for (int n = 0; n < 4; ++n) o_acc[n][r] *= factor;
        }
        #pragma unroll
        for (int n = 0; n < 4; ++n)
            #pragma unroll
            for (int r = 0; r < 4; ++r)
                Ps[wid][g * 4 + r][n * 16 + r16] = f2bf(s[n][r]);
        bf16x8 pa0 = *(const bf16x8*)&Ps[wid][r16][g * 8];
        bf16x8 pa1 = *(const bf16x8*)&Ps[wid][r16][g * 8 + 32];
        #pragma unroll
        for (int n = 0; n < 4; ++n) {
            bf16x8 v0 = *(const bf16x8*)&Vs[n * 16 + r16][g * 8];
            bf16x8 v1 = *(const bf16x8*)&Vs[n * 16 + r16][g * 8 + 32];
            o_acc[n] = __builtin_amdgcn_mfma_f32_16x16x32_bf16(pa0, v0, o_acc[n], 0, 0, 0);
            o_acc[n] = __builtin_amdgcn_mfma_f32_16x16x32_bf16(pa1, v1, o_acc[n], 0, 0, 0);
        }
    }
    #pragma unroll
    for (int r = 0; r < 4; ++r) {
        float inv = 1.0f / l_run[r];
        size_t ro = (size_t)(b * L + q0 + g * 4 + r) * D + h * DH;
        #pragma unroll
        for (int n = 0; n < 4; ++n)
            O[ro + n * 16 + r16] = f2bf(o_acc[n][r] * inv);
    }
}

extern "C" void kernel_launch(void* const* d_in, const int* in_sizes, int n_in,
                              void* d_out, int out_size, void* d_ws, size_t ws_size,
                              hipStream_t stream) {
    const float* hid = (const float*)d_in[0];
    const float* img = (const float*)d_in[1];
    const float* Wq  = (const float*)d_in[2];
    const float* Wk  = (const float*)d_in[3];
    const float* Wv  = (const float*)d_in[4];
    const float* Wo  = (const float*)d_in[5];
    const float* Wq2 = (const float*)d_in[6];
    const float* Wk2 = (const float*)d_in[7];
    const float* Wv2 = (const float*)d_in[8];
    const float* Wo2 = (const float*)d_in[9];
    const float* W1  = (const float*)d_in[10];
    const float* W2  = (const float*)d_in[11];
    const int* seq   = (const int*)d_in[12];
    const int* pSOC  = (const int*)d_in[13];
    const int* pEOS  = (const int*)d_in[14];
    float* out0 = (float*)d_out;            // hid_new
    float* out1 = out0 + (size_t)BLD;       // x

    char* w = (char*)d_ws;
    int* pos    = (int*)w;
    int* counts = pos + B * L;
    size_t off = 64 * 1024;
    float* x = (float*)(w + off);                     off += (size_t)BLD * 4;          // 16MB
    unsigned short* xn  = (unsigned short*)(w + off); off += (size_t)BLD * 2;          // 8MB
    unsigned short* qkv = (unsigned short*)(w + off); off += (size_t)M_TOT * 3 * D * 2;// 24MB
    unsigned short* o   = (unsigned short*)(w + off); off += (size_t)BLD * 2;          // 8MB
    unsigned short* vt  = (unsigned short*)(w + off); off += (size_t)BLD * 2;          // 8MB
    unsigned short* imgb= (unsigned short*)(w + off); off += (size_t)BLD * 2;          // 8MB
    unsigned short* Wqt  = (unsigned short*)(w + off); off += (size_t)D * D * 2; // Wq,Wk,Wv contiguous
    unsigned short* Wkt  = (unsigned short*)(w + off); off += (size_t)D * D * 2;
    unsigned short* Wvt  = (unsigned short*)(w + off); off += (size_t)D * D * 2;
    unsigned short* Wot  = (unsigned short*)(w + off); off += (size_t)D * D * 2;
    unsigned short* Wq2t = (unsigned short*)(w + off); off += (size_t)D * D * 2;
    unsigned short* Wk2t = (unsigned short*)(w + off); off += (size_t)D * D * 2; // Wk2,Wv2 contiguous
    unsigned short* Wv2t = (unsigned short*)(w + off); off += (size_t)D * D * 2;
    unsigned short* Wo2t = (unsigned short*)(w + off); off += (size_t)D * D * 2;
    unsigned short* W1t  = (unsigned short*)(w + off); off += (size_t)D * DF * 2;
    unsigned short* W2t  = (unsigned short*)(w + off); off += (size_t)D * DF * 2;
    // aliases (sequential-stream safe):
    unsigned short* q2  = qkv;                       // [M,512], qkv dead in block 2
    unsigned short* kv2 = qkv + (size_t)M_TOT * D;   // [M,1024]
    unsigned short* mid = qkv;                       // [M,2048] spans qkv+o, both dead in FFN

    pos_kernel<<<B, 1024, 0, stream>>>(seq, pSOC, pEOS, pos, counts);
    dim3 wtb(32, 8);
    dim3 gdd(D / 32, D / 32);
    wtrans_kernel<<<gdd, wtb, 0, stream>>>(Wq,  Wqt,  D, D);
    wtrans_kernel<<<gdd, wtb, 0, stream>>>(Wk,  Wkt,  D, D);
    wtrans_kernel<<<gdd, wtb, 0, stream>>>(Wv,  Wvt,  D, D);
    wtrans_kernel<<<gdd, wtb, 0, stream>>>(Wo,  Wot,  D, D);
    wtrans_kernel<<<gdd, wtb, 0, stream>>>(Wq2, Wq2t, D, D);
    wtrans_kernel<<<gdd, wtb, 0, stream>>>(Wk2, Wk2t, D, D);
    wtrans_kernel<<<gdd, wtb, 0, stream>>>(Wv2, Wv2t, D, D);
    wtrans_kernel<<<gdd, wtb, 0, stream>>>(Wo2, Wo2t, D, D);
    wtrans_kernel<<<dim3(DF / 32, D / 32), wtb, 0, stream>>>(W1, W1t, D, DF);
    wtrans_kernel<<<dim3(D / 32, DF / 32), wtb, 0, stream>>>(W2, W2t, DF, D);
    cvt_kernel<<<(BLD / 4 + 255) / 256, 256, 0, stream>>>(img, imgb, BLD / 4);

    gather_kernel<<<B * L, 128, 0, stream>>>(hid, pos, counts, x);

    int attn_grid = B * H * (L / 64);
    dim3 gDD(4, 64), gQKV(12, 64), gKV2(8, 64), gF1(16, 64);
    // block 1: masked self-attention (fused QKV)
    ln_kernel<<<M_TOT, 256, 0, stream>>>(x, xn);
    gemm_mfma<3><<<gQKV, 256, 0, stream>>>(xn, Wqt, qkv, M_TOT, D, 3 * D);
    vtrans_kernel<<<attn_grid, 256, 0, stream>>>(qkv + 2 * D, 3 * D, vt);
    attn_mfma<true><<<attn_grid, 256, 0, stream>>>(qkv, 3 * D, qkv + D, 3 * D, vt, o, counts);
    gemm_mfma<1><<<gDD, 256, 0, stream>>>(o, Wot, x, M_TOT, D, D);
    // block 2: cross-attention to img (fused KV)
    ln_kernel<<<M_TOT, 256, 0, stream>>>(x, xn);
    gemm_mfma<3><<<gKV2, 256, 0, stream>>>(imgb, Wk2t, kv2, M_TOT, D, 2 * D);
    gemm_mfma<3><<<gDD, 256, 0, stream>>>(xn, Wq2t, q2, M_TOT, D, D);
    vtrans_kernel<<<attn_grid, 256, 0, stream>>>(kv2 + D, 2 * D, vt);
    attn_mfma<false><<<attn_grid, 256, 0, stream>>>(q2, D, kv2, 2 * D, vt, o, counts);
    gemm_mfma<1><<<gDD, 256, 0, stream>>>(o, Wo2t, x, M_TOT, D, D);
    // FFN
    ln_kernel<<<M_TOT, 256, 0, stream>>>(x, xn);
    gemm_mfma<2><<<gF1, 256, 0, stream>>>(xn, W1t, mid, M_TOT, D, DF);
    gemm_mfma<1><<<gDD, 256, 0, stream>>>(mid, W2t, x, M_TOT, DF, D);
    // outputs
    hipMemcpyAsync(out0, hid, (size_t)BLD * sizeof(float), hipMemcpyDeviceToDevice, stream);
    hipMemcpyAsync(out1, x, (size_t)BLD * sizeof(float), hipMemcpyDeviceToDevice, stream);
    scatter_kernel<<<B * L, 128, 0, stream>>>(x, pos, counts, out0);
}

// Round 6
// 355.351 us; speedup vs baseline: 3.5713x; 1.1103x over previous
//
#include <hip/hip_runtime.h>
#include <cmath>

#define B 8
#define L 1024
#define D 512
#define H 8
#define DH 64
#define DF 2048
#define BLD (B*L*D)
#define M_TOT (B*L)

typedef __attribute__((ext_vector_type(8))) short bf16x8;
typedef __attribute__((ext_vector_type(4))) float f32x4;
typedef const __attribute__((address_space(1))) void* gas_ptr;
typedef __attribute__((address_space(3))) void* las_ptr;

__device__ __forceinline__ unsigned short f2bf(float f) {
    unsigned int u = __builtin_bit_cast(unsigned int, f);
    u += 0x7FFFu + ((u >> 16) & 1u);
    return (unsigned short)(u >> 16);
}

__device__ __forceinline__ float gelu_f(float x) {
    float x3 = x * x * x;
    return 0.5f * x * (1.0f + tanhf(0.7978845608028654f * (x + 0.044715f * x3)));
}

// parallel compaction scan: 1 block/batch, 1024 threads
__global__ __launch_bounds__(1024) void pos_kernel(const int* __restrict__ seq,
                                                   const int* __restrict__ pSOC,
                                                   const int* __restrict__ pEOS,
                                                   int* __restrict__ pos,
                                                   int* __restrict__ counts) {
    int b = blockIdx.x, t = threadIdx.x;
    int lane = t & 63, w = t >> 6;
    int sv = seq[b * L + t];
    int SOC = pSOC[0], EOS = pEOS[0];
    int eosf = (sv == EOS) ? 1 : 0;
    unsigned long long em = __ballot(eosf);
    int eexcl = __popcll(em & ((1ull << lane) - 1ull));
    __shared__ int ewt[16], swt[16];
    if (lane == 63) ewt[w] = eexcl + eosf;
    __syncthreads();
    int ebase = 0;
    for (int i = 0; i < w; ++i) ebase += ewt[i];
    int ecum_incl = ebase + eexcl + eosf;
    int socf = (sv == SOC && ecum_incl == 0) ? 1 : 0;
    unsigned long long sm = __ballot(socf);
    int sexcl = __popcll(sm & ((1ull << lane) - 1ull));
    if (lane == 63) swt[w] = sexcl + socf;
    __syncthreads();
    int sbase = 0, stot = 0;
    for (int i = 0; i < 16; ++i) { int v = swt[i]; if (i < w) sbase += v; stot += v; }
    if (socf) pos[b * L + sbase + sexcl] = t;
    if (t == 0) counts[b] = stot;
}

__global__ void gather_kernel(const float* __restrict__ hid, const int* __restrict__ pos,
                              const int* __restrict__ counts, float* __restrict__ x) {
    int j = blockIdx.x % L, b = blockIdx.x / L;
    int t = threadIdx.x;
    float4 val = make_float4(0.f, 0.f, 0.f, 0.f);
    if (j < counts[b]) {
        const float4* src = (const float4*)(hid + (size_t)(b * L + pos[b * L + j]) * D);
        val = src[t];
    }
    ((float4*)(x + (size_t)(b * L + j) * D))[t] = val;
}

__global__ void scatter_kernel(const float* __restrict__ x, const int* __restrict__ pos,
                               const int* __restrict__ counts, float* __restrict__ out0) {
    int j = blockIdx.x % L, b = blockIdx.x / L;
    if (j >= counts[b]) return;
    int t = threadIdx.x;
    const float4* src = (const float4*)(x + (size_t)(b * L + j) * D);
    float4* dst = (float4*)(out0 + (size_t)(b * L + pos[b * L + j]) * D);
    dst[t] = src[t];
}

// all rows j > cnt get a copy of pad-representative row cnt
__global__ void bcast_kernel(float* __restrict__ x, const int* __restrict__ counts) {
    int j = blockIdx.x % L, b = blockIdx.x / L;
    int cnt = counts[b];
    if (j <= cnt) return;
    int t = threadIdx.x; // 128
    const float4* src = (const float4*)(x + (size_t)(b * L + cnt) * D);
    float4* dst = (float4*)(x + (size_t)(b * L + j) * D);
    dst[t] = src[t];
}

// LayerNorm, f32 in -> bf16 out; skips rows in fully-padding 128-blocks
__global__ void ln_kernel(const float* __restrict__ X, unsigned short* __restrict__ Y,
                          const int* __restrict__ counts) {
    int row = blockIdx.x;
    if ((row & 1023 & ~127) > counts[row >> 10]) return;
    int t = threadIdx.x; // 256
    const float* xr = X + (size_t)row * D;
    float a = xr[t], b2 = xr[t + 256];
    float s = a + b2, sq = a * a + b2 * b2;
    for (int m = 1; m < 64; m <<= 1) {
        s += __shfl_xor(s, m);
        sq += __shfl_xor(sq, m);
    }
    __shared__ float ws[4], wq[4];
    int wid = t >> 6;
    if ((t & 63) == 0) { ws[wid] = s; wq[wid] = sq; }
    __syncthreads();
    s = ws[0] + ws[1] + ws[2] + ws[3];
    sq = wq[0] + wq[1] + wq[2] + wq[3];
    float mu = s * (1.0f / D);
    float var = sq * (1.0f / D) - mu * mu;
    float rs = rsqrtf(var + 1e-5f);
    Y[(size_t)row * D + t] = f2bf((a - mu) * rs);
    Y[(size_t)row * D + t + 256] = f2bf((b2 - mu) * rs);
}

// One-time: Wt[n][k] = bf16(W[k][n]).  W is [K][N] f32 row-major.
__global__ void wtrans_kernel(const float* __restrict__ W, unsigned short* __restrict__ Wt,
                              int K, int N) {
    __shared__ float t[32][33];
    int k0 = blockIdx.y * 32, n0 = blockIdx.x * 32;
    int tx = threadIdx.x, ty = threadIdx.y; // (32,8)
    for (int i = ty; i < 32; i += 8)
        t[i][tx] = W[(size_t)(k0 + i) * N + n0 + tx];
    __syncthreads();
    for (int i = ty; i < 32; i += 8)
        Wt[(size_t)(n0 + i) * K + k0 + tx] = f2bf(t[tx][i]);
}

__global__ void cvt_kernel(const float* __restrict__ X, unsigned short* __restrict__ Y, int n4) {
    int i = blockIdx.x * blockDim.x + threadIdx.x;
    if (i >= n4) return;
    float4 f = ((const float4*)X)[i];
    ushort4 u;
    u.x = f2bf(f.x); u.y = f2bf(f.y); u.z = f2bf(f.z); u.w = f2bf(f.w);
    ((ushort4*)Y)[i] = u;
}

// V rows (stride vstride, head h at col h*DH) -> Vt [B,H,DH,L]
template<bool SKIP>
__global__ __launch_bounds__(256) void vtrans_kernel(const unsigned short* __restrict__ V,
                                                     int vstride,
                                                     unsigned short* __restrict__ Vt,
                                                     const int* __restrict__ counts) {
    __shared__ unsigned short t[64][72];
    int l0 = (blockIdx.x & 15) * 64;
    int h = (blockIdx.x >> 4) & 7;
    int b = blockIdx.x >> 7;
    if (SKIP && l0 > counts[b]) return;
    int tid = threadIdx.x; // 256
    const unsigned short* vb = V + (size_t)b * L * vstride + h * DH;
    for (int e = tid; e < 512; e += 256) {
        int i = e >> 3, d0 = (e & 7) * 8;
        *(bf16x8*)&t[i][d0] = *(const bf16x8*)&vb[(size_t)(l0 + i) * vstride + d0];
    }
    __syncthreads();
    for (int e = tid; e < 512; e += 256) {
        int d = e & 63, i0 = (e >> 6) * 8;
        bf16x8 val;
        #pragma unroll
        for (int j = 0; j < 8; ++j) val[j] = t[i0 + j][d];
        *(bf16x8*)&Vt[((size_t)((b * H + h) * DH + d)) * L + l0 + i0] = val;
    }
}

// C[M,N] = A[M,K] @ W[K,N]; A bf16 row-major [B*L rows], Wt = W^T bf16 [N][K].
// MODE 0: f32 store; 1: f32 accumulate; 2: gelu->bf16; 3: bf16 store.
// SKIP: drop blocks whose 128-row within-batch start exceeds counts[b].
template<int MODE, bool SKIP>
__global__ __launch_bounds__(256) void gemm_mfma(const unsigned short* __restrict__ A,
                                                 const unsigned short* __restrict__ Wt,
                                                 void* __restrict__ Cv,
                                                 int M, int K, int N,
                                                 const int* __restrict__ counts) {
    int m0 = blockIdx.y * 128, n0 = blockIdx.x * 128;
    if (SKIP && (m0 & 1023) > counts[m0 >> 10]) return;
    __shared__ __align__(16) unsigned short As[128 * 32];
    __shared__ __align__(16) unsigned short Bs[128 * 32];
    int tid = threadIdx.x, lane = tid & 63;
    int wid = tid >> 6;
    int wr = (wid >> 1) * 64, wc = (wid & 1) * 64;
    int row16 = lane & 15, g = lane >> 4;
    f32x4 acc[4][4] = {};
    for (int k0 = 0; k0 < K; k0 += 32) {
        #pragma unroll
        for (int q = 0; q < 2; ++q) {
            int e = q * 256 + tid;
            int r = e >> 2, c8 = (e & 3) * 8;
            int ldso = (q * 256 + wid * 64) * 8;
            __builtin_amdgcn_global_load_lds((gas_ptr)(A + (size_t)(m0 + r) * K + k0 + c8),
                                             (las_ptr)(As + ldso), 16, 0, 0);
            __builtin_amdgcn_global_load_lds((gas_ptr)(Wt + (size_t)(n0 + r) * K + k0 + c8),
                                             (las_ptr)(Bs + ldso), 16, 0, 0);
        }
        __syncthreads();
        bf16x8 av[4], bv[4];
        #pragma unroll
        for (int m = 0; m < 4; ++m) av[m] = *(const bf16x8*)&As[(wr + m * 16 + row16) * 32 + g * 8];
        #pragma unroll
        for (int n = 0; n < 4; ++n) bv[n] = *(const bf16x8*)&Bs[(wc + n * 16 + row16) * 32 + g * 8];
        #pragma unroll
        for (int m = 0; m < 4; ++m)
            #pragma unroll
            for (int n = 0; n < 4; ++n)
                acc[m][n] = __builtin_amdgcn_mfma_f32_16x16x32_bf16(av[m], bv[n], acc[m][n], 0, 0, 0);
        __syncthreads();
    }
    int crow = (lane >> 4) * 4, ccol = lane & 15;
    #pragma unroll
    for (int m = 0; m < 4; ++m)
        #pragma unroll
        for (int n = 0; n < 4; ++n)
            #pragma unroll
            for (int r = 0; r < 4; ++r) {
                int grow = m0 + wr + m * 16 + crow + r;
                int gcol = n0 + wc + n * 16 + ccol;
                size_t off = (size_t)grow * N + gcol;
                float vv = acc[m][n][r];
                if (MODE == 0) ((float*)Cv)[off] = vv;
                else if (MODE == 1) ((float*)Cv)[off] += vv;
                else if (MODE == 2) ((unsigned short*)Cv)[off] = f2bf(gelu_f(vv));
                else ((unsigned short*)Cv)[off] = f2bf(vv);
            }
}

// MFMA flash attention with XOR-swizzled LDS. Q,K row-strided; Vt [B,H,DH,L]; O bf16 [B,L,D].
template<bool MASK>
__global__ __launch_bounds__(256) void attn_mfma(const unsigned short* __restrict__ Q, int qstride,
                                                 const unsigned short* __restrict__ Kb, int kstride,
                                                 const unsigned short* __restrict__ Vt,
                                                 unsigned short* __restrict__ O,
                                                 const int* __restrict__ counts) {
    int qt = blockIdx.x & 15, h = (blockIdx.x >> 4) & 7, b = blockIdx.x >> 7;
    int cntb = counts[b];
    if (qt * 64 > cntb) return;           // pad q-tiles (broadcast fixes them)
    __shared__ __align__(16) unsigned short Ks[64][64];
    __shared__ __align__(16) unsigned short Vs[64][64];
    __shared__ __align__(16) unsigned short Ps[4][16][64];
    int tid = threadIdx.x, lane = tid & 63, wid = tid >> 6;
    int q0 = qt * 64 + wid * 16;
    int cnt = MASK ? cntb : L;
    int nt = MASK ? min(16, max(1, (cnt + 63) >> 6)) : 16;
    int r16 = lane & 15, g = lane >> 4;
    int swmask = (r16 & 7) << 3;
    const unsigned short* qbase = Q + ((size_t)(b * L + q0 + r16) * qstride + h * DH + g * 8);
    bf16x8 qv0 = *(const bf16x8*)(qbase);
    bf16x8 qv1 = *(const bf16x8*)(qbase + 32);
    f32x4 o_acc[4] = {};
    float m_run[4], l_run[4];
    #pragma unroll
    for (int r = 0; r < 4; ++r) { m_run[r] = -1e30f; l_run[r] = 0.f; }
    const unsigned short* kb = Kb + (size_t)b * L * kstride + h * DH;
    const unsigned short* vtb = Vt + (size_t)(b * H + h) * DH * L;
    for (int kt = 0; kt < nt; ++kt) {
        __syncthreads();
        for (int e = tid; e < 512; e += 256) {
            int kv = e >> 3, c0 = (e & 7) * 8;
            int sw = c0 ^ ((kv & 7) << 3);
            *(bf16x8*)&Ks[kv][sw] = *(const bf16x8*)&kb[(size_t)(kt * 64 + kv) * kstride + c0];
            *(bf16x8*)&Vs[kv][sw] = *(const bf16x8*)&vtb[(size_t)kv * L + kt * 64 + c0];
        }
        __syncthreads();
        f32x4 s[4];
        #pragma unroll
        for (int n = 0; n < 4; ++n) {
            bf16x8 k0 = *(const bf16x8*)&Ks[n * 16 + r16][(g * 8) ^ swmask];
            bf16x8 k1 = *(const bf16x8*)&Ks[n * 16 + r16][(g * 8 + 32) ^ swmask];
            f32x4 z = {};
            z = __builtin_amdgcn_mfma_f32_16x16x32_bf16(qv0, k0, z, 0, 0, 0);
            s[n] = __builtin_amdgcn_mfma_f32_16x16x32_bf16(qv1, k1, z, 0, 0, 0);
        }
        #pragma unroll
        for (int n = 0; n < 4; ++n)
            #pragma unroll
            for (int r = 0; r < 4; ++r) {
                float v = s[n][r] * 0.125f;
                if (MASK) {
                    int kidx = kt * 64 + n * 16 + r16;
                    v = (kidx < cnt) ? v : -1e30f;
                }
                s[n][r] = v;
            }
        #pragma unroll
        for (int r = 0; r < 4; ++r) {
            float rm = fmaxf(fmaxf(s[0][r], s[1][r]), fmaxf(s[2][r], s[3][r]));
            #pragma unroll
            for (int mm = 1; mm < 16; mm <<= 1) rm = fmaxf(rm, __shfl_xor(rm, mm));
            float m_new = fmaxf(m_run[r], rm);
            float rs = 0.f;
            #pragma unroll
            for (int n = 0; n < 4; ++n) { float e = __expf(s[n][r] - m_new); s[n][r] = e; rs += e; }
            #pragma unroll
            for (int mm = 1; mm < 16; mm <<= 1) rs += __shfl_xor(rs, mm);
            float factor = __expf(m_run[r] - m_new);
            l_run[r] = l_run[r] * factor + rs;
            m_run[r] = m_new;
            #pragma unroll
            for (int n = 0; n < 4; ++n) o_acc[n][r] *= factor;
        }
        #pragma unroll
        for (int n = 0; n < 4; ++n)
            #pragma unroll
            for (int r = 0; r < 4; ++r) {
                int qrow = g * 4 + r;
                Ps[wid][qrow][(n * 16 + r16) ^ ((qrow & 7) << 3)] = f2bf(s[n][r]);
            }
        bf16x8 pa0 = *(const bf16x8*)&Ps[wid][r16][(g * 8) ^ swmask];
        bf16x8 pa1 = *(const bf16x8*)&Ps[wid][r16][(g * 8 + 32) ^ swmask];
        #pragma unroll
        for (int n = 0; n < 4; ++n) {
            bf16x8 v0 = *(const bf16x8*)&Vs[n * 16 + r16][(g * 8) ^ swmask];
            bf16x8 v1 = *(const bf16x8*)&Vs[n * 16 + r16][(g * 8 + 32) ^ swmask];
            o_acc[n] = __builtin_amdgcn_mfma_f32_16x16x32_bf16(pa0, v0, o_acc[n], 0, 0, 0);
            o_acc[n] = __builtin_amdgcn_mfma_f32_16x16x32_bf16(pa1, v1, o_acc[n], 0, 0, 0);
        }
    }
    #pragma unroll
    for (int r = 0; r < 4; ++r) {
        float inv = 1.0f / l_run[r];
        size_t ro = (size_t)(b * L + q0 + g * 4 + r) * D + h * DH;
        #pragma unroll
        for (int n = 0; n < 4; ++n)
            O[ro + n * 16 + r16] = f2bf(o_acc[n][r] * inv);
    }
}

extern "C" void kernel_launch(void* const* d_in, const int* in_sizes, int n_in,
                              void* d_out, int out_size, void* d_ws, size_t ws_size,
                              hipStream_t stream) {
    const float* hid = (const float*)d_in[0];
    const float* img = (const float*)d_in[1];
    const float* Wq  = (const float*)d_in[2];
    const float* Wk  = (const float*)d_in[3];
    const float* Wv  = (const float*)d_in[4];
    const float* Wo  = (const float*)d_in[5];
    const float* Wq2 = (const float*)d_in[6];
    const float* Wk2 = (const float*)d_in[7];
    const float* Wv2 = (const float*)d_in[8];
    const float* Wo2 = (const float*)d_in[9];
    const float* W1  = (const float*)d_in[10];
    const float* W2  = (const float*)d_in[11];
    const int* seq   = (const int*)d_in[12];
    const int* pSOC  = (const int*)d_in[13];
    const int* pEOS  = (const int*)d_in[14];
    float* out0 = (float*)d_out;            // hid_new
    float* out1 = out0 + (size_t)BLD;       // x

    char* w = (char*)d_ws;
    int* pos    = (int*)w;
    int* counts = pos + B * L;
    size_t off = 64 * 1024;
    float* x = (float*)(w + off);                     off += (size_t)BLD * 4;
    unsigned short* xn  = (unsigned short*)(w + off); off += (size_t)BLD * 2;
    unsigned short* qkv = (unsigned short*)(w + off); off += (size_t)M_TOT * 3 * D * 2;
    unsigned short* o   = (unsigned short*)(w + off); off += (size_t)BLD * 2;
    unsigned short* vt  = (unsigned short*)(w + off); off += (size_t)BLD * 2;
    unsigned short* imgb= (unsigned short*)(w + off); off += (size_t)BLD * 2;
    unsigned short* Wqt  = (unsigned short*)(w + off); off += (size_t)D * D * 2; // Wq,Wk,Wv contiguous
    unsigned short* Wkt  = (unsigned short*)(w + off); off += (size_t)D * D * 2;
    unsigned short* Wvt  = (unsigned short*)(w + off); off += (size_t)D * D * 2;
    unsigned short* Wot  = (unsigned short*)(w + off); off += (size_t)D * D * 2;
    unsigned short* Wq2t = (unsigned short*)(w + off); off += (size_t)D * D * 2;
    unsigned short* Wk2t = (unsigned short*)(w + off); off += (size_t)D * D * 2; // Wk2,Wv2 contiguous
    unsigned short* Wv2t = (unsigned short*)(w + off); off += (size_t)D * D * 2;
    unsigned short* Wo2t = (unsigned short*)(w + off); off += (size_t)D * D * 2;
    unsigned short* W1t  = (unsigned short*)(w + off); off += (size_t)D * DF * 2;
    unsigned short* W2t  = (unsigned short*)(w + off); off += (size_t)D * DF * 2;
    unsigned short* q2  = qkv;
    unsigned short* kv2 = qkv + (size_t)M_TOT * D;
    unsigned short* mid = qkv;

    pos_kernel<<<B, 1024, 0, stream>>>(seq, pSOC, pEOS, pos, counts);
    dim3 wtb(32, 8);
    dim3 gdd(D / 32, D / 32);
    wtrans_kernel<<<gdd, wtb, 0, stream>>>(Wq,  Wqt,  D, D);
    wtrans_kernel<<<gdd, wtb, 0, stream>>>(Wk,  Wkt,  D, D);
    wtrans_kernel<<<gdd, wtb, 0, stream>>>(Wv,  Wvt,  D, D);
    wtrans_kernel<<<gdd, wtb, 0, stream>>>(Wo,  Wot,  D, D);
    wtrans_kernel<<<gdd, wtb, 0, stream>>>(Wq2, Wq2t, D, D);
    wtrans_kernel<<<gdd, wtb, 0, stream>>>(Wk2, Wk2t, D, D);
    wtrans_kernel<<<gdd, wtb, 0, stream>>>(Wv2, Wv2t, D, D);
    wtrans_kernel<<<gdd, wtb, 0, stream>>>(Wo2, Wo2t, D, D);
    wtrans_kernel<<<dim3(DF / 32, D / 32), wtb, 0, stream>>>(W1, W1t, D, DF);
    wtrans_kernel<<<dim3(D / 32, DF / 32), wtb, 0, stream>>>(W2, W2t, DF, D);
    cvt_kernel<<<(BLD / 4 + 255) / 256, 256, 0, stream>>>(img, imgb, BLD / 4);

    gather_kernel<<<B * L, 128, 0, stream>>>(hid, pos, counts, x);

    int attn_grid = B * H * (L / 64);
    dim3 gDD(4, 64), gQKV(12, 64), gKV2(8, 64), gF1(16, 64);
    // block 1: masked self-attention (fused QKV)
    ln_kernel<<<M_TOT, 256, 0, stream>>>(x, xn, counts);
    gemm_mfma<3, true><<<gQKV, 256, 0, stream>>>(xn, Wqt, qkv, M_TOT, D, 3 * D, counts);
    vtrans_kernel<true><<<attn_grid, 256, 0, stream>>>(qkv + 2 * D, 3 * D, vt, counts);
    attn_mfma<true><<<attn_grid, 256, 0, stream>>>(qkv, 3 * D, qkv + D, 3 * D, vt, o, counts);
    gemm_mfma<1, true><<<gDD, 256, 0, stream>>>(o, Wot, x, M_TOT, D, D, counts);
    // block 2: cross-attention to img (fused KV)
    ln_kernel<<<M_TOT, 256, 0, stream>>>(x, xn, counts);
    gemm_mfma<3, false><<<gKV2, 256, 0, stream>>>(imgb, Wk2t, kv2, M_TOT, D, 2 * D, counts);
    gemm_mfma<3, true><<<gDD, 256, 0, stream>>>(xn, Wq2t, q2, M_TOT, D, D, counts);
    vtrans_kernel<false><<<attn_grid, 256, 0, stream>>>(kv2 + D, 2 * D, vt, counts);
    attn_mfma<false><<<attn_grid, 256, 0, stream>>>(q2, D, kv2, 2 * D, vt, o, counts);
    gemm_mfma<1, true><<<gDD, 256, 0, stream>>>(o, Wo2t, x, M_TOT, D, D, counts);
    // FFN
    ln_kernel<<<M_TOT, 256, 0, stream>>>(x, xn, counts);
    gemm_mfma<2, true><<<gF1, 256, 0, stream>>>(xn, W1t, mid, M_TOT, D, DF, counts);
    gemm_mfma<1, true><<<gDD, 256, 0, stream>>>(mid, W2t, x, M_TOT, DF, D, counts);
    // pad-row broadcast, then outputs
    bcast_kernel<<<B * L, 128, 0, stream>>>(x, counts);
    hipMemcpyAsync(out0, hid, (size_t)BLD * sizeof(float), hipMemcpyDeviceToDevice, stream);
    hipMemcpyAsync(out1, x, (size_t)BLD * sizeof(float), hipMemcpyDeviceToDevice, stream);
    scatter_kernel<<<B * L, 128, 0, stream>>>(x, pos, counts, out0);
}

// Round 7
// 305.855 us; speedup vs baseline: 4.1492x; 1.1618x over previous
//
#include <hip/hip_runtime.h>
#include <cmath>

#define B 8
#define L 1024
#define D 512
#define H 8
#define DH 64
#define DF 2048
#define BLD (B*L*D)
#define M_TOT (B*L)

typedef __attribute__((ext_vector_type(8))) short bf16x8;
typedef __attribute__((ext_vector_type(4))) float f32x4;
typedef const __attribute__((address_space(1))) void* gas_ptr;
typedef __attribute__((address_space(3))) void* las_ptr;

__device__ __forceinline__ unsigned short f2bf(float f) {
    unsigned int u = __builtin_bit_cast(unsigned int, f);
    u += 0x7FFFu + ((u >> 16) & 1u);
    return (unsigned short)(u >> 16);
}
__device__ __forceinline__ float bf2f(unsigned short s) {
    return __builtin_bit_cast(float, ((unsigned int)s) << 16);
}

__device__ __forceinline__ float gelu_f(float x) {
    float x3 = x * x * x;
    return 0.5f * x * (1.0f + tanhf(0.7978845608028654f * (x + 0.044715f * x3)));
}

// parallel compaction scan: 1 block/batch, 1024 threads
__global__ __launch_bounds__(1024) void pos_kernel(const int* __restrict__ seq,
                                                   const int* __restrict__ pSOC,
                                                   const int* __restrict__ pEOS,
                                                   int* __restrict__ pos,
                                                   int* __restrict__ counts) {
    int b = blockIdx.x, t = threadIdx.x;
    int lane = t & 63, w = t >> 6;
    int sv = seq[b * L + t];
    int SOC = pSOC[0], EOS = pEOS[0];
    int eosf = (sv == EOS) ? 1 : 0;
    unsigned long long em = __ballot(eosf);
    int eexcl = __popcll(em & ((1ull << lane) - 1ull));
    __shared__ int ewt[16], swt[16];
    if (lane == 63) ewt[w] = eexcl + eosf;
    __syncthreads();
    int ebase = 0;
    for (int i = 0; i < w; ++i) ebase += ewt[i];
    int ecum_incl = ebase + eexcl + eosf;
    int socf = (sv == SOC && ecum_incl == 0) ? 1 : 0;
    unsigned long long sm = __ballot(socf);
    int sexcl = __popcll(sm & ((1ull << lane) - 1ull));
    if (lane == 63) swt[w] = sexcl + socf;
    __syncthreads();
    int sbase = 0, stot = 0;
    for (int i = 0; i < 16; ++i) { int v = swt[i]; if (i < w) sbase += v; stot += v; }
    if (socf) pos[b * L + sbase + sexcl] = t;
    if (t == 0) counts[b] = stot;
}

__global__ void gather_kernel(const float* __restrict__ hid, const int* __restrict__ pos,
                              const int* __restrict__ counts, float* __restrict__ x) {
    int j = blockIdx.x % L, b = blockIdx.x / L;
    int t = threadIdx.x;
    float4 val = make_float4(0.f, 0.f, 0.f, 0.f);
    if (j < counts[b]) {
        const float4* src = (const float4*)(hid + (size_t)(b * L + pos[b * L + j]) * D);
        val = src[t];
    }
    ((float4*)(x + (size_t)(b * L + j) * D))[t] = val;
}

__global__ void scatter_kernel(const float* __restrict__ x, const int* __restrict__ pos,
                               const int* __restrict__ counts, float* __restrict__ out0) {
    int j = blockIdx.x % L, b = blockIdx.x / L;
    if (j >= counts[b]) return;
    int t = threadIdx.x;
    const float4* src = (const float4*)(x + (size_t)(b * L + j) * D);
    float4* dst = (float4*)(out0 + (size_t)(b * L + pos[b * L + j]) * D);
    dst[t] = src[t];
}

// all rows j > cnt get a copy of pad-representative row cnt
__global__ void bcast_kernel(float* __restrict__ x, const int* __restrict__ counts) {
    int j = blockIdx.x % L, b = blockIdx.x / L;
    int cnt = counts[b];
    if (j <= cnt) return;
    int t = threadIdx.x; // 128
    const float4* src = (const float4*)(x + (size_t)(b * L + cnt) * D);
    float4* dst = (float4*)(x + (size_t)(b * L + j) * D);
    dst[t] = src[t];
}

// LayerNorm, f32 in -> bf16 out; skips rows in fully-padding 128-blocks
__global__ void ln_kernel(const float* __restrict__ X, unsigned short* __restrict__ Y,
                          const int* __restrict__ counts) {
    int row = blockIdx.x;
    if ((row & 1023 & ~127) > counts[row >> 10]) return;
    int t = threadIdx.x; // 256
    const float* xr = X + (size_t)row * D;
    float a = xr[t], b2 = xr[t + 256];
    float s = a + b2, sq = a * a + b2 * b2;
    for (int m = 1; m < 64; m <<= 1) {
        s += __shfl_xor(s, m);
        sq += __shfl_xor(sq, m);
    }
    __shared__ float ws[4], wq[4];
    int wid = t >> 6;
    if ((t & 63) == 0) { ws[wid] = s; wq[wid] = sq; }
    __syncthreads();
    s = ws[0] + ws[1] + ws[2] + ws[3];
    sq = wq[0] + wq[1] + wq[2] + wq[3];
    float mu = s * (1.0f / D);
    float var = sq * (1.0f / D) - mu * mu;
    float rs = rsqrtf(var + 1e-5f);
    Y[(size_t)row * D + t] = f2bf((a - mu) * rs);
    Y[(size_t)row * D + t + 256] = f2bf((b2 - mu) * rs);
}

// fused one-time weight transpose: all 10 weights in one launch
struct WtArgs {
    const float* src[10];
    unsigned short* dst[10];
};
__global__ void wtrans_all(WtArgs a) {
    __shared__ float t[32][33];
    int bid = blockIdx.x;
    int w, tn, tk, K, N;
    if (bid < 2048)      { w = bid >> 8;      int t2 = bid & 255;  N = 512;  K = 512;  tn = t2 & 15; tk = t2 >> 4; }
    else if (bid < 3072) { w = 8;             int t2 = bid - 2048; N = 2048; K = 512;  tn = t2 & 63; tk = t2 >> 6; }
    else                 { w = 9;             int t2 = bid - 3072; N = 512;  K = 2048; tn = t2 & 15; tk = t2 >> 4; }
    const float* W = a.src[w];
    unsigned short* Wt = a.dst[w];
    int k0 = tk * 32, n0 = tn * 32;
    int tx = threadIdx.x, ty = threadIdx.y; // (32,8)
    for (int i = ty; i < 32; i += 8)
        t[i][tx] = W[(size_t)(k0 + i) * N + n0 + tx];
    __syncthreads();
    for (int i = ty; i < 32; i += 8)
        Wt[(size_t)(n0 + i) * K + k0 + tx] = f2bf(t[tx][i]);
}

__global__ void cvt_kernel(const float* __restrict__ X, unsigned short* __restrict__ Y, int n4) {
    int i = blockIdx.x * blockDim.x + threadIdx.x;
    if (i >= n4) return;
    float4 f = ((const float4*)X)[i];
    ushort4 u;
    u.x = f2bf(f.x); u.y = f2bf(f.y); u.z = f2bf(f.z); u.w = f2bf(f.w);
    ((ushort4*)Y)[i] = u;
}

// V rows (stride vstride, head h at col h*DH) -> Vt [B,H,DH,L]
template<bool SKIP>
__global__ __launch_bounds__(256) void vtrans_kernel(const unsigned short* __restrict__ V,
                                                     int vstride,
                                                     unsigned short* __restrict__ Vt,
                                                     const int* __restrict__ counts) {
    __shared__ unsigned short t[64][72];
    int l0 = (blockIdx.x & 15) * 64;
    int h = (blockIdx.x >> 4) & 7;
    int b = blockIdx.x >> 7;
    if (SKIP && l0 > counts[b]) return;
    int tid = threadIdx.x; // 256
    const unsigned short* vb = V + (size_t)b * L * vstride + h * DH;
    for (int e = tid; e < 512; e += 256) {
        int i = e >> 3, d0 = (e & 7) * 8;
        *(bf16x8*)&t[i][d0] = *(const bf16x8*)&vb[(size_t)(l0 + i) * vstride + d0];
    }
    __syncthreads();
    for (int e = tid; e < 512; e += 256) {
        int d = e & 63, i0 = (e >> 6) * 8;
        bf16x8 val;
        #pragma unroll
        for (int j = 0; j < 8; ++j) val[j] = t[i0 + j][d];
        *(bf16x8*)&Vt[((size_t)((b * H + h) * DH + d)) * L + l0 + i0] = val;
    }
}

// C[M,N] = A[M,K] @ W[K,N]; A bf16 row-major [B*L rows], Wt = W^T bf16 [N][K].
// MODE 0: f32 store; 1: f32 accumulate; 2: gelu->bf16; 3: bf16 store.
template<int MODE, bool SKIP>
__global__ __launch_bounds__(256) void gemm_mfma(const unsigned short* __restrict__ A,
                                                 const unsigned short* __restrict__ Wt,
                                                 void* __restrict__ Cv,
                                                 int M, int K, int N,
                                                 const int* __restrict__ counts) {
    int m0 = blockIdx.y * 128, n0 = blockIdx.x * 128;
    if (SKIP && (m0 & 1023) > counts[m0 >> 10]) return;
    __shared__ __align__(16) unsigned short As[128 * 32];
    __shared__ __align__(16) unsigned short Bs[128 * 32];
    int tid = threadIdx.x, lane = tid & 63;
    int wid = tid >> 6;
    int wr = (wid >> 1) * 64, wc = (wid & 1) * 64;
    int row16 = lane & 15, g = lane >> 4;
    f32x4 acc[4][4] = {};
    for (int k0 = 0; k0 < K; k0 += 32) {
        #pragma unroll
        for (int q = 0; q < 2; ++q) {
            int e = q * 256 + tid;
            int r = e >> 2, c8 = (e & 3) * 8;
            int ldso = (q * 256 + wid * 64) * 8;
            __builtin_amdgcn_global_load_lds((gas_ptr)(A + (size_t)(m0 + r) * K + k0 + c8),
                                             (las_ptr)(As + ldso), 16, 0, 0);
            __builtin_amdgcn_global_load_lds((gas_ptr)(Wt + (size_t)(n0 + r) * K + k0 + c8),
                                             (las_ptr)(Bs + ldso), 16, 0, 0);
        }
        __syncthreads();
        bf16x8 av[4], bv[4];
        #pragma unroll
        for (int m = 0; m < 4; ++m) av[m] = *(const bf16x8*)&As[(wr + m * 16 + row16) * 32 + g * 8];
        #pragma unroll
        for (int n = 0; n < 4; ++n) bv[n] = *(const bf16x8*)&Bs[(wc + n * 16 + row16) * 32 + g * 8];
        #pragma unroll
        for (int m = 0; m < 4; ++m)
            #pragma unroll
            for (int n = 0; n < 4; ++n)
                acc[m][n] = __builtin_amdgcn_mfma_f32_16x16x32_bf16(av[m], bv[n], acc[m][n], 0, 0, 0);
        __syncthreads();
    }
    int crow = (lane >> 4) * 4, ccol = lane & 15;
    #pragma unroll
    for (int m = 0; m < 4; ++m)
        #pragma unroll
        for (int n = 0; n < 4; ++n)
            #pragma unroll
            for (int r = 0; r < 4; ++r) {
                int grow = m0 + wr + m * 16 + crow + r;
                int gcol = n0 + wc + n * 16 + ccol;
                size_t off = (size_t)grow * N + gcol;
                float vv = acc[m][n][r];
                if (MODE == 0) ((float*)Cv)[off] = vv;
                else if (MODE == 1) ((float*)Cv)[off] += vv;
                else if (MODE == 2) ((unsigned short*)Cv)[off] = f2bf(gelu_f(vv));
                else ((unsigned short*)Cv)[off] = f2bf(vv);
            }
}

// MFMA flash attention, XOR-swizzled LDS, register K/V prefetch,
// XCD-chunked grid swizzle, optional split-KV (2 chunks of 8 tiles).
// SPLIT=false: grid B*H*16, writes O. SPLIT=true: grid B*H*16*2, writes PO+ML.
template<bool MASK, bool SPLIT>
__global__ __launch_bounds__(256) void attn_mfma(const unsigned short* __restrict__ Q, int qstride,
                                                 const unsigned short* __restrict__ Kb, int kstride,
                                                 const unsigned short* __restrict__ Vt,
                                                 unsigned short* __restrict__ O,
                                                 unsigned short* __restrict__ PO,
                                                 float* __restrict__ ML,
                                                 const int* __restrict__ counts) {
    int nwg = gridDim.x;
    int wg = (blockIdx.x & 7) * (nwg >> 3) + (blockIdx.x >> 3); // XCD-chunked: each XCD = one b
    int qt = wg & 15;
    int cidx = SPLIT ? ((wg >> 4) & 1) : 0;
    int h = SPLIT ? ((wg >> 5) & 7) : ((wg >> 4) & 7);
    int b = SPLIT ? (wg >> 8) : (wg >> 7);
    int cntb = counts[b];
    if (qt * 64 > cntb) return;
    __shared__ __align__(16) unsigned short Ks[64][64];
    __shared__ __align__(16) unsigned short Vs[64][64];
    __shared__ __align__(16) unsigned short Ps[4][16][64];
    int tid = threadIdx.x, lane = tid & 63, wid = tid >> 6;
    int q0 = qt * 64 + wid * 16;
    int cnt = MASK ? cntb : L;
    int nt = MASK ? min(16, max(1, (cnt + 63) >> 6)) : 16;
    int kt0 = SPLIT ? cidx * 8 : 0;
    int kt1 = SPLIT ? (cidx * 8 + 8) : nt;
    int r16 = lane & 15, g = lane >> 4;
    int swmask = (r16 & 7) << 3;
    const unsigned short* qbase = Q + ((size_t)(b * L + q0 + r16) * qstride + h * DH + g * 8);
    bf16x8 qv0 = *(const bf16x8*)(qbase);
    bf16x8 qv1 = *(const bf16x8*)(qbase + 32);
    f32x4 o_acc[4] = {};
    float m_run[4], l_run[4];
    #pragma unroll
    for (int r = 0; r < 4; ++r) { m_run[r] = -1e30f; l_run[r] = 0.f; }
    const unsigned short* kb = Kb + (size_t)b * L * kstride + h * DH;
    const unsigned short* vtb = Vt + (size_t)(b * H + h) * DH * L;
    // register prefetch (T14): stage tile kt0 now
    bf16x8 kreg[2], vreg[2];
    #pragma unroll
    for (int q = 0; q < 2; ++q) {
        int e = q * 256 + tid, kv = e >> 3, c0 = (e & 7) * 8;
        kreg[q] = *(const bf16x8*)&kb[(size_t)(kt0 * 64 + kv) * kstride + c0];
        vreg[q] = *(const bf16x8*)&vtb[(size_t)kv * L + kt0 * 64 + c0];
    }
    for (int kt = kt0; kt < kt1; ++kt) {
        __syncthreads();   // previous tile's LDS reads complete
        #pragma unroll
        for (int q = 0; q < 2; ++q) {
            int e = q * 256 + tid, kv = e >> 3, c0 = (e & 7) * 8;
            int sw = c0 ^ ((kv & 7) << 3);
            *(bf16x8*)&Ks[kv][sw] = kreg[q];
            *(bf16x8*)&Vs[kv][sw] = vreg[q];
        }
        __syncthreads();
        if (kt + 1 < kt1) {   // issue next tile's loads; latency hidden under compute
            #pragma unroll
            for (int q = 0; q < 2; ++q) {
                int e = q * 256 + tid, kv = e >> 3, c0 = (e & 7) * 8;
                kreg[q] = *(const bf16x8*)&kb[(size_t)((kt + 1) * 64 + kv) * kstride + c0];
                vreg[q] = *(const bf16x8*)&vtb[(size_t)kv * L + (kt + 1) * 64 + c0];
            }
        }
        f32x4 s[4];
        #pragma unroll
        for (int n = 0; n < 4; ++n) {
            bf16x8 k0 = *(const bf16x8*)&Ks[n * 16 + r16][(g * 8) ^ swmask];
            bf16x8 k1 = *(const bf16x8*)&Ks[n * 16 + r16][(g * 8 + 32) ^ swmask];
            f32x4 z = {};
            z = __builtin_amdgcn_mfma_f32_16x16x32_bf16(qv0, k0, z, 0, 0, 0);
            s[n] = __builtin_amdgcn_mfma_f32_16x16x32_bf16(qv1, k1, z, 0, 0, 0);
        }
        #pragma unroll
        for (int n = 0; n < 4; ++n)
            #pragma unroll
            for (int r = 0; r < 4; ++r) {
                float v = s[n][r] * 0.125f;
                if (MASK) {
                    int kidx = kt * 64 + n * 16 + r16;
                    v = (kidx < cnt) ? v : -1e30f;
                }
                s[n][r] = v;
            }
        #pragma unroll
        for (int r = 0; r < 4; ++r) {
            float rm = fmaxf(fmaxf(s[0][r], s[1][r]), fmaxf(s[2][r], s[3][r]));
            #pragma unroll
            for (int mm = 1; mm < 16; mm <<= 1) rm = fmaxf(rm, __shfl_xor(rm, mm));
            float m_new = fmaxf(m_run[r], rm);
            float rs = 0.f;
            #pragma unroll
            for (int n = 0; n < 4; ++n) { float e = __expf(s[n][r] - m_new); s[n][r] = e; rs += e; }
            #pragma unroll
            for (int mm = 1; mm < 16; mm <<= 1) rs += __shfl_xor(rs, mm);
            float factor = __expf(m_run[r] - m_new);
            l_run[r] = l_run[r] * factor + rs;
            m_run[r] = m_new;
            #pragma unroll
            for (int n = 0; n < 4; ++n) o_acc[n][r] *= factor;
        }
        #pragma unroll
        for (int n = 0; n < 4; ++n)
            #pragma unroll
            for (int r = 0; r < 4; ++r) {
                int qrow = g * 4 + r;
                Ps[wid][qrow][(n * 16 + r16) ^ ((qrow & 7) << 3)] = f2bf(s[n][r]);
            }
        bf16x8 pa0 = *(const bf16x8*)&Ps[wid][r16][(g * 8) ^ swmask];
        bf16x8 pa1 = *(const bf16x8*)&Ps[wid][r16][(g * 8 + 32) ^ swmask];
        #pragma unroll
        for (int n = 0; n < 4; ++n) {
            bf16x8 v0 = *(const bf16x8*)&Vs[n * 16 + r16][(g * 8) ^ swmask];
            bf16x8 v1 = *(const bf16x8*)&Vs[n * 16 + r16][(g * 8 + 32) ^ swmask];
            o_acc[n] = __builtin_amdgcn_mfma_f32_16x16x32_bf16(pa0, v0, o_acc[n], 0, 0, 0);
            o_acc[n] = __builtin_amdgcn_mfma_f32_16x16x32_bf16(pa1, v1, o_acc[n], 0, 0, 0);
        }
    }
    #pragma unroll
    for (int r = 0; r < 4; ++r) {
        float inv = 1.0f / l_run[r];
        int row = q0 + g * 4 + r;
        if (SPLIT) {
            size_t basec = (((size_t)cidx * B + b) * H + h) * L + row;
            #pragma unroll
            for (int n = 0; n < 4; ++n)
                PO[basec * DH + n * 16 + r16] = f2bf(o_acc[n][r] * inv);
            if (r16 == 0) { ML[basec * 2] = m_run[r]; ML[basec * 2 + 1] = l_run[r]; }
        } else {
            size_t ro = (size_t)(b * L + row) * D + h * DH;
            #pragma unroll
            for (int n = 0; n < 4; ++n)
                O[ro + n * 16 + r16] = f2bf(o_acc[n][r] * inv);
        }
    }
}

// merge 2 split-KV chunks: o = (o0*l0*w0 + o1*l1*w1) / (l0*w0 + l1*w1), wi = exp(mi - M)
__global__ __launch_bounds__(256) void attn_merge(const unsigned short* __restrict__ PO,
                                                  const float* __restrict__ ML,
                                                  unsigned short* __restrict__ O,
                                                  const int* __restrict__ counts) {
    int qt = blockIdx.x & 15, h = (blockIdx.x >> 4) & 7, b = blockIdx.x >> 7;
    if (qt * 64 > counts[b]) return;
    int tid = threadIdx.x;
    int row = qt * 64 + (tid >> 2);
    int d0 = (tid & 3) * 16;
    size_t base = (size_t)(b * H + h) * L + row;
    size_t cstride = (size_t)B * H * L;
    float m0 = ML[base * 2], l0 = ML[base * 2 + 1];
    float m1 = ML[(base + cstride) * 2], l1 = ML[(base + cstride) * 2 + 1];
    float M = fmaxf(m0, m1);
    float w0 = __expf(m0 - M) * l0, w1 = __expf(m1 - M) * l1;
    float inv = 1.0f / (w0 + w1);
    w0 *= inv; w1 *= inv;
    const bf16x8* p0 = (const bf16x8*)&PO[base * DH + d0];
    const bf16x8* p1 = (const bf16x8*)&PO[(base + cstride) * DH + d0];
    unsigned short* op = O + ((size_t)(b * L + row) * D + h * DH + d0);
    #pragma unroll
    for (int q = 0; q < 2; ++q) {
        bf16x8 a = p0[q], c = p1[q], r;
        #pragma unroll
        for (int j = 0; j < 8; ++j)
            r[j] = (short)f2bf(bf2f((unsigned short)a[j]) * w0 + bf2f((unsigned short)c[j]) * w1);
        *(bf16x8*)(op + q * 8) = r;
    }
}

extern "C" void kernel_launch(void* const* d_in, const int* in_sizes, int n_in,
                              void* d_out, int out_size, void* d_ws, size_t ws_size,
                              hipStream_t stream) {
    const float* hid = (const float*)d_in[0];
    const float* img = (const float*)d_in[1];
    const int* seq   = (const int*)d_in[12];
    const int* pSOC  = (const int*)d_in[13];
    const int* pEOS  = (const int*)d_in[14];
    float* out0 = (float*)d_out;            // hid_new
    float* out1 = out0 + (size_t)BLD;       // x

    char* w = (char*)d_ws;
    int* pos    = (int*)w;
    int* counts = pos + B * L;
    size_t off = 64 * 1024;
    float* x = (float*)(w + off);                     off += (size_t)BLD * 4;           // 16MB
    unsigned short* qkv = (unsigned short*)(w + off); off += (size_t)M_TOT * 3 * D * 2; // 24MB
    unsigned short* o   = (unsigned short*)(w + off); off += (size_t)BLD * 2;           // 8MB
    unsigned short* vt  = (unsigned short*)(w + off); off += (size_t)BLD * 2;           // 8MB
    unsigned short* xn  = (unsigned short*)(w + off); off += (size_t)BLD * 2;           // 8MB
    unsigned short* imgb= (unsigned short*)(w + off); off += (size_t)BLD * 2;           // 8MB
    unsigned short* Wqt  = (unsigned short*)(w + off); off += (size_t)D * D * 2; // Wq,Wk,Wv contiguous
    unsigned short* Wkt  = (unsigned short*)(w + off); off += (size_t)D * D * 2;
    unsigned short* Wvt  = (unsigned short*)(w + off); off += (size_t)D * D * 2;
    unsigned short* Wot  = (unsigned short*)(w + off); off += (size_t)D * D * 2;
    unsigned short* Wq2t = (unsigned short*)(w + off); off += (size_t)D * D * 2;
    unsigned short* Wk2t = (unsigned short*)(w + off); off += (size_t)D * D * 2; // Wk2,Wv2 contiguous
    unsigned short* Wv2t = (unsigned short*)(w + off); off += (size_t)D * D * 2;
    unsigned short* Wo2t = (unsigned short*)(w + off); off += (size_t)D * D * 2;
    unsigned short* W1t  = (unsigned short*)(w + off); off += (size_t)D * DF * 2;
    unsigned short* W2t  = (unsigned short*)(w + off); off += (size_t)D * DF * 2;
    float* ml            = (float*)(w + off);          off += (size_t)2 * B * H * L * 2 * 4; // 1MB
    unsigned short* q2  = qkv;
    unsigned short* kv2 = qkv + (size_t)M_TOT * D;
    unsigned short* mid = qkv;
    unsigned short* po  = xn;   // 16MB over xn+imgb (both dead during cross-attn)

    pos_kernel<<<B, 1024, 0, stream>>>(seq, pSOC, pEOS, pos, counts);
    WtArgs wa;
    wa.src[0] = (const float*)d_in[2];  wa.dst[0] = Wqt;
    wa.src[1] = (const float*)d_in[3];  wa.dst[1] = Wkt;
    wa.src[2] = (const float*)d_in[4];  wa.dst[2] = Wvt;
    wa.src[3] = (const float*)d_in[5];  wa.dst[3] = Wot;
    wa.src[4] = (const float*)d_in[6];  wa.dst[4] = Wq2t;
    wa.src[5] = (const float*)d_in[7];  wa.dst[5] = Wk2t;
    wa.src[6] = (const float*)d_in[8];  wa.dst[6] = Wv2t;
    wa.src[7] = (const float*)d_in[9];  wa.dst[7] = Wo2t;
    wa.src[8] = (const float*)d_in[10]; wa.dst[8] = W1t;
    wa.src[9] = (const float*)d_in[11]; wa.dst[9] = W2t;
    wtrans_all<<<4096, dim3(32, 8), 0, stream>>>(wa);
    cvt_kernel<<<(BLD / 4 + 255) / 256, 256, 0, stream>>>(img, imgb, BLD / 4);

    gather_kernel<<<B * L, 128, 0, stream>>>(hid, pos, counts, x);

    int attn_grid = B * H * (L / 64);
    dim3 gDD(4, 64), gQKV(12, 64), gKV2(8, 64), gF1(16, 64);
    // block 1: masked self-attention (fused QKV)
    ln_kernel<<<M_TOT, 256, 0, stream>>>(x, xn, counts);
    gemm_mfma<3, true><<<gQKV, 256, 0, stream>>>(xn, Wqt, qkv, M_TOT, D, 3 * D, counts);
    vtrans_kernel<true><<<attn_grid, 256, 0, stream>>>(qkv + 2 * D, 3 * D, vt, counts);
    attn_mfma<true, false><<<attn_grid, 256, 0, stream>>>(qkv, 3 * D, qkv + D, 3 * D, vt, o, po, ml, counts);
    gemm_mfma<1, true><<<gDD, 256, 0, stream>>>(o, Wot, x, M_TOT, D, D, counts);
    // block 2: cross-attention to img (fused KV), split-KV 2 chunks
    ln_kernel<<<M_TOT, 256, 0, stream>>>(x, xn, counts);
    gemm_mfma<3, false><<<gKV2, 256, 0, stream>>>(imgb, Wk2t, kv2, M_TOT, D, 2 * D, counts);
    gemm_mfma<3, true><<<gDD, 256, 0, stream>>>(xn, Wq2t, q2, M_TOT, D, D, counts);
    vtrans_kernel<false><<<attn_grid, 256, 0, stream>>>(kv2 + D, 2 * D, vt, counts);
    attn_mfma<false, true><<<attn_grid * 2, 256, 0, stream>>>(q2, D, kv2, 2 * D, vt, o, po, ml, counts);
    attn_merge<<<attn_grid, 256, 0, stream>>>(po, ml, o, counts);
    gemm_mfma<1, true><<<gDD, 256, 0, stream>>>(o, Wo2t, x, M_TOT, D, D, counts);
    // FFN
    ln_kernel<<<M_TOT, 256, 0, stream>>>(x, xn, counts);
    gemm_mfma<2, true><<<gF1, 256, 0, stream>>>(xn, W1t, mid, M_TOT, D, DF, counts);
    gemm_mfma<1, true><<<gDD, 256, 0, stream>>>(mid, W2t, x, M_TOT, DF, D, counts);
    // pad-row broadcast, then outputs
    bcast_kernel<<<B * L, 128, 0, stream>>>(x, counts);
    hipMemcpyAsync(out0, hid, (size_t)BLD * sizeof(float), hipMemcpyDeviceToDevice, stream);
    hipMemcpyAsync(out1, x, (size_t)BLD * sizeof(float), hipMemcpyDeviceToDevice, stream);
    scatter_kernel<<<B * L, 128, 0, stream>>>(x, pos, counts, out0);
}

// Round 8
// 246.455 us; speedup vs baseline: 5.1493x; 1.2410x over previous
//
#include <hip/hip_runtime.h>
#include <cmath>

#define B 8
#define L 1024
#define D 512
#define H 8
#define DH 64
#define DF 2048
#define BLD (B*L*D)
#define M_TOT (B*L)

typedef __attribute__((ext_vector_type(8))) short bf16x8;
typedef __attribute__((ext_vector_type(4))) float f32x4;
typedef const __attribute__((address_space(1))) void* gas_ptr;
typedef __attribute__((address_space(3))) void* las_ptr;

__device__ __forceinline__ unsigned short f2bf(float f) {
    unsigned int u = __builtin_bit_cast(unsigned int, f);
    u += 0x7FFFu + ((u >> 16) & 1u);
    return (unsigned short)(u >> 16);
}
__device__ __forceinline__ float bf2f(unsigned short s) {
    return __builtin_bit_cast(float, ((unsigned int)s) << 16);
}

__device__ __forceinline__ float gelu_f(float x) {
    float x3 = x * x * x;
    return 0.5f * x * (1.0f + tanhf(0.7978845608028654f * (x + 0.044715f * x3)));
}

// parallel compaction scan: 1 block/batch, 1024 threads
__global__ __launch_bounds__(1024) void pos_kernel(const int* __restrict__ seq,
                                                   const int* __restrict__ pSOC,
                                                   const int* __restrict__ pEOS,
                                                   int* __restrict__ pos,
                                                   int* __restrict__ counts) {
    int b = blockIdx.x, t = threadIdx.x;
    int lane = t & 63, w = t >> 6;
    int sv = seq[b * L + t];
    int SOC = pSOC[0], EOS = pEOS[0];
    int eosf = (sv == EOS) ? 1 : 0;
    unsigned long long em = __ballot(eosf);
    int eexcl = __popcll(em & ((1ull << lane) - 1ull));
    __shared__ int ewt[16], swt[16];
    if (lane == 63) ewt[w] = eexcl + eosf;
    __syncthreads();
    int ebase = 0;
    for (int i = 0; i < w; ++i) ebase += ewt[i];
    int ecum_incl = ebase + eexcl + eosf;
    int socf = (sv == SOC && ecum_incl == 0) ? 1 : 0;
    unsigned long long sm = __ballot(socf);
    int sexcl = __popcll(sm & ((1ull << lane) - 1ull));
    if (lane == 63) swt[w] = sexcl + socf;
    __syncthreads();
    int sbase = 0, stot = 0;
    for (int i = 0; i < 16; ++i) { int v = swt[i]; if (i < w) sbase += v; stot += v; }
    if (socf) pos[b * L + sbase + sexcl] = t;
    if (t == 0) counts[b] = stot;
}

__global__ void gather_kernel(const float* __restrict__ hid, const int* __restrict__ pos,
                              const int* __restrict__ counts, float* __restrict__ x) {
    int j = blockIdx.x % L, b = blockIdx.x / L;
    int t = threadIdx.x;
    float4 val = make_float4(0.f, 0.f, 0.f, 0.f);
    if (j < counts[b]) {
        const float4* src = (const float4*)(hid + (size_t)(b * L + pos[b * L + j]) * D);
        val = src[t];
    }
    ((float4*)(x + (size_t)(b * L + j) * D))[t] = val;
}

__global__ void scatter_kernel(const float* __restrict__ x, const int* __restrict__ pos,
                               const int* __restrict__ counts, float* __restrict__ out0) {
    int j = blockIdx.x % L, b = blockIdx.x / L;
    if (j >= counts[b]) return;
    int t = threadIdx.x;
    const float4* src = (const float4*)(x + (size_t)(b * L + j) * D);
    float4* dst = (float4*)(out0 + (size_t)(b * L + pos[b * L + j]) * D);
    dst[t] = src[t];
}

// all rows j > cnt get a copy of pad-representative row cnt
__global__ void bcast_kernel(float* __restrict__ x, const int* __restrict__ counts) {
    int j = blockIdx.x % L, b = blockIdx.x / L;
    int cnt = counts[b];
    if (j <= cnt) return;
    int t = threadIdx.x; // 128
    const float4* src = (const float4*)(x + (size_t)(b * L + cnt) * D);
    float4* dst = (float4*)(x + (size_t)(b * L + j) * D);
    dst[t] = src[t];
}

// LayerNorm, f32 in -> bf16 out; skips rows in fully-padding 128-blocks
__global__ void ln_kernel(const float* __restrict__ X, unsigned short* __restrict__ Y,
                          const int* __restrict__ counts) {
    int row = blockIdx.x;
    if ((row & 1023 & ~127) > counts[row >> 10]) return;
    int t = threadIdx.x; // 256
    const float* xr = X + (size_t)row * D;
    float a = xr[t], b2 = xr[t + 256];
    float s = a + b2, sq = a * a + b2 * b2;
    for (int m = 1; m < 64; m <<= 1) {
        s += __shfl_xor(s, m);
        sq += __shfl_xor(sq, m);
    }
    __shared__ float ws[4], wq[4];
    int wid = t >> 6;
    if ((t & 63) == 0) { ws[wid] = s; wq[wid] = sq; }
    __syncthreads();
    s = ws[0] + ws[1] + ws[2] + ws[3];
    sq = wq[0] + wq[1] + wq[2] + wq[3];
    float mu = s * (1.0f / D);
    float var = sq * (1.0f / D) - mu * mu;
    float rs = rsqrtf(var + 1e-5f);
    Y[(size_t)row * D + t] = f2bf((a - mu) * rs);
    Y[(size_t)row * D + t + 256] = f2bf((b2 - mu) * rs);
}

// fused one-time weight transpose: all 10 weights in one launch
struct WtArgs {
    const float* src[10];
    unsigned short* dst[10];
};
__global__ void wtrans_all(WtArgs a) {
    __shared__ float t[32][33];
    int bid = blockIdx.x;
    int w, tn, tk, K, N;
    if (bid < 2048)      { w = bid >> 8;      int t2 = bid & 255;  N = 512;  K = 512;  tn = t2 & 15; tk = t2 >> 4; }
    else if (bid < 3072) { w = 8;             int t2 = bid - 2048; N = 2048; K = 512;  tn = t2 & 63; tk = t2 >> 6; }
    else                 { w = 9;             int t2 = bid - 3072; N = 512;  K = 2048; tn = t2 & 15; tk = t2 >> 4; }
    const float* W = a.src[w];
    unsigned short* Wt = a.dst[w];
    int k0 = tk * 32, n0 = tn * 32;
    int tx = threadIdx.x, ty = threadIdx.y; // (32,8)
    for (int i = ty; i < 32; i += 8)
        t[i][tx] = W[(size_t)(k0 + i) * N + n0 + tx];
    __syncthreads();
    for (int i = ty; i < 32; i += 8)
        Wt[(size_t)(n0 + i) * K + k0 + tx] = f2bf(t[tx][i]);
}

__global__ void cvt_kernel(const float* __restrict__ X, unsigned short* __restrict__ Y, int n4) {
    int i = blockIdx.x * blockDim.x + threadIdx.x;
    if (i >= n4) return;
    float4 f = ((const float4*)X)[i];
    ushort4 u;
    u.x = f2bf(f.x); u.y = f2bf(f.y); u.z = f2bf(f.z); u.w = f2bf(f.w);
    ((ushort4*)Y)[i] = u;
}

// V rows (stride vstride, head h at col h*DH) -> Vt [B,H,DH,L]
template<bool SKIP>
__global__ __launch_bounds__(256) void vtrans_kernel(const unsigned short* __restrict__ V,
                                                     int vstride,
                                                     unsigned short* __restrict__ Vt,
                                                     const int* __restrict__ counts) {
    __shared__ unsigned short t[64][72];
    int l0 = (blockIdx.x & 15) * 64;
    int h = (blockIdx.x >> 4) & 7;
    int b = blockIdx.x >> 7;
    if (SKIP && l0 > counts[b]) return;
    int tid = threadIdx.x; // 256
    const unsigned short* vb = V + (size_t)b * L * vstride + h * DH;
    for (int e = tid; e < 512; e += 256) {
        int i = e >> 3, d0 = (e & 7) * 8;
        *(bf16x8*)&t[i][d0] = *(const bf16x8*)&vb[(size_t)(l0 + i) * vstride + d0];
    }
    __syncthreads();
    for (int e = tid; e < 512; e += 256) {
        int d = e & 63, i0 = (e >> 6) * 8;
        bf16x8 val;
        #pragma unroll
        for (int j = 0; j < 8; ++j) val[j] = t[i0 + j][d];
        *(bf16x8*)&Vt[((size_t)((b * H + h) * DH + d)) * L + l0 + i0] = val;
    }
}

// C[M,N] = A[M,K] @ W[K,N]; A bf16 row-major, Wt = W^T bf16 [N][K].
// 64x128 tile, BK=64, triple-buffered global_load_lds pipeline with counted vmcnt,
// both-sides XOR swizzle (chunk ^= row&7) for conflict-free b128 frag reads.
// Split-K via blockIdx.z (S chunks); MODE 1 uses atomicAdd when S>1.
// MODE 1: f32 accumulate; 2: gelu->bf16; 3: bf16 store.
template<int MODE, bool SKIP, int S>
__global__ __launch_bounds__(256) void gemm_mfma(const unsigned short* __restrict__ A,
                                                 const unsigned short* __restrict__ Wt,
                                                 void* __restrict__ Cv,
                                                 int K, int N,
                                                 const int* __restrict__ counts) {
    int m0 = blockIdx.y * 64, n0 = blockIdx.x * 128;
    if (SKIP && (m0 & 1023) > counts[m0 >> 10]) return;
    int Kc = K / S;
    int kbeg = blockIdx.z * Kc;
    int nk = Kc / 64;
    __shared__ __align__(16) unsigned short As[3][64 * 64];
    __shared__ __align__(16) unsigned short Bs[3][128 * 64];
    int tid = threadIdx.x, lane = tid & 63, wid = tid >> 6;
    int wm = (wid >> 1) * 32, wn = (wid & 1) * 64;
    int r16 = lane & 15, g = lane >> 4;
    f32x4 acc[2][4] = {};

#define STAGE(bufi, kt) do {                                                          \
    int kk_ = kbeg + (kt) * 64;                                                       \
    _Pragma("unroll")                                                                 \
    for (int q_ = 0; q_ < 2; ++q_) {                                                  \
        int e_ = q_ * 256 + tid;                                                      \
        int r_ = e_ >> 3, c_ = ((e_ & 7) ^ (r_ & 7)) * 8;                             \
        __builtin_amdgcn_global_load_lds((gas_ptr)(A + (size_t)(m0 + r_) * K + kk_ + c_), \
                                         (las_ptr)(&As[bufi][0] + (size_t)e_ * 8), 16, 0, 0); \
    }                                                                                 \
    _Pragma("unroll")                                                                 \
    for (int q_ = 0; q_ < 4; ++q_) {                                                  \
        int e_ = q_ * 256 + tid;                                                      \
        int r_ = e_ >> 3, c_ = ((e_ & 7) ^ (r_ & 7)) * 8;                             \
        __builtin_amdgcn_global_load_lds((gas_ptr)(Wt + (size_t)(n0 + r_) * K + kk_ + c_), \
                                         (las_ptr)(&Bs[bufi][0] + (size_t)e_ * 8), 16, 0, 0); \
    }                                                                                 \
} while (0)

    STAGE(0, 0);
    if (nk > 1) STAGE(1, 1);
    asm volatile("s_waitcnt vmcnt(6)" ::: "memory");
    __builtin_amdgcn_s_barrier();
    __builtin_amdgcn_sched_barrier(0);
    int swz = (r16 & 7) * 8;
    for (int kt = 0; kt < nk; ++kt) {
        int cur = kt % 3;
        if (kt + 2 < nk) STAGE((kt + 2) % 3, kt + 2);
        #pragma unroll
        for (int ks = 0; ks < 2; ++ks) {
            bf16x8 av[2], bv[4];
            #pragma unroll
            for (int m = 0; m < 2; ++m)
                av[m] = *(const bf16x8*)&As[cur][(wm + m * 16 + r16) * 64 + ((ks * 32 + g * 8) ^ swz)];
            #pragma unroll
            for (int n = 0; n < 4; ++n)
                bv[n] = *(const bf16x8*)&Bs[cur][(wn + n * 16 + r16) * 64 + ((ks * 32 + g * 8) ^ swz)];
            #pragma unroll
            for (int m = 0; m < 2; ++m)
                #pragma unroll
                for (int n = 0; n < 4; ++n)
                    acc[m][n] = __builtin_amdgcn_mfma_f32_16x16x32_bf16(av[m], bv[n], acc[m][n], 0, 0, 0);
        }
        if (kt + 2 < nk) asm volatile("s_waitcnt vmcnt(6)" ::: "memory");
        else             asm volatile("s_waitcnt vmcnt(0)" ::: "memory");
        __builtin_amdgcn_s_barrier();
        __builtin_amdgcn_sched_barrier(0);
    }
#undef STAGE
    #pragma unroll
    for (int m = 0; m < 2; ++m)
        #pragma unroll
        for (int n = 0; n < 4; ++n)
            #pragma unroll
            for (int r = 0; r < 4; ++r) {
                int grow = m0 + wm + m * 16 + g * 4 + r;
                int gcol = n0 + wn + n * 16 + r16;
                size_t off = (size_t)grow * N + gcol;
                float vv = acc[m][n][r];
                if (MODE == 1) {
                    if (S > 1) atomicAdd((float*)Cv + off, vv);
                    else ((float*)Cv)[off] += vv;
                }
                else if (MODE == 2) ((unsigned short*)Cv)[off] = f2bf(gelu_f(vv));
                else ((unsigned short*)Cv)[off] = f2bf(vv);
            }
}

// MFMA flash attention, XOR-swizzled LDS, register K/V prefetch,
// XCD-chunked grid swizzle, optional split-KV (2 chunks of 8 tiles).
template<bool MASK, bool SPLIT>
__global__ __launch_bounds__(256) void attn_mfma(const unsigned short* __restrict__ Q, int qstride,
                                                 const unsigned short* __restrict__ Kb, int kstride,
                                                 const unsigned short* __restrict__ Vt,
                                                 unsigned short* __restrict__ O,
                                                 unsigned short* __restrict__ PO,
                                                 float* __restrict__ ML,
                                                 const int* __restrict__ counts) {
    int nwg = gridDim.x;
    int wg = (blockIdx.x & 7) * (nwg >> 3) + (blockIdx.x >> 3);
    int qt = wg & 15;
    int cidx = SPLIT ? ((wg >> 4) & 1) : 0;
    int h = SPLIT ? ((wg >> 5) & 7) : ((wg >> 4) & 7);
    int b = SPLIT ? (wg >> 8) : (wg >> 7);
    int cntb = counts[b];
    if (qt * 64 > cntb) return;
    __shared__ __align__(16) unsigned short Ks[64][64];
    __shared__ __align__(16) unsigned short Vs[64][64];
    __shared__ __align__(16) unsigned short Ps[4][16][64];
    int tid = threadIdx.x, lane = tid & 63, wid = tid >> 6;
    int q0 = qt * 64 + wid * 16;
    int cnt = MASK ? cntb : L;
    int nt = MASK ? min(16, max(1, (cnt + 63) >> 6)) : 16;
    int kt0 = SPLIT ? cidx * 8 : 0;
    int kt1 = SPLIT ? (cidx * 8 + 8) : nt;
    int r16 = lane & 15, g = lane >> 4;
    int swmask = (r16 & 7) << 3;
    const unsigned short* qbase = Q + ((size_t)(b * L + q0 + r16) * qstride + h * DH + g * 8);
    bf16x8 qv0 = *(const bf16x8*)(qbase);
    bf16x8 qv1 = *(const bf16x8*)(qbase + 32);
    f32x4 o_acc[4] = {};
    float m_run[4], l_run[4];
    #pragma unroll
    for (int r = 0; r < 4; ++r) { m_run[r] = -1e30f; l_run[r] = 0.f; }
    const unsigned short* kb = Kb + (size_t)b * L * kstride + h * DH;
    const unsigned short* vtb = Vt + (size_t)(b * H + h) * DH * L;
    bf16x8 kreg[2], vreg[2];
    #pragma unroll
    for (int q = 0; q < 2; ++q) {
        int e = q * 256 + tid, kv = e >> 3, c0 = (e & 7) * 8;
        kreg[q] = *(const bf16x8*)&kb[(size_t)(kt0 * 64 + kv) * kstride + c0];
        vreg[q] = *(const bf16x8*)&vtb[(size_t)kv * L + kt0 * 64 + c0];
    }
    for (int kt = kt0; kt < kt1; ++kt) {
        __syncthreads();
        #pragma unroll
        for (int q = 0; q < 2; ++q) {
            int e = q * 256 + tid, kv = e >> 3, c0 = (e & 7) * 8;
            int sw = c0 ^ ((kv & 7) << 3);
            *(bf16x8*)&Ks[kv][sw] = kreg[q];
            *(bf16x8*)&Vs[kv][sw] = vreg[q];
        }
        __syncthreads();
        if (kt + 1 < kt1) {
            #pragma unroll
            for (int q = 0; q < 2; ++q) {
                int e = q * 256 + tid, kv = e >> 3, c0 = (e & 7) * 8;
                kreg[q] = *(const bf16x8*)&kb[(size_t)((kt + 1) * 64 + kv) * kstride + c0];
                vreg[q] = *(const bf16x8*)&vtb[(size_t)kv * L + (kt + 1) * 64 + c0];
            }
        }
        f32x4 s[4];
        #pragma unroll
        for (int n = 0; n < 4; ++n) {
            bf16x8 k0 = *(const bf16x8*)&Ks[n * 16 + r16][(g * 8) ^ swmask];
            bf16x8 k1 = *(const bf16x8*)&Ks[n * 16 + r16][(g * 8 + 32) ^ swmask];
            f32x4 z = {};
            z = __builtin_amdgcn_mfma_f32_16x16x32_bf16(qv0, k0, z, 0, 0, 0);
            s[n] = __builtin_amdgcn_mfma_f32_16x16x32_bf16(qv1, k1, z, 0, 0, 0);
        }
        #pragma unroll
        for (int n = 0; n < 4; ++n)
            #pragma unroll
            for (int r = 0; r < 4; ++r) {
                float v = s[n][r] * 0.125f;
                if (MASK) {
                    int kidx = kt * 64 + n * 16 + r16;
                    v = (kidx < cnt) ? v : -1e30f;
                }
                s[n][r] = v;
            }
        #pragma unroll
        for (int r = 0; r < 4; ++r) {
            float rm = fmaxf(fmaxf(s[0][r], s[1][r]), fmaxf(s[2][r], s[3][r]));
            #pragma unroll
            for (int mm = 1; mm < 16; mm <<= 1) rm = fmaxf(rm, __shfl_xor(rm, mm));
            float m_new = fmaxf(m_run[r], rm);
            float rs = 0.f;
            #pragma unroll
            for (int n = 0; n < 4; ++n) { float e = __expf(s[n][r] - m_new); s[n][r] = e; rs += e; }
            #pragma unroll
            for (int mm = 1; mm < 16; mm <<= 1) rs += __shfl_xor(rs, mm);
            float factor = __expf(m_run[r] - m_new);
            l_run[r] = l_run[r] * factor + rs;
            m_run[r] = m_new;
            #pragma unroll
            for (int n = 0; n < 4; ++n) o_acc[n][r] *= factor;
        }
        #pragma unroll
        for (int n = 0; n < 4; ++n)
            #pragma unroll
            for (int r = 0; r < 4; ++r) {
                int qrow = g * 4 + r;
                Ps[wid][qrow][(n * 16 + r16) ^ ((qrow & 7) << 3)] = f2bf(s[n][r]);
            }
        bf16x8 pa0 = *(const bf16x8*)&Ps[wid][r16][(g * 8) ^ swmask];
        bf16x8 pa1 = *(const bf16x8*)&Ps[wid][r16][(g * 8 + 32) ^ swmask];
        #pragma unroll
        for (int n = 0; n < 4; ++n) {
            bf16x8 v0 = *(const bf16x8*)&Vs[n * 16 + r16][(g * 8) ^ swmask];
            bf16x8 v1 = *(const bf16x8*)&Vs[n * 16 + r16][(g * 8 + 32) ^ swmask];
            o_acc[n] = __builtin_amdgcn_mfma_f32_16x16x32_bf16(pa0, v0, o_acc[n], 0, 0, 0);
            o_acc[n] = __builtin_amdgcn_mfma_f32_16x16x32_bf16(pa1, v1, o_acc[n], 0, 0, 0);
        }
    }
    #pragma unroll
    for (int r = 0; r < 4; ++r) {
        float inv = 1.0f / l_run[r];
        int row = q0 + g * 4 + r;
        if (SPLIT) {
            size_t basec = (((size_t)cidx * B + b) * H + h) * L + row;
            #pragma unroll
            for (int n = 0; n < 4; ++n)
                PO[basec * DH + n * 16 + r16] = f2bf(o_acc[n][r] * inv);
            if (r16 == 0) { ML[basec * 2] = m_run[r]; ML[basec * 2 + 1] = l_run[r]; }
        } else {
            size_t ro = (size_t)(b * L + row) * D + h * DH;
            #pragma unroll
            for (int n = 0; n < 4; ++n)
                O[ro + n * 16 + r16] = f2bf(o_acc[n][r] * inv);
        }
    }
}

// merge 2 split-KV chunks
__global__ __launch_bounds__(256) void attn_merge(const unsigned short* __restrict__ PO,
                                                  const float* __restrict__ ML,
                                                  unsigned short* __restrict__ O,
                                                  const int* __restrict__ counts) {
    int qt = blockIdx.x & 15, h = (blockIdx.x >> 4) & 7, b = blockIdx.x >> 7;
    if (qt * 64 > counts[b]) return;
    int tid = threadIdx.x;
    int row = qt * 64 + (tid >> 2);
    int d0 = (tid & 3) * 16;
    size_t base = (size_t)(b * H + h) * L + row;
    size_t cstride = (size_t)B * H * L;
    float m0 = ML[base * 2], l0 = ML[base * 2 + 1];
    float m1 = ML[(base + cstride) * 2], l1 = ML[(base + cstride) * 2 + 1];
    float M = fmaxf(m0, m1);
    float w0 = __expf(m0 - M) * l0, w1 = __expf(m1 - M) * l1;
    float inv = 1.0f / (w0 + w1);
    w0 *= inv; w1 *= inv;
    const bf16x8* p0 = (const bf16x8*)&PO[base * DH + d0];
    const bf16x8* p1 = (const bf16x8*)&PO[(base + cstride) * DH + d0];
    unsigned short* op = O + ((size_t)(b * L + row) * D + h * DH + d0);
    #pragma unroll
    for (int q = 0; q < 2; ++q) {
        bf16x8 a = p0[q], c = p1[q], r;
        #pragma unroll
        for (int j = 0; j < 8; ++j)
            r[j] = (short)f2bf(bf2f((unsigned short)a[j]) * w0 + bf2f((unsigned short)c[j]) * w1);
        *(bf16x8*)(op + q * 8) = r;
    }
}

extern "C" void kernel_launch(void* const* d_in, const int* in_sizes, int n_in,
                              void* d_out, int out_size, void* d_ws, size_t ws_size,
                              hipStream_t stream) {
    const float* hid = (const float*)d_in[0];
    const float* img = (const float*)d_in[1];
    const int* seq   = (const int*)d_in[12];
    const int* pSOC  = (const int*)d_in[13];
    const int* pEOS  = (const int*)d_in[14];
    float* out0 = (float*)d_out;            // hid_new
    float* out1 = out0 + (size_t)BLD;       // x

    char* w = (char*)d_ws;
    int* pos    = (int*)w;
    int* counts = pos + B * L;
    size_t off = 64 * 1024;
    float* x = (float*)(w + off);                     off += (size_t)BLD * 4;
    unsigned short* qkv = (unsigned short*)(w + off); off += (size_t)M_TOT * 3 * D * 2;
    unsigned short* o   = (unsigned short*)(w + off); off += (size_t)BLD * 2;
    unsigned short* vt  = (unsigned short*)(w + off); off += (size_t)BLD * 2;
    unsigned short* xn  = (unsigned short*)(w + off); off += (size_t)BLD * 2;
    unsigned short* imgb= (unsigned short*)(w + off); off += (size_t)BLD * 2;
    unsigned short* Wqt  = (unsigned short*)(w + off); off += (size_t)D * D * 2; // Wq,Wk,Wv contiguous
    unsigned short* Wkt  = (unsigned short*)(w + off); off += (size_t)D * D * 2;
    unsigned short* Wvt  = (unsigned short*)(w + off); off += (size_t)D * D * 2;
    unsigned short* Wot  = (unsigned short*)(w + off); off += (size_t)D * D * 2;
    unsigned short* Wq2t = (unsigned short*)(w + off); off += (size_t)D * D * 2;
    unsigned short* Wk2t = (unsigned short*)(w + off); off += (size_t)D * D * 2; // Wk2,Wv2 contiguous
    unsigned short* Wv2t = (unsigned short*)(w + off); off += (size_t)D * D * 2;
    unsigned short* Wo2t = (unsigned short*)(w + off); off += (size_t)D * D * 2;
    unsigned short* W1t  = (unsigned short*)(w + off); off += (size_t)D * DF * 2;
    unsigned short* W2t  = (unsigned short*)(w + off); off += (size_t)D * DF * 2;
    float* ml            = (float*)(w + off);          off += (size_t)2 * B * H * L * 2 * 4;
    unsigned short* q2  = qkv;
    unsigned short* kv2 = qkv + (size_t)M_TOT * D;
    unsigned short* mid = qkv;
    unsigned short* po  = xn;   // 16MB over xn+imgb (both dead during cross-attn)

    pos_kernel<<<B, 1024, 0, stream>>>(seq, pSOC, pEOS, pos, counts);
    WtArgs wa;
    wa.src[0] = (const float*)d_in[2];  wa.dst[0] = Wqt;
    wa.src[1] = (const float*)d_in[3];  wa.dst[1] = Wkt;
    wa.src[2] = (const float*)d_in[4];  wa.dst[2] = Wvt;
    wa.src[3] = (const float*)d_in[5];  wa.dst[3] = Wot;
    wa.src[4] = (const float*)d_in[6];  wa.dst[4] = Wq2t;
    wa.src[5] = (const float*)d_in[7];  wa.dst[5] = Wk2t;
    wa.src[6] = (const float*)d_in[8];  wa.dst[6] = Wv2t;
    wa.src[7] = (const float*)d_in[9];  wa.dst[7] = Wo2t;
    wa.src[8] = (const float*)d_in[10]; wa.dst[8] = W1t;
    wa.src[9] = (const float*)d_in[11]; wa.dst[9] = W2t;
    wtrans_all<<<4096, dim3(32, 8), 0, stream>>>(wa);
    cvt_kernel<<<(BLD / 4 + 255) / 256, 256, 0, stream>>>(img, imgb, BLD / 4);

    gather_kernel<<<B * L, 128, 0, stream>>>(hid, pos, counts, x);

    int attn_grid = B * H * (L / 64);
    // block 1: masked self-attention (fused QKV)
    ln_kernel<<<M_TOT, 256, 0, stream>>>(x, xn, counts);
    gemm_mfma<3, true, 1><<<dim3(12, 128, 1), 256, 0, stream>>>(xn, Wqt, qkv, D, 3 * D, counts);
    vtrans_kernel<true><<<attn_grid, 256, 0, stream>>>(qkv + 2 * D, 3 * D, vt, counts);
    attn_mfma<true, false><<<attn_grid, 256, 0, stream>>>(qkv, 3 * D, qkv + D, 3 * D, vt, o, po, ml, counts);
    gemm_mfma<1, true, 4><<<dim3(4, 128, 4), 256, 0, stream>>>(o, Wot, x, D, D, counts);
    // block 2: cross-attention to img (fused KV), split-KV 2 chunks
    ln_kernel<<<M_TOT, 256, 0, stream>>>(x, xn, counts);
    gemm_mfma<3, false, 1><<<dim3(8, 128, 1), 256, 0, stream>>>(imgb, Wk2t, kv2, D, 2 * D, counts);
    gemm_mfma<3, true, 1><<<dim3(4, 128, 1), 256, 0, stream>>>(xn, Wq2t, q2, D, D, counts);
    vtrans_kernel<false><<<attn_grid, 256, 0, stream>>>(kv2 + D, 2 * D, vt, counts);
    attn_mfma<false, true><<<attn_grid * 2, 256, 0, stream>>>(q2, D, kv2, 2 * D, vt, o, po, ml, counts);
    attn_merge<<<attn_grid, 256, 0, stream>>>(po, ml, o, counts);
    gemm_mfma<1, true, 4><<<dim3(4, 128, 4), 256, 0, stream>>>(o, Wo2t, x, D, D, counts);
    // FFN
    ln_kernel<<<M_TOT, 256, 0, stream>>>(x, xn, counts);
    gemm_mfma<2, true, 1><<<dim3(16, 128, 1), 256, 0, stream>>>(xn, W1t, mid, D, DF, counts);
    gemm_mfma<1, true, 4><<<dim3(4, 128, 4), 256, 0, stream>>>(mid, W2t, x, DF, D, counts);
    // pad-row broadcast, then outputs
    bcast_kernel<<<B * L, 128, 0, stream>>>(x, counts);
    hipMemcpyAsync(out0, hid, (size_t)BLD * sizeof(float), hipMemcpyDeviceToDevice, stream);
    hipMemcpyAsync(out1, x, (size_t)BLD * sizeof(float), hipMemcpyDeviceToDevice, stream);
    scatter_kernel<<<B * L, 128, 0, stream>>>(x, pos, counts, out0);
}

// Round 9
// 232.836 us; speedup vs baseline: 5.4505x; 1.0585x over previous
//
#include <hip/hip_runtime.h>
#include <cmath>

#define B 8
#define L 1024
#define D 512
#define H 8
#define DH 64
#define DF 2048
#define BLD (B*L*D)
#define M_TOT (B*L)

typedef __attribute__((ext_vector_type(8))) short bf16x8;
typedef __attribute__((ext_vector_type(4))) float f32x4;
typedef const __attribute__((address_space(1))) void* gas_ptr;
typedef __attribute__((address_space(3))) void* las_ptr;

__device__ __forceinline__ unsigned short f2bf(float f) {
    unsigned int u = __builtin_bit_cast(unsigned int, f);
    u += 0x7FFFu + ((u >> 16) & 1u);
    return (unsigned short)(u >> 16);
}
__device__ __forceinline__ float bf2f(unsigned short s) {
    return __builtin_bit_cast(float, ((unsigned int)s) << 16);
}

__device__ __forceinline__ float gelu_f(float x) {
    float x3 = x * x * x;
    return 0.5f * x * (1.0f + tanhf(0.7978845608028654f * (x + 0.044715f * x3)));
}

// parallel compaction scan: 1 block/batch, 1024 threads; also emits inv (rank or -1)
__global__ __launch_bounds__(1024) void pos_kernel(const int* __restrict__ seq,
                                                   const int* __restrict__ pSOC,
                                                   const int* __restrict__ pEOS,
                                                   int* __restrict__ pos,
                                                   int* __restrict__ inv,
                                                   int* __restrict__ counts) {
    int b = blockIdx.x, t = threadIdx.x;
    int lane = t & 63, w = t >> 6;
    int sv = seq[b * L + t];
    int SOC = pSOC[0], EOS = pEOS[0];
    int eosf = (sv == EOS) ? 1 : 0;
    unsigned long long em = __ballot(eosf);
    int eexcl = __popcll(em & ((1ull << lane) - 1ull));
    __shared__ int ewt[16], swt[16];
    if (lane == 63) ewt[w] = eexcl + eosf;
    __syncthreads();
    int ebase = 0;
    for (int i = 0; i < w; ++i) ebase += ewt[i];
    int ecum_incl = ebase + eexcl + eosf;
    int socf = (sv == SOC && ecum_incl == 0) ? 1 : 0;
    unsigned long long sm = __ballot(socf);
    int sexcl = __popcll(sm & ((1ull << lane) - 1ull));
    if (lane == 63) swt[w] = sexcl + socf;
    __syncthreads();
    int sbase = 0, stot = 0;
    for (int i = 0; i < 16; ++i) { int v = swt[i]; if (i < w) sbase += v; stot += v; }
    int rank = sbase + sexcl;
    if (socf) pos[b * L + rank] = t;
    inv[b * L + t] = socf ? rank : -1;
    if (t == 0) counts[b] = stot;
}

// fused gather + LayerNorm: writes x (f32, compacted+zero-pad) and xn (bf16 LN)
__global__ void gather_ln(const float* __restrict__ hid, const int* __restrict__ pos,
                          const int* __restrict__ counts,
                          float* __restrict__ X, unsigned short* __restrict__ Y) {
    int j = blockIdx.x % L, b = blockIdx.x / L;
    int cnt = counts[b];
    if ((j & ~127) > cnt) return;    // inactive 128-block: never read downstream
    int t = threadIdx.x;             // 256
    float a = 0.f, b2 = 0.f;
    if (j < cnt) {
        const float* src = hid + (size_t)(b * L + pos[b * L + j]) * D;
        a = src[t]; b2 = src[t + 256];
    }
    size_t row = (size_t)(b * L + j);
    X[row * D + t] = a;
    X[row * D + t + 256] = b2;
    float s = a + b2, sq = a * a + b2 * b2;
    for (int m = 1; m < 64; m <<= 1) {
        s += __shfl_xor(s, m);
        sq += __shfl_xor(sq, m);
    }
    __shared__ float ws[4], wq[4];
    int wid = t >> 6;
    if ((t & 63) == 0) { ws[wid] = s; wq[wid] = sq; }
    __syncthreads();
    s = ws[0] + ws[1] + ws[2] + ws[3];
    sq = wq[0] + wq[1] + wq[2] + wq[3];
    float mu = s * (1.0f / D);
    float var = sq * (1.0f / D) - mu * mu;
    float rs = rsqrtf(var + 1e-5f);
    Y[row * D + t] = f2bf((a - mu) * rs);
    Y[row * D + t + 256] = f2bf((b2 - mu) * rs);
}

// fused epilogue: out0 = scatter(x rows by rank) else hid;  out1 = x with pad-broadcast
__global__ void epilogue_kernel(const float* __restrict__ x, const float* __restrict__ hid,
                                const int* __restrict__ inv, const int* __restrict__ counts,
                                float* __restrict__ out0, float* __restrict__ out1) {
    int l = blockIdx.x % L, b = blockIdx.x / L;
    int t = threadIdx.x;   // 128, float4
    int cnt = counts[b];
    int r = inv[b * L + l];
    const float4* s0 = (const float4*)((r >= 0 ? x + (size_t)(b * L + r) * D
                                               : hid + (size_t)(b * L + l) * D));
    ((float4*)(out0 + (size_t)(b * L + l) * D))[t] = s0[t];
    int jsrc = l < cnt ? l : cnt;
    const float4* s1 = (const float4*)(x + (size_t)(b * L + jsrc) * D);
    ((float4*)(out1 + (size_t)(b * L + l) * D))[t] = s1[t];
}

// LayerNorm, f32 in -> bf16 out; skips rows in fully-padding 128-blocks
__global__ void ln_kernel(const float* __restrict__ X, unsigned short* __restrict__ Y,
                          const int* __restrict__ counts) {
    int row = blockIdx.x;
    if ((row & 1023 & ~127) > counts[row >> 10]) return;
    int t = threadIdx.x; // 256
    const float* xr = X + (size_t)row * D;
    float a = xr[t], b2 = xr[t + 256];
    float s = a + b2, sq = a * a + b2 * b2;
    for (int m = 1; m < 64; m <<= 1) {
        s += __shfl_xor(s, m);
        sq += __shfl_xor(sq, m);
    }
    __shared__ float ws[4], wq[4];
    int wid = t >> 6;
    if ((t & 63) == 0) { ws[wid] = s; wq[wid] = sq; }
    __syncthreads();
    s = ws[0] + ws[1] + ws[2] + ws[3];
    sq = wq[0] + wq[1] + wq[2] + wq[3];
    float mu = s * (1.0f / D);
    float var = sq * (1.0f / D) - mu * mu;
    float rs = rsqrtf(var + 1e-5f);
    Y[(size_t)row * D + t] = f2bf((a - mu) * rs);
    Y[(size_t)row * D + t + 256] = f2bf((b2 - mu) * rs);
}

// fused one-time preprocessing: 10 weight transposes + img f32->bf16
struct WtArgs {
    const float* src[10];
    unsigned short* dst[10];
    const float* img;
    unsigned short* imgb;
};
__global__ void wtrans_cvt_all(WtArgs a) {
    int bid = blockIdx.x;
    int tx = threadIdx.x, ty = threadIdx.y; // (32,8)
    if (bid >= 4096) {   // cvt: 4096 blocks x 1024 floats
        int t = ty * 32 + tx;
        int i = (bid - 4096) * 256 + t;
        float4 f = ((const float4*)a.img)[i];
        ushort4 u;
        u.x = f2bf(f.x); u.y = f2bf(f.y); u.z = f2bf(f.z); u.w = f2bf(f.w);
        ((ushort4*)a.imgb)[i] = u;
        return;
    }
    __shared__ float t[32][33];
    int w, tn, tk, K, N;
    if (bid < 2048)      { w = bid >> 8;      int t2 = bid & 255;  N = 512;  K = 512;  tn = t2 & 15; tk = t2 >> 4; }
    else if (bid < 3072) { w = 8;             int t2 = bid - 2048; N = 2048; K = 512;  tn = t2 & 63; tk = t2 >> 6; }
    else                 { w = 9;             int t2 = bid - 3072; N = 512;  K = 2048; tn = t2 & 15; tk = t2 >> 4; }
    const float* W = a.src[w];
    unsigned short* Wt = a.dst[w];
    int k0 = tk * 32, n0 = tn * 32;
    for (int i = ty; i < 32; i += 8)
        t[i][tx] = W[(size_t)(k0 + i) * N + n0 + tx];
    __syncthreads();
    for (int i = ty; i < 32; i += 8)
        Wt[(size_t)(n0 + i) * K + k0 + tx] = f2bf(t[tx][i]);
}

// V rows (stride vstride, head h at col h*DH) -> Vt [B,H,DH,L]
template<bool SKIP>
__global__ __launch_bounds__(256) void vtrans_kernel(const unsigned short* __restrict__ V,
                                                     int vstride,
                                                     unsigned short* __restrict__ Vt,
                                                     const int* __restrict__ counts) {
    __shared__ unsigned short t[64][72];
    int l0 = (blockIdx.x & 15) * 64;
    int h = (blockIdx.x >> 4) & 7;
    int b = blockIdx.x >> 7;
    if (SKIP && l0 > counts[b]) return;
    int tid = threadIdx.x; // 256
    const unsigned short* vb = V + (size_t)b * L * vstride + h * DH;
    for (int e = tid; e < 512; e += 256) {
        int i = e >> 3, d0 = (e & 7) * 8;
        *(bf16x8*)&t[i][d0] = *(const bf16x8*)&vb[(size_t)(l0 + i) * vstride + d0];
    }
    __syncthreads();
    for (int e = tid; e < 512; e += 256) {
        int d = e & 63, i0 = (e >> 6) * 8;
        bf16x8 val;
        #pragma unroll
        for (int j = 0; j < 8; ++j) val[j] = t[i0 + j][d];
        *(bf16x8*)&Vt[((size_t)((b * H + h) * DH + d)) * L + l0 + i0] = val;
    }
}

// ---- 64x128 GEMM (3-buffer, counted vmcnt) — for parallelism-starved cases ----
template<int MODE, bool SKIP, int S>
__global__ __launch_bounds__(256) void gemm_mfma(const unsigned short* __restrict__ A,
                                                 const unsigned short* __restrict__ Wt,
                                                 void* __restrict__ Cv,
                                                 int K, int N,
                                                 const int* __restrict__ counts) {
    int m0 = blockIdx.y * 64, n0 = blockIdx.x * 128;
    if (SKIP && (m0 & 1023) > counts[m0 >> 10]) return;
    int Kc = K / S;
    int kbeg = blockIdx.z * Kc;
    int nk = Kc / 64;
    __shared__ __align__(16) unsigned short As[3][64 * 64];
    __shared__ __align__(16) unsigned short Bs[3][128 * 64];
    int tid = threadIdx.x, lane = tid & 63, wid = tid >> 6;
    int wm = (wid >> 1) * 32, wn = (wid & 1) * 64;
    int r16 = lane & 15, g = lane >> 4;
    f32x4 acc[2][4] = {};

#define STAGE(bufi, kt) do {                                                          \
    int kk_ = kbeg + (kt) * 64;                                                       \
    _Pragma("unroll")                                                                 \
    for (int q_ = 0; q_ < 2; ++q_) {                                                  \
        int e_ = q_ * 256 + tid;                                                      \
        int r_ = e_ >> 3, c_ = ((e_ & 7) ^ (r_ & 7)) * 8;                             \
        __builtin_amdgcn_global_load_lds((gas_ptr)(A + (size_t)(m0 + r_) * K + kk_ + c_), \
                                         (las_ptr)(&As[bufi][0] + (size_t)e_ * 8), 16, 0, 0); \
    }                                                                                 \
    _Pragma("unroll")                                                                 \
    for (int q_ = 0; q_ < 4; ++q_) {                                                  \
        int e_ = q_ * 256 + tid;                                                      \
        int r_ = e_ >> 3, c_ = ((e_ & 7) ^ (r_ & 7)) * 8;                             \
        __builtin_amdgcn_global_load_lds((gas_ptr)(Wt + (size_t)(n0 + r_) * K + kk_ + c_), \
                                         (las_ptr)(&Bs[bufi][0] + (size_t)e_ * 8), 16, 0, 0); \
    }                                                                                 \
} while (0)

    STAGE(0, 0);
    if (nk > 1) STAGE(1, 1);
    asm volatile("s_waitcnt vmcnt(6)" ::: "memory");
    __builtin_amdgcn_s_barrier();
    __builtin_amdgcn_sched_barrier(0);
    int swz = (r16 & 7) * 8;
    for (int kt = 0; kt < nk; ++kt) {
        int cur = kt % 3;
        if (kt + 2 < nk) STAGE((kt + 2) % 3, kt + 2);
        #pragma unroll
        for (int ks = 0; ks < 2; ++ks) {
            bf16x8 av[2], bv[4];
            #pragma unroll
            for (int m = 0; m < 2; ++m)
                av[m] = *(const bf16x8*)&As[cur][(wm + m * 16 + r16) * 64 + ((ks * 32 + g * 8) ^ swz)];
            #pragma unroll
            for (int n = 0; n < 4; ++n)
                bv[n] = *(const bf16x8*)&Bs[cur][(wn + n * 16 + r16) * 64 + ((ks * 32 + g * 8) ^ swz)];
            #pragma unroll
            for (int m = 0; m < 2; ++m)
                #pragma unroll
                for (int n = 0; n < 4; ++n)
                    acc[m][n] = __builtin_amdgcn_mfma_f32_16x16x32_bf16(av[m], bv[n], acc[m][n], 0, 0, 0);
        }
        if (kt + 2 < nk) asm volatile("s_waitcnt vmcnt(6)" ::: "memory");
        else             asm volatile("s_waitcnt vmcnt(0)" ::: "memory");
        __builtin_amdgcn_s_barrier();
        __builtin_amdgcn_sched_barrier(0);
    }
#undef STAGE
    #pragma unroll
    for (int m = 0; m < 2; ++m)
        #pragma unroll
        for (int n = 0; n < 4; ++n)
            #pragma unroll
            for (int r = 0; r < 4; ++r) {
                int grow = m0 + wm + m * 16 + g * 4 + r;
                int gcol = n0 + wn + n * 16 + r16;
                size_t off = (size_t)grow * N + gcol;
                float vv = acc[m][n][r];
                if (MODE == 1) {
                    if (S > 1) atomicAdd((float*)Cv + off, vv);
                    else ((float*)Cv)[off] += vv;
                }
                else if (MODE == 2) ((unsigned short*)Cv)[off] = f2bf(gelu_f(vv));
                else ((unsigned short*)Cv)[off] = f2bf(vv);
            }
}

// ---- 128x128 GEMM (2-buffer, counted vmcnt(8)) — for the big / no-skip GEMMs ----
template<int MODE, bool SKIP, int S>
__global__ __launch_bounds__(256) void gemm_mfma128(const unsigned short* __restrict__ A,
                                                    const unsigned short* __restrict__ Wt,
                                                    void* __restrict__ Cv,
                                                    int K, int N,
                                                    const int* __restrict__ counts) {
    int m0 = blockIdx.y * 128, n0 = blockIdx.x * 128;
    if (SKIP && (m0 & 1023) > counts[m0 >> 10]) return;
    int Kc = K / S;
    int kbeg = blockIdx.z * Kc;
    int nk = Kc / 64;
    __shared__ __align__(16) unsigned short As[2][128 * 64];
    __shared__ __align__(16) unsigned short Bs[2][128 * 64];
    int tid = threadIdx.x, lane = tid & 63, wid = tid >> 6;
    int wm = (wid >> 1) * 64, wn = (wid & 1) * 64;
    int r16 = lane & 15, g = lane >> 4;
    f32x4 acc[4][4] = {};

#define STAGE(bufi, kt) do {                                                          \
    int kk_ = kbeg + (kt) * 64;                                                       \
    _Pragma("unroll")                                                                 \
    for (int q_ = 0; q_ < 4; ++q_) {                                                  \
        int e_ = q_ * 256 + tid;                                                      \
        int r_ = e_ >> 3, c_ = ((e_ & 7) ^ (r_ & 7)) * 8;                             \
        __builtin_amdgcn_global_load_lds((gas_ptr)(A + (size_t)(m0 + r_) * K + kk_ + c_), \
                                         (las_ptr)(&As[bufi][0] + (size_t)e_ * 8), 16, 0, 0); \
        __builtin_amdgcn_global_load_lds((gas_ptr)(Wt + (size_t)(n0 + r_) * K + kk_ + c_), \
                                         (las_ptr)(&Bs[bufi][0] + (size_t)e_ * 8), 16, 0, 0); \
    }                                                                                 \
} while (0)

    STAGE(0, 0);
    if (nk > 1) STAGE(1, 1);
    asm volatile("s_waitcnt vmcnt(8)" ::: "memory");
    __builtin_amdgcn_s_barrier();
    __builtin_amdgcn_sched_barrier(0);
    int swz = (r16 & 7) * 8;
    for (int kt = 0; kt < nk; ++kt) {
        int cur = kt & 1;
        #pragma unroll
        for (int ks = 0; ks < 2; ++ks) {
            bf16x8 av[4], bv[4];
            #pragma unroll
            for (int m = 0; m < 4; ++m)
                av[m] = *(const bf16x8*)&As[cur][(wm + m * 16 + r16) * 64 + ((ks * 32 + g * 8) ^ swz)];
            #pragma unroll
            for (int n = 0; n < 4; ++n)
                bv[n] = *(const bf16x8*)&Bs[cur][(wn + n * 16 + r16) * 64 + ((ks * 32 + g * 8) ^ swz)];
            #pragma unroll
            for (int m = 0; m < 4; ++m)
                #pragma unroll
                for (int n = 0; n < 4; ++n)
                    acc[m][n] = __builtin_amdgcn_mfma_f32_16x16x32_bf16(av[m], bv[n], acc[m][n], 0, 0, 0);
        }
        __builtin_amdgcn_s_barrier();          // all waves done reading buf[cur]
        if (kt + 2 < nk) STAGE(cur, kt + 2);   // overwrite just-consumed buffer
        if (kt + 1 < nk) {
            if (kt + 2 < nk) asm volatile("s_waitcnt vmcnt(8)" ::: "memory");
            else             asm volatile("s_waitcnt vmcnt(0)" ::: "memory");
        }
        __builtin_amdgcn_s_barrier();          // buf[kt+1] visible to all
        __builtin_amdgcn_sched_barrier(0);
    }
#undef STAGE
    #pragma unroll
    for (int m = 0; m < 4; ++m)
        #pragma unroll
        for (int n = 0; n < 4; ++n)
            #pragma unroll
            for (int r = 0; r < 4; ++r) {
                int grow = m0 + wm + m * 16 + g * 4 + r;
                int gcol = n0 + wn + n * 16 + r16;
                size_t off = (size_t)grow * N + gcol;
                float vv = acc[m][n][r];
                if (MODE == 1) {
                    if (S > 1) atomicAdd((float*)Cv + off, vv);
                    else ((float*)Cv)[off] += vv;
                }
                else if (MODE == 2) ((unsigned short*)Cv)[off] = f2bf(gelu_f(vv));
                else ((unsigned short*)Cv)[off] = f2bf(vv);
            }
}

// MFMA flash attention, XOR-swizzled LDS, register K/V prefetch,
// XCD-chunked grid swizzle, optional split-KV (2 chunks of 8 tiles).
template<bool MASK, bool SPLIT>
__global__ __launch_bounds__(256) void attn_mfma(const unsigned short* __restrict__ Q, int qstride,
                                                 const unsigned short* __restrict__ Kb, int kstride,
                                                 const unsigned short* __restrict__ Vt,
                                                 unsigned short* __restrict__ O,
                                                 unsigned short* __restrict__ PO,
                                                 float* __restrict__ ML,
                                                 const int* __restrict__ counts) {
    int nwg = gridDim.x;
    int wg = (blockIdx.x & 7) * (nwg >> 3) + (blockIdx.x >> 3);
    int qt = wg & 15;
    int cidx = SPLIT ? ((wg >> 4) & 1) : 0;
    int h = SPLIT ? ((wg >> 5) & 7) : ((wg >> 4) & 7);
    int b = SPLIT ? (wg >> 8) : (wg >> 7);
    int cntb = counts[b];
    if (qt * 64 > cntb) return;
    __shared__ __align__(16) unsigned short Ks[64][64];
    __shared__ __align__(16) unsigned short Vs[64][64];
    __shared__ __align__(16) unsigned short Ps[4][16][64];
    int tid = threadIdx.x, lane = tid & 63, wid = tid >> 6;
    int q0 = qt * 64 + wid * 16;
    int cnt = MASK ? cntb : L;
    int nt = MASK ? min(16, max(1, (cnt + 63) >> 6)) : 16;
    int kt0 = SPLIT ? cidx * 8 : 0;
    int kt1 = SPLIT ? (cidx * 8 + 8) : nt;
    int r16 = lane & 15, g = lane >> 4;
    int swmask = (r16 & 7) << 3;
    const unsigned short* qbase = Q + ((size_t)(b * L + q0 + r16) * qstride + h * DH + g * 8);
    bf16x8 qv0 = *(const bf16x8*)(qbase);
    bf16x8 qv1 = *(const bf16x8*)(qbase + 32);
    f32x4 o_acc[4] = {};
    float m_run[4], l_run[4];
    #pragma unroll
    for (int r = 0; r < 4; ++r) { m_run[r] = -1e30f; l_run[r] = 0.f; }
    const unsigned short* kb = Kb + (size_t)b * L * kstride + h * DH;
    const unsigned short* vtb = Vt + (size_t)(b * H + h) * DH * L;
    bf16x8 kreg[2], vreg[2];
    #pragma unroll
    for (int q = 0; q < 2; ++q) {
        int e = q * 256 + tid, kv = e >> 3, c0 = (e & 7) * 8;
        kreg[q] = *(const bf16x8*)&kb[(size_t)(kt0 * 64 + kv) * kstride + c0];
        vreg[q] = *(const bf16x8*)&vtb[(size_t)kv * L + kt0 * 64 + c0];
    }
    for (int kt = kt0; kt < kt1; ++kt) {
        __syncthreads();
        #pragma unroll
        for (int q = 0; q < 2; ++q) {
            int e = q * 256 + tid, kv = e >> 3, c0 = (e & 7) * 8;
            int sw = c0 ^ ((kv & 7) << 3);
            *(bf16x8*)&Ks[kv][sw] = kreg[q];
            *(bf16x8*)&Vs[kv][sw] = vreg[q];
        }
        __syncthreads();
        if (kt + 1 < kt1) {
            #pragma unroll
            for (int q = 0; q < 2; ++q) {
                int e = q * 256 + tid, kv = e >> 3, c0 = (e & 7) * 8;
                kreg[q] = *(const bf16x8*)&kb[(size_t)((kt + 1) * 64 + kv) * kstride + c0];
                vreg[q] = *(const bf16x8*)&vtb[(size_t)kv * L + (kt + 1) * 64 + c0];
            }
        }
        f32x4 s[4];
        #pragma unroll
        for (int n = 0; n < 4; ++n) {
            bf16x8 k0 = *(const bf16x8*)&Ks[n * 16 + r16][(g * 8) ^ swmask];
            bf16x8 k1 = *(const bf16x8*)&Ks[n * 16 + r16][(g * 8 + 32) ^ swmask];
            f32x4 z = {};
            z = __builtin_amdgcn_mfma_f32_16x16x32_bf16(qv0, k0, z, 0, 0, 0);
            s[n] = __builtin_amdgcn_mfma_f32_16x16x32_bf16(qv1, k1, z, 0, 0, 0);
        }
        #pragma unroll
        for (int n = 0; n < 4; ++n)
            #pragma unroll
            for (int r = 0; r < 4; ++r) {
                float v = s[n][r] * 0.125f;
                if (MASK) {
                    int kidx = kt * 64 + n * 16 + r16;
                    v = (kidx < cnt) ? v : -1e30f;
                }
                s[n][r] = v;
            }
        #pragma unroll
        for (int r = 0; r < 4; ++r) {
            float rm = fmaxf(fmaxf(s[0][r], s[1][r]), fmaxf(s[2][r], s[3][r]));
            #pragma unroll
            for (int mm = 1; mm < 16; mm <<= 1) rm = fmaxf(rm, __shfl_xor(rm, mm));
            float m_new = fmaxf(m_run[r], rm);
            float rs = 0.f;
            #pragma unroll
            for (int n = 0; n < 4; ++n) { float e = __expf(s[n][r] - m_new); s[n][r] = e; rs += e; }
            #pragma unroll
            for (int mm = 1; mm < 16; mm <<= 1) rs += __shfl_xor(rs, mm);
            float factor = __expf(m_run[r] - m_new);
            l_run[r] = l_run[r] * factor + rs;
            m_run[r] = m_new;
            #pragma unroll
            for (int n = 0; n < 4; ++n) o_acc[n][r] *= factor;
        }
        #pragma unroll
        for (int n = 0; n < 4; ++n)
            #pragma unroll
            for (int r = 0; r < 4; ++r) {
                int qrow = g * 4 + r;
                Ps[wid][qrow][(n * 16 + r16) ^ ((qrow & 7) << 3)] = f2bf(s[n][r]);
            }
        bf16x8 pa0 = *(const bf16x8*)&Ps[wid][r16][(g * 8) ^ swmask];
        bf16x8 pa1 = *(const bf16x8*)&Ps[wid][r16][(g * 8 + 32) ^ swmask];
        #pragma unroll
        for (int n = 0; n < 4; ++n) {
            bf16x8 v0 = *(const bf16x8*)&Vs[n * 16 + r16][(g * 8) ^ swmask];
            bf16x8 v1 = *(const bf16x8*)&Vs[n * 16 + r16][(g * 8 + 32) ^ swmask];
            o_acc[n] = __builtin_amdgcn_mfma_f32_16x16x32_bf16(pa0, v0, o_acc[n], 0, 0, 0);
            o_acc[n] = __builtin_amdgcn_mfma_f32_16x16x32_bf16(pa1, v1, o_acc[n], 0, 0, 0);
        }
    }
    #pragma unroll
    for (int r = 0; r < 4; ++r) {
        float inv = 1.0f / l_run[r];
        int row = q0 + g * 4 + r;
        if (SPLIT) {
            size_t basec = (((size_t)cidx * B + b) * H + h) * L + row;
            #pragma unroll
            for (int n = 0; n < 4; ++n)
                PO[basec * DH + n * 16 + r16] = f2bf(o_acc[n][r] * inv);
            if (r16 == 0) { ML[basec * 2] = m_run[r]; ML[basec * 2 + 1] = l_run[r]; }
        } else {
            size_t ro = (size_t)(b * L + row) * D + h * DH;
            #pragma unroll
            for (int n = 0; n < 4; ++n)
                O[ro + n * 16 + r16] = f2bf(o_acc[n][r] * inv);
        }
    }
}

// merge 2 split-KV chunks
__global__ __launch_bounds__(256) void attn_merge(const unsigned short* __restrict__ PO,
                                                  const float* __restrict__ ML,
                                                  unsigned short* __restrict__ O,
                                                  const int* __restrict__ counts) {
    int qt = blockIdx.x & 15, h = (blockIdx.x >> 4) & 7, b = blockIdx.x >> 7;
    if (qt * 64 > counts[b]) return;
    int tid = threadIdx.x;
    int row = qt * 64 + (tid >> 2);
    int d0 = (tid & 3) * 16;
    size_t base = (size_t)(b * H + h) * L + row;
    size_t cstride = (size_t)B * H * L;
    float m0 = ML[base * 2], l0 = ML[base * 2 + 1];
    float m1 = ML[(base + cstride) * 2], l1 = ML[(base + cstride) * 2 + 1];
    float M = fmaxf(m0, m1);
    float w0 = __expf(m0 - M) * l0, w1 = __expf(m1 - M) * l1;
    float inv = 1.0f / (w0 + w1);
    w0 *= inv; w1 *= inv;
    const bf16x8* p0 = (const bf16x8*)&PO[base * DH + d0];
    const bf16x8* p1 = (const bf16x8*)&PO[(base + cstride) * DH + d0];
    unsigned short* op = O + ((size_t)(b * L + row) * D + h * DH + d0);
    #pragma unroll
    for (int q = 0; q < 2; ++q) {
        bf16x8 a = p0[q], c = p1[q], r;
        #pragma unroll
        for (int j = 0; j < 8; ++j)
            r[j] = (short)f2bf(bf2f((unsigned short)a[j]) * w0 + bf2f((unsigned short)c[j]) * w1);
        *(bf16x8*)(op + q * 8) = r;
    }
}

extern "C" void kernel_launch(void* const* d_in, const int* in_sizes, int n_in,
                              void* d_out, int out_size, void* d_ws, size_t ws_size,
                              hipStream_t stream) {
    const float* hid = (const float*)d_in[0];
    const float* img = (const float*)d_in[1];
    const int* seq   = (const int*)d_in[12];
    const int* pSOC  = (const int*)d_in[13];
    const int* pEOS  = (const int*)d_in[14];
    float* out0 = (float*)d_out;            // hid_new
    float* out1 = out0 + (size_t)BLD;       // x

    char* w = (char*)d_ws;
    int* pos    = (int*)w;
    int* inv    = pos + B * L;
    int* counts = inv + B * L;
    size_t off = 128 * 1024;
    float* x = (float*)(w + off);                     off += (size_t)BLD * 4;
    unsigned short* qkv = (unsigned short*)(w + off); off += (size_t)M_TOT * 3 * D * 2;
    unsigned short* o   = (unsigned short*)(w + off); off += (size_t)BLD * 2;
    unsigned short* vt  = (unsigned short*)(w + off); off += (size_t)BLD * 2;
    unsigned short* xn  = (unsigned short*)(w + off); off += (size_t)BLD * 2;
    unsigned short* imgb= (unsigned short*)(w + off); off += (size_t)BLD * 2;
    unsigned short* Wqt  = (unsigned short*)(w + off); off += (size_t)D * D * 2; // Wq,Wk,Wv contiguous
    unsigned short* Wkt  = (unsigned short*)(w + off); off += (size_t)D * D * 2;
    unsigned short* Wvt  = (unsigned short*)(w + off); off += (size_t)D * D * 2;
    unsigned short* Wot  = (unsigned short*)(w + off); off += (size_t)D * D * 2;
    unsigned short* Wq2t = (unsigned short*)(w + off); off += (size_t)D * D * 2;
    unsigned short* Wk2t = (unsigned short*)(w + off); off += (size_t)D * D * 2; // Wk2,Wv2 contiguous
    unsigned short* Wv2t = (unsigned short*)(w + off); off += (size_t)D * D * 2;
    unsigned short* Wo2t = (unsigned short*)(w + off); off += (size_t)D * D * 2;
    unsigned short* W1t  = (unsigned short*)(w + off); off += (size_t)D * DF * 2;
    unsigned short* W2t  = (unsigned short*)(w + off); off += (size_t)D * DF * 2;
    float* ml            = (float*)(w + off);          off += (size_t)2 * B * H * L * 2 * 4;
    unsigned short* q2  = qkv;
    unsigned short* kv2 = qkv + (size_t)M_TOT * D;
    unsigned short* mid = qkv;
    unsigned short* po  = xn;   // 16MB over xn+imgb (both dead during cross-attn)

    pos_kernel<<<B, 1024, 0, stream>>>(seq, pSOC, pEOS, pos, inv, counts);
    WtArgs wa;
    wa.src[0] = (const float*)d_in[2];  wa.dst[0] = Wqt;
    wa.src[1] = (const float*)d_in[3];  wa.dst[1] = Wkt;
    wa.src[2] = (const float*)d_in[4];  wa.dst[2] = Wvt;
    wa.src[3] = (const float*)d_in[5];  wa.dst[3] = Wot;
    wa.src[4] = (const float*)d_in[6];  wa.dst[4] = Wq2t;
    wa.src[5] = (const float*)d_in[7];  wa.dst[5] = Wk2t;
    wa.src[6] = (const float*)d_in[8];  wa.dst[6] = Wv2t;
    wa.src[7] = (const float*)d_in[9];  wa.dst[7] = Wo2t;
    wa.src[8] = (const float*)d_in[10]; wa.dst[8] = W1t;
    wa.src[9] = (const float*)d_in[11]; wa.dst[9] = W2t;
    wa.img = img; wa.imgb = imgb;
    wtrans_cvt_all<<<8192, dim3(32, 8), 0, stream>>>(wa);

    int attn_grid = B * H * (L / 64);
    // block 1: masked self-attention (fused QKV)
    gather_ln<<<B * L, 256, 0, stream>>>(hid, pos, counts, x, xn);
    gemm_mfma128<3, true, 1><<<dim3(12, 64, 1), 256, 0, stream>>>(xn, Wqt, qkv, D, 3 * D, counts);
    vtrans_kernel<true><<<attn_grid, 256, 0, stream>>>(qkv + 2 * D, 3 * D, vt, counts);
    attn_mfma<true, false><<<attn_grid, 256, 0, stream>>>(qkv, 3 * D, qkv + D, 3 * D, vt, o, po, ml, counts);
    gemm_mfma<1, true, 4><<<dim3(4, 128, 4), 256, 0, stream>>>(o, Wot, x, D, D, counts);
    // block 2: cross-attention to img (fused KV), split-KV 2 chunks
    ln_kernel<<<M_TOT, 256, 0, stream>>>(x, xn, counts);
    gemm_mfma128<3, false, 1><<<dim3(8, 64, 1), 256, 0, stream>>>(imgb, Wk2t, kv2, D, 2 * D, counts);
    gemm_mfma<3, true, 1><<<dim3(4, 128, 1), 256, 0, stream>>>(xn, Wq2t, q2, D, D, counts);
    vtrans_kernel<false><<<attn_grid, 256, 0, stream>>>(kv2 + D, 2 * D, vt, counts);
    attn_mfma<false, true><<<attn_grid * 2, 256, 0, stream>>>(q2, D, kv2, 2 * D, vt, o, po, ml, counts);
    attn_merge<<<attn_grid, 256, 0, stream>>>(po, ml, o, counts);
    gemm_mfma<1, true, 4><<<dim3(4, 128, 4), 256, 0, stream>>>(o, Wo2t, x, D, D, counts);
    // FFN
    ln_kernel<<<M_TOT, 256, 0, stream>>>(x, xn, counts);
    gemm_mfma128<2, true, 1><<<dim3(16, 64, 1), 256, 0, stream>>>(xn, W1t, mid, D, DF, counts);
    gemm_mfma128<1, true, 4><<<dim3(4, 64, 4), 256, 0, stream>>>(mid, W2t, x, DF, D, counts);
    // fused epilogue: out0 (scatter) + out1 (pad-broadcast view of x)
    epilogue_kernel<<<B * L, 128, 0, stream>>>(x, hid, inv, counts, out0, out1);
}

// Round 12
// 232.003 us; speedup vs baseline: 5.4700x; 1.0036x over previous
//
#include <hip/hip_runtime.h>
#include <cmath>

#define B 8
#define L 1024
#define D 512
#define H 8
#define DH 64
#define DF 2048
#define BLD (B*L*D)
#define M_TOT (B*L)

typedef __attribute__((ext_vector_type(8))) short bf16x8;
typedef __attribute__((ext_vector_type(4))) float f32x4;
typedef const __attribute__((address_space(1))) void* gas_ptr;
typedef __attribute__((address_space(3))) void* las_ptr;

__device__ __forceinline__ unsigned short f2bf(float f) {
    unsigned int u = __builtin_bit_cast(unsigned int, f);
    u += 0x7FFFu + ((u >> 16) & 1u);
    return (unsigned short)(u >> 16);
}
__device__ __forceinline__ float bf2f(unsigned short s) {
    return __builtin_bit_cast(float, ((unsigned int)s) << 16);
}

__device__ __forceinline__ float gelu_f(float x) {
    float x3 = x * x * x;
    return 0.5f * x * (1.0f + tanhf(0.7978845608028654f * (x + 0.044715f * x3)));
}

// parallel compaction scan: 1 block/batch, 1024 threads; also emits inv (rank or -1)
__global__ __launch_bounds__(1024) void pos_kernel(const int* __restrict__ seq,
                                                   const int* __restrict__ pSOC,
                                                   const int* __restrict__ pEOS,
                                                   int* __restrict__ pos,
                                                   int* __restrict__ inv,
                                                   int* __restrict__ counts) {
    int b = blockIdx.x, t = threadIdx.x;
    int lane = t & 63, w = t >> 6;
    int sv = seq[b * L + t];
    int SOC = pSOC[0], EOS = pEOS[0];
    int eosf = (sv == EOS) ? 1 : 0;
    unsigned long long em = __ballot(eosf);
    int eexcl = __popcll(em & ((1ull << lane) - 1ull));
    __shared__ int ewt[16], swt[16];
    if (lane == 63) ewt[w] = eexcl + eosf;
    __syncthreads();
    int ebase = 0;
    for (int i = 0; i < w; ++i) ebase += ewt[i];
    int ecum_incl = ebase + eexcl + eosf;
    int socf = (sv == SOC && ecum_incl == 0) ? 1 : 0;
    unsigned long long sm = __ballot(socf);
    int sexcl = __popcll(sm & ((1ull << lane) - 1ull));
    if (lane == 63) swt[w] = sexcl + socf;
    __syncthreads();
    int sbase = 0, stot = 0;
    for (int i = 0; i < 16; ++i) { int v = swt[i]; if (i < w) sbase += v; stot += v; }
    int rank = sbase + sexcl;
    if (socf) pos[b * L + rank] = t;
    inv[b * L + t] = socf ? rank : -1;
    if (t == 0) counts[b] = stot;
}

// fused gather + LayerNorm: writes x (f32, compacted+zero-pad) and xn (bf16 LN)
__global__ void gather_ln(const float* __restrict__ hid, const int* __restrict__ pos,
                          const int* __restrict__ counts,
                          float* __restrict__ X, unsigned short* __restrict__ Y) {
    int j = blockIdx.x % L, b = blockIdx.x / L;
    int cnt = counts[b];
    if ((j & ~127) > cnt) return;    // inactive 128-block: never read downstream
    int t = threadIdx.x;             // 256
    float a = 0.f, b2 = 0.f;
    if (j < cnt) {
        const float* src = hid + (size_t)(b * L + pos[b * L + j]) * D;
        a = src[t]; b2 = src[t + 256];
    }
    size_t row = (size_t)(b * L + j);
    X[row * D + t] = a;
    X[row * D + t + 256] = b2;
    float s = a + b2, sq = a * a + b2 * b2;
    for (int m = 1; m < 64; m <<= 1) {
        s += __shfl_xor(s, m);
        sq += __shfl_xor(sq, m);
    }
    __shared__ float ws[4], wq[4];
    int wid = t >> 6;
    if ((t & 63) == 0) { ws[wid] = s; wq[wid] = sq; }
    __syncthreads();
    s = ws[0] + ws[1] + ws[2] + ws[3];
    sq = wq[0] + wq[1] + wq[2] + wq[3];
    float mu = s * (1.0f / D);
    float var = sq * (1.0f / D) - mu * mu;
    float rs = rsqrtf(var + 1e-5f);
    Y[row * D + t] = f2bf((a - mu) * rs);
    Y[row * D + t + 256] = f2bf((b2 - mu) * rs);
}

// fused epilogue: out0 = scatter(x rows by rank) else hid;  out1 = x with pad-broadcast
__global__ void epilogue_kernel(const float* __restrict__ x, const float* __restrict__ hid,
                                const int* __restrict__ inv, const int* __restrict__ counts,
                                float* __restrict__ out0, float* __restrict__ out1) {
    int l = blockIdx.x % L, b = blockIdx.x / L;
    int t = threadIdx.x;   // 128, float4
    int cnt = counts[b];
    int r = inv[b * L + l];
    const float4* s0 = (const float4*)((r >= 0 ? x + (size_t)(b * L + r) * D
                                               : hid + (size_t)(b * L + l) * D));
    ((float4*)(out0 + (size_t)(b * L + l) * D))[t] = s0[t];
    int jsrc = l < cnt ? l : cnt;
    const float4* s1 = (const float4*)(x + (size_t)(b * L + jsrc) * D);
    ((float4*)(out1 + (size_t)(b * L + l) * D))[t] = s1[t];
}

// LayerNorm, f32 in -> bf16 out; skips rows in fully-padding 128-blocks
__global__ void ln_kernel(const float* __restrict__ X, unsigned short* __restrict__ Y,
                          const int* __restrict__ counts) {
    int row = blockIdx.x;
    if ((row & 1023 & ~127) > counts[row >> 10]) return;
    int t = threadIdx.x; // 256
    const float* xr = X + (size_t)row * D;
    float a = xr[t], b2 = xr[t + 256];
    float s = a + b2, sq = a * a + b2 * b2;
    for (int m = 1; m < 64; m <<= 1) {
        s += __shfl_xor(s, m);
        sq += __shfl_xor(sq, m);
    }
    __shared__ float ws[4], wq[4];
    int wid = t >> 6;
    if ((t & 63) == 0) { ws[wid] = s; wq[wid] = sq; }
    __syncthreads();
    s = ws[0] + ws[1] + ws[2] + ws[3];
    sq = wq[0] + wq[1] + wq[2] + wq[3];
    float mu = s * (1.0f / D);
    float var = sq * (1.0f / D) - mu * mu;
    float rs = rsqrtf(var + 1e-5f);
    Y[(size_t)row * D + t] = f2bf((a - mu) * rs);
    Y[(size_t)row * D + t + 256] = f2bf((b2 - mu) * rs);
}

// fused one-time preprocessing: 10 weight transposes + img f32->bf16
struct WtArgs {
    const float* src[10];
    unsigned short* dst[10];
    const float* img;
    unsigned short* imgb;
};
__global__ void wtrans_cvt_all(WtArgs a) {
    int bid = blockIdx.x;
    int tx = threadIdx.x, ty = threadIdx.y; // (32,8)
    if (bid >= 4096) {   // cvt: 4096 blocks x 1024 floats
        int t = ty * 32 + tx;
        int i = (bid - 4096) * 256 + t;
        float4 f = ((const float4*)a.img)[i];
        ushort4 u;
        u.x = f2bf(f.x); u.y = f2bf(f.y); u.z = f2bf(f.z); u.w = f2bf(f.w);
        ((ushort4*)a.imgb)[i] = u;
        return;
    }
    __shared__ float t[32][33];
    int w, tn, tk, K, N;
    if (bid < 2048)      { w = bid >> 8;      int t2 = bid & 255;  N = 512;  K = 512;  tn = t2 & 15; tk = t2 >> 4; }
    else if (bid < 3072) { w = 8;             int t2 = bid - 2048; N = 2048; K = 512;  tn = t2 & 63; tk = t2 >> 6; }
    else                 { w = 9;             int t2 = bid - 3072; N = 512;  K = 2048; tn = t2 & 15; tk = t2 >> 4; }
    const float* W = a.src[w];
    unsigned short* Wt = a.dst[w];
    int k0 = tk * 32, n0 = tn * 32;
    for (int i = ty; i < 32; i += 8)
        t[i][tx] = W[(size_t)(k0 + i) * N + n0 + tx];
    __syncthreads();
    for (int i = ty; i < 32; i += 8)
        Wt[(size_t)(n0 + i) * K + k0 + tx] = f2bf(t[tx][i]);
}

// V rows (stride vstride, head h at col h*DH) -> Vt [B,H,DH,L]
template<bool SKIP>
__global__ __launch_bounds__(256) void vtrans_kernel(const unsigned short* __restrict__ V,
                                                     int vstride,
                                                     unsigned short* __restrict__ Vt,
                                                     const int* __restrict__ counts) {
    __shared__ unsigned short t[64][72];
    int l0 = (blockIdx.x & 15) * 64;
    int h = (blockIdx.x >> 4) & 7;
    int b = blockIdx.x >> 7;
    if (SKIP && l0 > counts[b]) return;
    int tid = threadIdx.x; // 256
    const unsigned short* vb = V + (size_t)b * L * vstride + h * DH;
    for (int e = tid; e < 512; e += 256) {
        int i = e >> 3, d0 = (e & 7) * 8;
        *(bf16x8*)&t[i][d0] = *(const bf16x8*)&vb[(size_t)(l0 + i) * vstride + d0];
    }
    __syncthreads();
    for (int e = tid; e < 512; e += 256) {
        int d = e & 63, i0 = (e >> 6) * 8;
        bf16x8 val;
        #pragma unroll
        for (int j = 0; j < 8; ++j) val[j] = t[i0 + j][d];
        *(bf16x8*)&Vt[((size_t)((b * H + h) * DH + d)) * L + l0 + i0] = val;
    }
}

// ---- 64x128 GEMM (3-buffer, counted vmcnt) — for parallelism-starved cases ----
template<int MODE, bool SKIP, int S>
__global__ __launch_bounds__(256) void gemm_mfma(const unsigned short* __restrict__ A,
                                                 const unsigned short* __restrict__ Wt,
                                                 void* __restrict__ Cv,
                                                 int K, int N,
                                                 const int* __restrict__ counts) {
    int m0 = blockIdx.y * 64, n0 = blockIdx.x * 128;
    if (SKIP && (m0 & 1023) > counts[m0 >> 10]) return;
    int Kc = K / S;
    int kbeg = blockIdx.z * Kc;
    int nk = Kc / 64;
    __shared__ __align__(16) unsigned short As[3][64 * 64];
    __shared__ __align__(16) unsigned short Bs[3][128 * 64];
    int tid = threadIdx.x, lane = tid & 63, wid = tid >> 6;
    int wm = (wid >> 1) * 32, wn = (wid & 1) * 64;
    int r16 = lane & 15, g = lane >> 4;
    f32x4 acc[2][4] = {};

#define STAGE(bufi, kt) do {                                                          \
    int kk_ = kbeg + (kt) * 64;                                                       \
    _Pragma("unroll")                                                                 \
    for (int q_ = 0; q_ < 2; ++q_) {                                                  \
        int e_ = q_ * 256 + tid;                                                      \
        int r_ = e_ >> 3, c_ = ((e_ & 7) ^ (r_ & 7)) * 8;                             \
        __builtin_amdgcn_global_load_lds((gas_ptr)(A + (size_t)(m0 + r_) * K + kk_ + c_), \
                                         (las_ptr)(&As[bufi][0] + (size_t)e_ * 8), 16, 0, 0); \
    }                                                                                 \
    _Pragma("unroll")                                                                 \
    for (int q_ = 0; q_ < 4; ++q_) {                                                  \
        int e_ = q_ * 256 + tid;                                                      \
        int r_ = e_ >> 3, c_ = ((e_ & 7) ^ (r_ & 7)) * 8;                             \
        __builtin_amdgcn_global_load_lds((gas_ptr)(Wt + (size_t)(n0 + r_) * K + kk_ + c_), \
                                         (las_ptr)(&Bs[bufi][0] + (size_t)e_ * 8), 16, 0, 0); \
    }                                                                                 \
} while (0)

    STAGE(0, 0);
    if (nk > 1) STAGE(1, 1);
    asm volatile("s_waitcnt vmcnt(6)" ::: "memory");
    __builtin_amdgcn_s_barrier();
    __builtin_amdgcn_sched_barrier(0);
    int swz = (r16 & 7) * 8;
    for (int kt = 0; kt < nk; ++kt) {
        int cur = kt % 3;
        if (kt + 2 < nk) STAGE((kt + 2) % 3, kt + 2);
        #pragma unroll
        for (int ks = 0; ks < 2; ++ks) {
            bf16x8 av[2], bv[4];
            #pragma unroll
            for (int m = 0; m < 2; ++m)
                av[m] = *(const bf16x8*)&As[cur][(wm + m * 16 + r16) * 64 + ((ks * 32 + g * 8) ^ swz)];
            #pragma unroll
            for (int n = 0; n < 4; ++n)
                bv[n] = *(const bf16x8*)&Bs[cur][(wn + n * 16 + r16) * 64 + ((ks * 32 + g * 8) ^ swz)];
            #pragma unroll
            for (int m = 0; m < 2; ++m)
                #pragma unroll
                for (int n = 0; n < 4; ++n)
                    acc[m][n] = __builtin_amdgcn_mfma_f32_16x16x32_bf16(av[m], bv[n], acc[m][n], 0, 0, 0);
        }
        if (kt + 2 < nk) asm volatile("s_waitcnt vmcnt(6)" ::: "memory");
        else             asm volatile("s_waitcnt vmcnt(0)" ::: "memory");
        __builtin_amdgcn_s_barrier();
        __builtin_amdgcn_sched_barrier(0);
    }
#undef STAGE
    #pragma unroll
    for (int m = 0; m < 2; ++m)
        #pragma unroll
        for (int n = 0; n < 4; ++n)
            #pragma unroll
            for (int r = 0; r < 4; ++r) {
                int grow = m0 + wm + m * 16 + g * 4 + r;
                int gcol = n0 + wn + n * 16 + r16;
                size_t off = (size_t)grow * N + gcol;
                float vv = acc[m][n][r];
                if (MODE == 1) {
                    if (S > 1) atomicAdd((float*)Cv + off, vv);
                    else ((float*)Cv)[off] += vv;
                }
                else if (MODE == 2) ((unsigned short*)Cv)[off] = f2bf(gelu_f(vv));
                else ((unsigned short*)Cv)[off] = f2bf(vv);
            }
}

// ---- 128x128 GEMM (2-buffer, counted vmcnt(8)) — for the big / no-skip GEMMs ----
template<int MODE, bool SKIP, int S>
__global__ __launch_bounds__(256) void gemm_mfma128(const unsigned short* __restrict__ A,
                                                    const unsigned short* __restrict__ Wt,
                                                    void* __restrict__ Cv,
                                                    int K, int N,
                                                    const int* __restrict__ counts) {
    int m0 = blockIdx.y * 128, n0 = blockIdx.x * 128;
    if (SKIP && (m0 & 1023) > counts[m0 >> 10]) return;
    int Kc = K / S;
    int kbeg = blockIdx.z * Kc;
    int nk = Kc / 64;
    __shared__ __align__(16) unsigned short As[2][128 * 64];
    __shared__ __align__(16) unsigned short Bs[2][128 * 64];
    int tid = threadIdx.x, lane = tid & 63, wid = tid >> 6;
    int wm = (wid >> 1) * 64, wn = (wid & 1) * 64;
    int r16 = lane & 15, g = lane >> 4;
    f32x4 acc[4][4] = {};

#define STAGE(bufi, kt) do {                                                          \
    int kk_ = kbeg + (kt) * 64;                                                       \
    _Pragma("unroll")                                                                 \
    for (int q_ = 0; q_ < 4; ++q_) {                                                  \
        int e_ = q_ * 256 + tid;                                                      \
        int r_ = e_ >> 3, c_ = ((e_ & 7) ^ (r_ & 7)) * 8;                             \
        __builtin_amdgcn_global_load_lds((gas_ptr)(A + (size_t)(m0 + r_) * K + kk_ + c_), \
                                         (las_ptr)(&As[bufi][0] + (size_t)e_ * 8), 16, 0, 0); \
        __builtin_amdgcn_global_load_lds((gas_ptr)(Wt + (size_t)(n0 + r_) * K + kk_ + c_), \
                                         (las_ptr)(&Bs[bufi][0] + (size_t)e_ * 8), 16, 0, 0); \
    }                                                                                 \
} while (0)

    STAGE(0, 0);
    if (nk > 1) STAGE(1, 1);
    asm volatile("s_waitcnt vmcnt(8)" ::: "memory");
    __builtin_amdgcn_s_barrier();
    __builtin_amdgcn_sched_barrier(0);
    int swz = (r16 & 7) * 8;
    for (int kt = 0; kt < nk; ++kt) {
        int cur = kt & 1;
        #pragma unroll
        for (int ks = 0; ks < 2; ++ks) {
            bf16x8 av[4], bv[4];
            #pragma unroll
            for (int m = 0; m < 4; ++m)
                av[m] = *(const bf16x8*)&As[cur][(wm + m * 16 + r16) * 64 + ((ks * 32 + g * 8) ^ swz)];
            #pragma unroll
            for (int n = 0; n < 4; ++n)
                bv[n] = *(const bf16x8*)&Bs[cur][(wn + n * 16 + r16) * 64 + ((ks * 32 + g * 8) ^ swz)];
            #pragma unroll
            for (int m = 0; m < 4; ++m)
                #pragma unroll
                for (int n = 0; n < 4; ++n)
                    acc[m][n] = __builtin_amdgcn_mfma_f32_16x16x32_bf16(av[m], bv[n], acc[m][n], 0, 0, 0);
        }
        __builtin_amdgcn_s_barrier();          // all waves done reading buf[cur]
        if (kt + 2 < nk) STAGE(cur, kt + 2);   // overwrite just-consumed buffer
        if (kt + 1 < nk) {
            if (kt + 2 < nk) asm volatile("s_waitcnt vmcnt(8)" ::: "memory");
            else             asm volatile("s_waitcnt vmcnt(0)" ::: "memory");
        }
        __builtin_amdgcn_s_barrier();          // buf[kt+1] visible to all
        __builtin_amdgcn_sched_barrier(0);
    }
#undef STAGE
    #pragma unroll
    for (int m = 0; m < 4; ++m)
        #pragma unroll
        for (int n = 0; n < 4; ++n)
            #pragma unroll
            for (int r = 0; r < 4; ++r) {
                int grow = m0 + wm + m * 16 + g * 4 + r;
                int gcol = n0 + wn + n * 16 + r16;
                size_t off = (size_t)grow * N + gcol;
                float vv = acc[m][n][r];
                if (MODE == 1) {
                    if (S > 1) atomicAdd((float*)Cv + off, vv);
                    else ((float*)Cv)[off] += vv;
                }
                else if (MODE == 2) ((unsigned short*)Cv)[off] = f2bf(gelu_f(vv));
                else ((unsigned short*)Cv)[off] = f2bf(vv);
            }
}

// MFMA flash attention, XOR-swizzled LDS, register K/V prefetch,
// XCD-chunked grid swizzle, optional split-KV (2 chunks of 8 tiles).
template<bool MASK, bool SPLIT>
__global__ __launch_bounds__(256) void attn_mfma(const unsigned short* __restrict__ Q, int qstride,
                                                 const unsigned short* __restrict__ Kb, int kstride,
                                                 const unsigned short* __restrict__ Vt,
                                                 unsigned short* __restrict__ O,
                                                 unsigned short* __restrict__ PO,
                                                 float* __restrict__ ML,
                                                 const int* __restrict__ counts) {
    int nwg = gridDim.x;
    int wg = (blockIdx.x & 7) * (nwg >> 3) + (blockIdx.x >> 3);
    int qt = wg & 15;
    int cidx = SPLIT ? ((wg >> 4) & 1) : 0;
    int h = SPLIT ? ((wg >> 5) & 7) : ((wg >> 4) & 7);
    int b = SPLIT ? (wg >> 8) : (wg >> 7);
    int cntb = counts[b];
    if (qt * 64 > cntb) return;
    __shared__ __align__(16) unsigned short Ks[64][64];
    __shared__ __align__(16) unsigned short Vs[64][64];
    __shared__ __align__(16) unsigned short Ps[4][16][64];
    int tid = threadIdx.x, lane = tid & 63, wid = tid >> 6;
    int q0 = qt * 64 + wid * 16;
    int cnt = MASK ? cntb : L;
    int nt = MASK ? min(16, max(1, (cnt + 63) >> 6)) : 16;
    int kt0 = SPLIT ? cidx * 8 : 0;
    int kt1 = SPLIT ? (cidx * 8 + 8) : nt;
    int r16 = lane & 15, g = lane >> 4;
    int swmask = (r16 & 7) << 3;
    const unsigned short* qbase = Q + ((size_t)(b * L + q0 + r16) * qstride + h * DH + g * 8);
    bf16x8 qv0 = *(const bf16x8*)(qbase);
    bf16x8 qv1 = *(const bf16x8*)(qbase + 32);
    f32x4 o_acc[4] = {};
    float m_run[4], l_run[4];
    #pragma unroll
    for (int r = 0; r < 4; ++r) { m_run[r] = -1e30f; l_run[r] = 0.f; }
    const unsigned short* kb = Kb + (size_t)b * L * kstride + h * DH;
    const unsigned short* vtb = Vt + (size_t)(b * H + h) * DH * L;
    bf16x8 kreg[2], vreg[2];
    #pragma unroll
    for (int q = 0; q < 2; ++q) {
        int e = q * 256 + tid, kv = e >> 3, c0 = (e & 7) * 8;
        kreg[q] = *(const bf16x8*)&kb[(size_t)(kt0 * 64 + kv) * kstride + c0];
        vreg[q] = *(const bf16x8*)&vtb[(size_t)kv * L + kt0 * 64 + c0];
    }
    for (int kt = kt0; kt < kt1; ++kt) {
        __syncthreads();
        #pragma unroll
        for (int q = 0; q < 2; ++q) {
            int e = q * 256 + tid, kv = e >> 3, c0 = (e & 7) * 8;
            int sw = c0 ^ ((kv & 7) << 3);
            *(bf16x8*)&Ks[kv][sw] = kreg[q];
            *(bf16x8*)&Vs[kv][sw] = vreg[q];
        }
        __syncthreads();
        if (kt + 1 < kt1) {
            #pragma unroll
            for (int q = 0; q < 2; ++q) {
                int e = q * 256 + tid, kv = e >> 3, c0 = (e & 7) * 8;
                kreg[q] = *(const bf16x8*)&kb[(size_t)((kt + 1) * 64 + kv) * kstride + c0];
                vreg[q] = *(const bf16x8*)&vtb[(size_t)kv * L + (kt + 1) * 64 + c0];
            }
        }
        f32x4 s[4];
        #pragma unroll
        for (int n = 0; n < 4; ++n) {
            bf16x8 k0 = *(const bf16x8*)&Ks[n * 16 + r16][(g * 8) ^ swmask];
            bf16x8 k1 = *(const bf16x8*)&Ks[n * 16 + r16][(g * 8 + 32) ^ swmask];
            f32x4 z = {};
            z = __builtin_amdgcn_mfma_f32_16x16x32_bf16(qv0, k0, z, 0, 0, 0);
            s[n] = __builtin_amdgcn_mfma_f32_16x16x32_bf16(qv1, k1, z, 0, 0, 0);
        }
        #pragma unroll
        for (int n = 0; n < 4; ++n)
            #pragma unroll
            for (int r = 0; r < 4; ++r) {
                float v = s[n][r] * 0.125f;
                if (MASK) {
                    int kidx = kt * 64 + n * 16 + r16;
                    v = (kidx < cnt) ? v : -1e30f;
                }
                s[n][r] = v;
            }
        #pragma unroll
        for (int r = 0; r < 4; ++r) {
            float rm = fmaxf(fmaxf(s[0][r], s[1][r]), fmaxf(s[2][r], s[3][r]));
            #pragma unroll
            for (int mm = 1; mm < 16; mm <<= 1) rm = fmaxf(rm, __shfl_xor(rm, mm));
            float m_new = fmaxf(m_run[r], rm);
            float rs = 0.f;
            #pragma unroll
            for (int n = 0; n < 4; ++n) { float e = __expf(s[n][r] - m_new); s[n][r] = e; rs += e; }
            #pragma unroll
            for (int mm = 1; mm < 16; mm <<= 1) rs += __shfl_xor(rs, mm);
            float factor = __expf(m_run[r] - m_new);
            l_run[r] = l_run[r] * factor + rs;
            m_run[r] = m_new;
            #pragma unroll
            for (int n = 0; n < 4; ++n) o_acc[n][r] *= factor;
        }
        #pragma unroll
        for (int n = 0; n < 4; ++n)
            #pragma unroll
            for (int r = 0; r < 4; ++r) {
                int qrow = g * 4 + r;
                Ps[wid][qrow][(n * 16 + r16) ^ ((qrow & 7) << 3)] = f2bf(s[n][r]);
            }
        bf16x8 pa0 = *(const bf16x8*)&Ps[wid][r16][(g * 8) ^ swmask];
        bf16x8 pa1 = *(const bf16x8*)&Ps[wid][r16][(g * 8 + 32) ^ swmask];
        #pragma unroll
        for (int n = 0; n < 4; ++n) {
            bf16x8 v0 = *(const bf16x8*)&Vs[n * 16 + r16][(g * 8) ^ swmask];
            bf16x8 v1 = *(const bf16x8*)&Vs[n * 16 + r16][(g * 8 + 32) ^ swmask];
            o_acc[n] = __builtin_amdgcn_mfma_f32_16x16x32_bf16(pa0, v0, o_acc[n], 0, 0, 0);
            o_acc[n] = __builtin_amdgcn_mfma_f32_16x16x32_bf16(pa1, v1, o_acc[n], 0, 0, 0);
        }
    }
    #pragma unroll
    for (int r = 0; r < 4; ++r) {
        float inv = 1.0f / l_run[r];
        int row = q0 + g * 4 + r;
        if (SPLIT) {
            size_t basec = (((size_t)cidx * B + b) * H + h) * L + row;
            #pragma unroll
            for (int n = 0; n < 4; ++n)
                PO[basec * DH + n * 16 + r16] = f2bf(o_acc[n][r] * inv);
            if (r16 == 0) { ML[basec * 2] = m_run[r]; ML[basec * 2 + 1] = l_run[r]; }
        } else {
            size_t ro = (size_t)(b * L + row) * D + h * DH;
            #pragma unroll
            for (int n = 0; n < 4; ++n)
                O[ro + n * 16 + r16] = f2bf(o_acc[n][r] * inv);
        }
    }
}

// merge 2 split-KV chunks
__global__ __launch_bounds__(256) void attn_merge(const unsigned short* __restrict__ PO,
                                                  const float* __restrict__ ML,
                                                  unsigned short* __restrict__ O,
                                                  const int* __restrict__ counts) {
    int qt = blockIdx.x & 15, h = (blockIdx.x >> 4) & 7, b = blockIdx.x >> 7;
    if (qt * 64 > counts[b]) return;
    int tid = threadIdx.x;
    int row = qt * 64 + (tid >> 2);
    int d0 = (tid & 3) * 16;
    size_t base = (size_t)(b * H + h) * L + row;
    size_t cstride = (size_t)B * H * L;
    float m0 = ML[base * 2], l0 = ML[base * 2 + 1];
    float m1 = ML[(base + cstride) * 2], l1 = ML[(base + cstride) * 2 + 1];
    float M = fmaxf(m0, m1);
    float w0 = __expf(m0 - M) * l0, w1 = __expf(m1 - M) * l1;
    float inv = 1.0f / (w0 + w1);
    w0 *= inv; w1 *= inv;
    const bf16x8* p0 = (const bf16x8*)&PO[base * DH + d0];
    const bf16x8* p1 = (const bf16x8*)&PO[(base + cstride) * DH + d0];
    unsigned short* op = O + ((size_t)(b * L + row) * D + h * DH + d0);
    #pragma unroll
    for (int q = 0; q < 2; ++q) {
        bf16x8 a = p0[q], c = p1[q], r;
        #pragma unroll
        for (int j = 0; j < 8; ++j)
            r[j] = (short)f2bf(bf2f((unsigned short)a[j]) * w0 + bf2f((unsigned short)c[j]) * w1);
        *(bf16x8*)(op + q * 8) = r;
    }
}

extern "C" void kernel_launch(void* const* d_in, const int* in_sizes, int n_in,
                              void* d_out, int out_size, void* d_ws, size_t ws_size,
                              hipStream_t stream) {
    const float* hid = (const float*)d_in[0];
    const float* img = (const float*)d_in[1];
    const int* seq   = (const int*)d_in[12];
    const int* pSOC  = (const int*)d_in[13];
    const int* pEOS  = (const int*)d_in[14];
    float* out0 = (float*)d_out;            // hid_new
    float* out1 = out0 + (size_t)BLD;       // x

    char* w = (char*)d_ws;
    int* pos    = (int*)w;
    int* inv    = pos + B * L;
    int* counts = inv + B * L;
    size_t off = 128 * 1024;
    float* x = (float*)(w + off);                     off += (size_t)BLD * 4;
    unsigned short* qkv = (unsigned short*)(w + off); off += (size_t)M_TOT * 3 * D * 2;
    unsigned short* o   = (unsigned short*)(w + off); off += (size_t)BLD * 2;
    unsigned short* vt  = (unsigned short*)(w + off); off += (size_t)BLD * 2;
    unsigned short* xn  = (unsigned short*)(w + off); off += (size_t)BLD * 2;
    unsigned short* imgb= (unsigned short*)(w + off); off += (size_t)BLD * 2;
    unsigned short* Wqt  = (unsigned short*)(w + off); off += (size_t)D * D * 2; // Wq,Wk,Wv contiguous
    unsigned short* Wkt  = (unsigned short*)(w + off); off += (size_t)D * D * 2;
    unsigned short* Wvt  = (unsigned short*)(w + off); off += (size_t)D * D * 2;
    unsigned short* Wot  = (unsigned short*)(w + off); off += (size_t)D * D * 2;
    unsigned short* Wq2t = (unsigned short*)(w + off); off += (size_t)D * D * 2;
    unsigned short* Wk2t = (unsigned short*)(w + off); off += (size_t)D * D * 2; // Wk2,Wv2 contiguous
    unsigned short* Wv2t = (unsigned short*)(w + off); off += (size_t)D * D * 2;
    unsigned short* Wo2t = (unsigned short*)(w + off); off += (size_t)D * D * 2;
    unsigned short* W1t  = (unsigned short*)(w + off); off += (size_t)D * DF * 2;
    unsigned short* W2t  = (unsigned short*)(w + off); off += (size_t)D * DF * 2;
    float* ml            = (float*)(w + off);          off += (size_t)2 * B * H * L * 2 * 4;
    unsigned short* q2  = qkv;
    unsigned short* kv2 = qkv + (size_t)M_TOT * D;
    unsigned short* mid = qkv;
    unsigned short* po  = xn;   // 16MB over xn+imgb (both dead during cross-attn)

    pos_kernel<<<B, 1024, 0, stream>>>(seq, pSOC, pEOS, pos, inv, counts);
    WtArgs wa;
    wa.src[0] = (const float*)d_in[2];  wa.dst[0] = Wqt;
    wa.src[1] = (const float*)d_in[3];  wa.dst[1] = Wkt;
    wa.src[2] = (const float*)d_in[4];  wa.dst[2] = Wvt;
    wa.src[3] = (const float*)d_in[5];  wa.dst[3] = Wot;
    wa.src[4] = (const float*)d_in[6];  wa.dst[4] = Wq2t;
    wa.src[5] = (const float*)d_in[7];  wa.dst[5] = Wk2t;
    wa.src[6] = (const float*)d_in[8];  wa.dst[6] = Wv2t;
    wa.src[7] = (const float*)d_in[9];  wa.dst[7] = Wo2t;
    wa.src[8] = (const float*)d_in[10]; wa.dst[8] = W1t;
    wa.src[9] = (const float*)d_in[11]; wa.dst[9] = W2t;
    wa.img = img; wa.imgb = imgb;
    wtrans_cvt_all<<<8192, dim3(32, 8), 0, stream>>>(wa);

    int attn_grid = B * H * (L / 64);
    // block 1: masked self-attention (fused QKV)
    gather_ln<<<B * L, 256, 0, stream>>>(hid, pos, counts, x, xn);
    gemm_mfma128<3, true, 1><<<dim3(12, 64, 1), 256, 0, stream>>>(xn, Wqt, qkv, D, 3 * D, counts);
    vtrans_kernel<true><<<attn_grid, 256, 0, stream>>>(qkv + 2 * D, 3 * D, vt, counts);
    attn_mfma<true, false><<<attn_grid, 256, 0, stream>>>(qkv, 3 * D, qkv + D, 3 * D, vt, o, po, ml, counts);
    gemm_mfma<1, true, 4><<<dim3(4, 128, 4), 256, 0, stream>>>(o, Wot, x, D, D, counts);
    // block 2: cross-attention to img (fused KV), split-KV 2 chunks
    ln_kernel<<<M_TOT, 256, 0, stream>>>(x, xn, counts);
    gemm_mfma128<3, false, 1><<<dim3(8, 64, 1), 256, 0, stream>>>(imgb, Wk2t, kv2, D, 2 * D, counts);
    gemm_mfma<3, true, 1><<<dim3(4, 128, 1), 256, 0, stream>>>(xn, Wq2t, q2, D, D, counts);
    vtrans_kernel<false><<<attn_grid, 256, 0, stream>>>(kv2 + D, 2 * D, vt, counts);
    attn_mfma<false, true><<<attn_grid * 2, 256, 0, stream>>>(q2, D, kv2, 2 * D, vt, o, po, ml, counts);
    attn_merge<<<attn_grid, 256, 0, stream>>>(po, ml, o, counts);
    gemm_mfma<1, true, 4><<<dim3(4, 128, 4), 256, 0, stream>>>(o, Wo2t, x, D, D, counts);
    // FFN
    ln_kernel<<<M_TOT, 256, 0, stream>>>(x, xn, counts);
    gemm_mfma128<2, true, 1><<<dim3(16, 64, 1), 256, 0, stream>>>(xn, W1t, mid, D, DF, counts);
    gemm_mfma128<1, true, 4><<<dim3(4, 64, 4), 256, 0, stream>>>(mid, W2t, x, DF, D, counts);
    // fused epilogue: out0 (scatter) + out1 (pad-broadcast view of x)
    epilogue_kernel<<<B * L, 128, 0, stream>>>(x, hid, inv, counts, out0, out1);
}